// Round 9
// baseline (122.695 us; speedup 1.0000x reference)
//
#include <hip/hip_runtime.h>
#include <math.h>

#define T_    2048
#define BTOK  4096   // B * T
#define KB    64
#define NSLOT 144    // sum over 32 strips of ceil((s+1)/4)

namespace {
constexpr int GRADE[16] = {0,1,1,1,1,2,2,2,2,2,2,3,3,3,3,4};
constexpr int AUGK[16]  = {-1,5,-1,-1,-1,6,6,6,-1,-1,-1,7,7,7,-1,8};
constexpr int AUGS[16]  = { 0,0, 0, 0, 0,2,3,4, 0, 0, 0,8,9,10,0,14};
constexpr float FINNER[16] = {1.f,0.f,1.f,1.f,1.f,0.f,0.f,0.f,1.f,1.f,1.f,0.f,0.f,0.f,1.f,0.f};
}

__device__ __forceinline__ float gelu_f(float v){
  return 0.5f*v*(1.f + erff(v*0.70710678118654752f));
}

__device__ __forceinline__ int rsign_d(int a, int b){
  int s=0; a>>=1; while(a){ s += __popc(a&b); a>>=1; } return (s&1) ? -1 : 1;
}

// ---- K_A: embed + in-linear + norm + QKV projections + pack --------------
// 64 threads = 4 tokens x 16 lanes (8 channels x 2 input-halves).
__global__ void __launch_bounds__(64) k_in(
    const float* __restrict__ x,
    const float* __restrict__ w_in_mv, const float* __restrict__ b_in_mv,
    const float* __restrict__ w_in_m2s, const float* __restrict__ b_in_s,
    const float* __restrict__ w_mv, const float* __restrict__ w_s2mv,
    const float* __restrict__ w_m2s, const float* __restrict__ w_s2s,
    float* __restrict__ h_mv, float* __restrict__ h_s,
    float* __restrict__ qp_, float* __restrict__ kp_, float* __restrict__ vp_)
{
  __shared__ float NS[4*152];   // per token: n_mv 128 + n_s 24
  int tid=threadIdx.x, tl=tid>>4, ln=tid&15;
  int o=ln&7, ih=ln>>3;
  int tt=blockIdx.x*4+tl;
  int b=tt>>11, t=tt&(T_-1);
  const float* xp = x+(size_t)tt*6;
  float mv[16];
  #pragma unroll
  for(int p=0;p<16;p++) mv[p]=0.f;
  mv[0]=1.f; mv[14]=1.f;
  mv[13]=-xp[0]; mv[12]=xp[1]; mv[11]=-xp[2];
  mv[5]=0.5f*xp[3]; mv[6]=0.5f*xp[4]; mv[7]=0.5f*xp[5];

  const float* wo=w_in_mv+o*9;
  float h[16]; float sq=0.f;
  #pragma unroll
  for(int p=0;p<16;p++){
    float v=wo[GRADE[p]]*mv[p];
    if(AUGK[p]>=0) v+=wo[AUGK[p]]*mv[AUGS[p]];
    if(p==0) v+=b_in_mv[o];
    h[p]=v; sq+=FINNER[p]*v*v;
  }
  sq+=__shfl_xor(sq,1); sq+=__shfl_xor(sq,2); sq+=__shfl_xor(sq,4);
  float dmv=rsqrtf(sq*0.125f+0.01f);
  float hs[3]; float ssq=0.f;
  #pragma unroll
  for(int jj=0;jj<3;jj++){ float v=w_in_m2s[o*3+jj]+b_in_s[o*3+jj]; hs[jj]=v; ssq+=v*v; }
  ssq+=__shfl_xor(ssq,1); ssq+=__shfl_xor(ssq,2); ssq+=__shfl_xor(ssq,4);
  float dss=rsqrtf(ssq*(1.f/24.f)+0.01f);

  float* ns=&NS[tl*152];
  if(ih==0){
    float4* hg=(float4*)(h_mv+(size_t)tt*128+o*16);
    hg[0]=make_float4(h[0],h[1],h[2],h[3]);
    hg[1]=make_float4(h[4],h[5],h[6],h[7]);
    hg[2]=make_float4(h[8],h[9],h[10],h[11]);
    hg[3]=make_float4(h[12],h[13],h[14],h[15]);
    #pragma unroll
    for(int jj=0;jj<3;jj++) h_s[(size_t)tt*24+o*3+jj]=hs[jj];
    #pragma unroll
    for(int p=0;p<16;p++) ns[o*16+p]=h[p]*dmv;
    #pragma unroll
    for(int jj=0;jj<3;jj++) ns[128+o*3+jj]=hs[jj]*dss;
  }
  __syncthreads();

  float yq[16],yk[16],yv[16];
  #pragma unroll
  for(int p=0;p<16;p++){ yq[p]=0.f; yk[p]=0.f; yv[p]=0.f; }
  float nx0p[4];
  const float* wq=w_mv+o*72;
  #pragma unroll
  for(int ii=0;ii<4;ii++){
    int i=ih*4+ii;
    float xi[16];
    const float4* xs4=(const float4*)&ns[i*16];
    #pragma unroll
    for(int r4=0;r4<4;r4++){ float4 v=xs4[r4]; xi[r4*4]=v.x; xi[r4*4+1]=v.y; xi[r4*4+2]=v.z; xi[r4*4+3]=v.w; }
    nx0p[ii]=xi[0];
    const float* aq=wq+i*9; const float* ak=aq+576; const float* av=aq+1152;
    #pragma unroll
    for(int p=0;p<16;p++){
      float bb=xi[p];
      yq[p]+=aq[GRADE[p]]*bb; yk[p]+=ak[GRADE[p]]*bb; yv[p]+=av[GRADE[p]]*bb;
      if(AUGK[p]>=0){
        float au=xi[AUGS[p]];
        yq[p]+=aq[AUGK[p]]*au; yk[p]+=ak[AUGK[p]]*au; yv[p]+=av[AUGK[p]]*au;
      }
    }
  }
  float eq=0.f,ek=0.f,ev=0.f;
  float sq3[3]={0,0,0}, sk3[3]={0,0,0}, sv3[3]={0,0,0};
  for(int j=ih*12;j<ih*12+12;j++){
    float s=ns[128+j];
    eq+=w_s2mv[o*24+j]*s; ek+=w_s2mv[192+o*24+j]*s; ev+=w_s2mv[384+o*24+j]*s;
    #pragma unroll
    for(int jj=0;jj<3;jj++){
      int d=o*3+jj;
      sq3[jj]+=w_s2s[d*24+j]*s;
      sk3[jj]+=w_s2s[576+d*24+j]*s;
      sv3[jj]+=w_s2s[1152+d*24+j]*s;
    }
  }
  #pragma unroll
  for(int ii=0;ii<4;ii++){
    int i=ih*4+ii;
    #pragma unroll
    for(int jj=0;jj<3;jj++){
      int d=o*3+jj;
      sq3[jj]+=w_m2s[d*8+i]*nx0p[ii];
      sk3[jj]+=w_m2s[192+d*8+i]*nx0p[ii];
      sv3[jj]+=w_m2s[384+d*8+i]*nx0p[ii];
    }
  }
  yq[0]+=eq; yk[0]+=ek; yv[0]+=ev;
  #pragma unroll
  for(int p=0;p<16;p++){
    yq[p]+=__shfl_xor(yq[p],8);
    yk[p]+=__shfl_xor(yk[p],8);
    yv[p]+=__shfl_xor(yv[p],8);
  }
  #pragma unroll
  for(int jj=0;jj<3;jj++){
    sq3[jj]+=__shfl_xor(sq3[jj],8);
    sk3[jj]+=__shfl_xor(sk3[jj],8);
    sv3[jj]+=__shfl_xor(sv3[jj],8);
  }

  const float scale = 0.3015113445777636f;  // 1/sqrt(11)
  size_t rb=((size_t)(b*8+o)*T_+t);
  if(ih==0){
    float4* qr=(float4*)(qp_+rb*12);
    qr[0]=make_float4(yq[0]*scale, yq[2]*scale, yq[3]*scale, yq[4]*scale);
    qr[1]=make_float4(yq[8]*scale, yq[9]*scale, yq[10]*scale, yq[14]*scale);
    qr[2]=make_float4(sq3[0]*scale, sq3[1]*scale, sq3[2]*scale, 0.f);
    float4* vr=(float4*)(vp_+rb*20);
    vr[0]=make_float4(yv[0],yv[1],yv[2],yv[3]);
    vr[1]=make_float4(yv[4],yv[5],yv[6],yv[7]);
    vr[2]=make_float4(yv[8],yv[9],yv[10],yv[11]);
  } else {
    float4* kr=(float4*)(kp_+rb*12);
    kr[0]=make_float4(yk[0],yk[2],yk[3],yk[4]);
    kr[1]=make_float4(yk[8],yk[9],yk[10],yk[14]);
    kr[2]=make_float4(sk3[0],sk3[1],sk3[2],0.f);
    float4* vr=(float4*)(vp_+rb*20);
    vr[3]=make_float4(yv[12],yv[13],yv[14],yv[15]);
    vr[4]=make_float4(sv3[0],sv3[1],sv3[2],0.f);
  }
}

// ---- K_B: attention, no-max softmax, 2 queries/thread, direct-global -----
// 256 thr = 32 q-threads x 8 key-lanes; 64-query strips (32 strips),
// splits c(s)=ceil((s+1)/4), NSLOT=144, 2304 blocks, <=4 key-tiles each.
// base(s) = (a+1)(2a+b), a=s>>2, b=s&3. Heavy slots first.
__global__ void __launch_bounds__(256,1) k_attn(
    const float* __restrict__ qp_, const float* __restrict__ kp_,
    const float* __restrict__ vp_,
    float* __restrict__ part)
{
  int tid=threadIdx.x; int qi=tid>>3, ki=tid&7;
  int j=blockIdx.x;
  int bh=j&15;
  int z=NSLOT-1-(j>>4);          // ascending slot id; j ordered heavy-first
  int a=0;
  while (2*(a+1)*(a+2) <= z) a++;      // <=7 iters
  int rem = z - 2*a*(a+1);
  int bq  = rem/(a+1);
  int sp  = rem - bq*(a+1);
  int s   = 4*a + bq;
  int c   = a+1;
  int ntiles = s+1;
  int t0 = sp*ntiles/c, t1 = (sp+1)*ntiles/c;
  int q0 = s*64;

  float qpA[12], qpB[12];
  { const float4* p4=(const float4*)(qp_+((size_t)bh*T_+q0+qi)*12);
    #pragma unroll
    for(int i=0;i<3;i++){ float4 v=p4[i]; qpA[i*4]=v.x; qpA[i*4+1]=v.y; qpA[i*4+2]=v.z; qpA[i*4+3]=v.w; } }
  { const float4* p4=(const float4*)(qp_+((size_t)bh*T_+q0+32+qi)*12);
    #pragma unroll
    for(int i=0;i<3;i++){ float4 v=p4[i]; qpB[i*4]=v.x; qpB[i*4+1]=v.y; qpB[i*4+2]=v.z; qpB[i*4+3]=v.w; } }
  int kendA=q0+(qi&~15)+16;           // kendB = kendA+32

  float accA[20], accB[20];
  #pragma unroll
  for(int p=0;p<20;p++){ accA[p]=0.f; accB[p]=0.f; }

  const float4* gk=(const float4*)kp_ + (size_t)bh*T_*3;
  const float4* gv=(const float4*)vp_ + (size_t)bh*T_*5;

  for(int tile=t0; tile<t1; ++tile){
    int s0=tile*KB;
    const float4* kb = gk + (size_t)(s0+ki)*3;
    const float4* vb = gv + (size_t)(s0+ki)*5;
    #pragma unroll 2
    for(int it=0; it<8; ++it){
      int skey=s0+ki+it*8;
      float4 k0=kb[it*24], k1=kb[it*24+1], k2=kb[it*24+2];
      float4 v0=vb[it*40], v1=vb[it*40+1], v2=vb[it*40+2], v3=vb[it*40+3], v4=vb[it*40+4];
      float dA = qpA[0]*k0.x+qpA[1]*k0.y+qpA[2]*k0.z+qpA[3]*k0.w
               + qpA[4]*k1.x+qpA[5]*k1.y+qpA[6]*k1.z+qpA[7]*k1.w
               + qpA[8]*k2.x+qpA[9]*k2.y+qpA[10]*k2.z;
      float dB = qpB[0]*k0.x+qpB[1]*k0.y+qpB[2]*k0.z+qpB[3]*k0.w
               + qpB[4]*k1.x+qpB[5]*k1.y+qpB[6]*k1.z+qpB[7]*k1.w
               + qpB[8]*k2.x+qpB[9]*k2.y+qpB[10]*k2.z;
      float cA=(skey<kendA)?    __expf(dA) : 0.f;
      float cB=(skey<kendA+32)? __expf(dB) : 0.f;
      accA[0]+=cA*v0.x; accA[1]+=cA*v0.y; accA[2]+=cA*v0.z; accA[3]+=cA*v0.w;
      accA[4]+=cA*v1.x; accA[5]+=cA*v1.y; accA[6]+=cA*v1.z; accA[7]+=cA*v1.w;
      accA[8]+=cA*v2.x; accA[9]+=cA*v2.y; accA[10]+=cA*v2.z; accA[11]+=cA*v2.w;
      accA[12]+=cA*v3.x; accA[13]+=cA*v3.y; accA[14]+=cA*v3.z; accA[15]+=cA*v3.w;
      accA[16]+=cA; accA[17]+=cA*v4.x; accA[18]+=cA*v4.y; accA[19]+=cA*v4.z;
      accB[0]+=cB*v0.x; accB[1]+=cB*v0.y; accB[2]+=cB*v0.z; accB[3]+=cB*v0.w;
      accB[4]+=cB*v1.x; accB[5]+=cB*v1.y; accB[6]+=cB*v1.z; accB[7]+=cB*v1.w;
      accB[8]+=cB*v2.x; accB[9]+=cB*v2.y; accB[10]+=cB*v2.z; accB[11]+=cB*v2.w;
      accB[12]+=cB*v3.x; accB[13]+=cB*v3.y; accB[14]+=cB*v3.z; accB[15]+=cB*v3.w;
      accB[16]+=cB; accB[17]+=cB*v4.x; accB[18]+=cB*v4.y; accB[19]+=cB*v4.z;
    }
  }

  // butterfly sum across 8 key-lanes (pure adds)
  #pragma unroll
  for(int mk=1; mk<8; mk<<=1){
    #pragma unroll
    for(int p=0;p<20;p++){ accA[p]+=__shfl_xor(accA[p],mk); accB[p]+=__shfl_xor(accB[p],mk); }
  }

  if(ki==0){
    float* pr = part + ((size_t)(bh*NSLOT + z)*64 + qi)*20;
    float4* p4=(float4*)pr;
    p4[0]=make_float4(accA[0],accA[1],accA[2],accA[3]);
    p4[1]=make_float4(accA[4],accA[5],accA[6],accA[7]);
    p4[2]=make_float4(accA[8],accA[9],accA[10],accA[11]);
    p4[3]=make_float4(accA[12],accA[13],accA[14],accA[15]);
    p4[4]=make_float4(accA[16],accA[17],accA[18],accA[19]);
    pr = part + ((size_t)(bh*NSLOT + z)*64 + 32 + qi)*20;
    p4=(float4*)pr;
    p4[0]=make_float4(accB[0],accB[1],accB[2],accB[3]);
    p4[1]=make_float4(accB[4],accB[5],accB[6],accB[7]);
    p4[2]=make_float4(accB[8],accB[9],accB[10],accB[11]);
    p4[3]=make_float4(accB[12],accB[13],accB[14],accB[15]);
    p4[4]=make_float4(accB[16],accB[17],accB[18],accB[19]);
  }
}

// ---- K_C: combine partials + ao + norm + m1 + GP/join + m2 + out ---------
__global__ void __launch_bounds__(64) k_tail(
    const float* __restrict__ part,
    const float* __restrict__ w_ao_mv, const float* __restrict__ w_ao_s2mv,
    const float* __restrict__ w_ao_m2s, const float* __restrict__ w_ao_s2s,
    const float* __restrict__ b_ao_mv, const float* __restrict__ b_ao_s,
    const float* __restrict__ h_mv, const float* __restrict__ h_s,
    const float* __restrict__ w_m1_mv, const float* __restrict__ w_m1_s2mv,
    const float* __restrict__ w_m1_m2s, const float* __restrict__ w_m1_s2s,
    const float* __restrict__ b_m1_mv, const float* __restrict__ b_m1_s,
    const float* __restrict__ w_m2_mv, const float* __restrict__ w_m2_s2mv,
    const float* __restrict__ b_m2_mv,
    const float* __restrict__ w_out_mv,
    float* __restrict__ out)
{
  __shared__ int   GPI[256]; __shared__ float GPS[256];
  __shared__ int   JNI[256]; __shared__ float JNS[256];
  __shared__ float OS[4*152];
  __shared__ float NS[4*152];
  __shared__ float U[4*264];
  __shared__ float G[4*136];
  __shared__ float GSm[4*24];
  int tid=threadIdx.x, tl=tid>>4, ln=tid&15;
  int o=ln&7, ih=ln>>3;
  int tt=blockIdx.x*4+tl;

  { // build tables (threads 0..31)
    const int mask_of[16]={0,1,2,4,8,3,5,9,6,10,12,7,11,13,14,15};
    const int idx_of[16] ={0,1,2,5,3,6,8,11,4,7,9,12,10,13,14,15};
    if (tid<16){
      int k=tid, km=mask_of[k], slotn=0;
      for(int i=0;i<16;i++){
        int im=mask_of[i], jm=im^km;
        if(im & jm & 1) continue;
        GPI[k*16+slotn]=i|(idx_of[jm]<<4);
        GPS[k*16+slotn]=(float)rsign_d(im,jm);
        slotn++;
      }
      for(;slotn<16;slotn++){ GPI[k*16+slotn]=0; GPS[k*16+slotn]=0.f; }
    } else if (tid<32){
      int p=tid-16, pm=mask_of[p], rest=15&~pm, slotn=0;
      for(int u=0;u<16;u++){
        if(u & ~rest) continue;
        int am=pm|u, bm=pm|(rest&~u);
        float s=(float)( rsign_d(pm,15&~pm)*rsign_d(15&~am,15&~bm)
                        *rsign_d(am,15&~am)*rsign_d(bm,15&~bm) );
        JNI[p*16+slotn]=idx_of[am]|(idx_of[bm]<<4);
        JNS[p*16+slotn]=s;
        slotn++;
      }
      for(;slotn<16;slotn++){ JNI[p*16+slotn]=0; JNS[p*16+slotn]=0.f; }
    }
  }

  // combine attention partials: lane = (head h, comp-half)
  {
    int b=tt>>11, t=tt&(T_-1);
    int strip=t>>6, qil=t&63;
    int h=ln>>1, half=ln&1;
    int aa=strip>>2, bb=strip&3;
    int nsp=aa+1;
    int rbase=(aa+1)*(2*aa+bb);
    const float* pb = part + ((size_t)((b*8+h)*NSLOT+rbase)*64 + qil)*20;
    float am[8]={0,0,0,0,0,0,0,0};
    float lv=0.f, s0=0.f, s1=0.f, s2=0.f;
    for(int spp=0; spp<nsp; ++spp){
      const float4* p4=(const float4*)(pb + (size_t)spp*64*20);
      float4 a4=p4[half*2], b4=p4[half*2+1], meta=p4[4];
      am[0]+=a4.x; am[1]+=a4.y; am[2]+=a4.z; am[3]+=a4.w;
      am[4]+=b4.x; am[5]+=b4.y; am[6]+=b4.z; am[7]+=b4.w;
      lv+=meta.x; s0+=meta.y; s1+=meta.z; s2+=meta.w;
    }
    float inv=1.f/lv;
    float* os=&OS[tl*152];
    #pragma unroll
    for(int p=0;p<8;p++) os[h*16+half*8+p]=am[p]*inv;
    if(half==1){ os[128+h*3]=s0*inv; os[128+h*3+1]=s1*inv; os[128+h*3+2]=s2*inv; }
  }
  __syncthreads();

  const float* os=&OS[tl*152];
  float xh[4][16];
  #pragma unroll
  for(int ii=0;ii<4;ii++){
    #pragma unroll
    for(int p=0;p<16;p++) xh[ii][p]=os[(ih*4+ii)*16+p];
  }
  float xs[24];
  #pragma unroll
  for(int jj=0;jj<24;jj++) xs[jj]=os[128+jj];

  // ao: channel o, partial over i-half and j-half
  float y[16];
  #pragma unroll
  for(int p=0;p<16;p++) y[p]=0.f;
  #pragma unroll
  for(int ii=0;ii<4;ii++){
    const float* wi=w_ao_mv+o*72+(ih*4+ii)*9;
    #pragma unroll
    for(int p=0;p<16;p++){
      y[p]+=wi[GRADE[p]]*xh[ii][p];
      if(AUGK[p]>=0) y[p]+=wi[AUGK[p]]*xh[ii][AUGS[p]];
    }
  }
  float e=(ih==0)? b_ao_mv[o] : 0.f;
  for(int j2=ih*12;j2<ih*12+12;j2++) e+=w_ao_s2mv[o*24+j2]*xs[j2];
  y[0]+=e;
  float a3[3];
  #pragma unroll
  for(int jj=0;jj<3;jj++) a3[jj]=(ih==0)? b_ao_s[o*3+jj] : 0.f;
  #pragma unroll
  for(int ii=0;ii<4;ii++){
    #pragma unroll
    for(int jj=0;jj<3;jj++) a3[jj]+=w_ao_m2s[(o*3+jj)*8+(ih*4+ii)]*xh[ii][0];
  }
  for(int j2=ih*12;j2<ih*12+12;j2++){
    #pragma unroll
    for(int jj=0;jj<3;jj++) a3[jj]+=w_ao_s2s[(o*3+jj)*24+j2]*xs[j2];
  }
  #pragma unroll
  for(int p=0;p<16;p++) y[p]+=__shfl_xor(y[p],8);
  #pragma unroll
  for(int jj=0;jj<3;jj++) a3[jj]+=__shfl_xor(a3[jj],8);

  // residual + norms
  float hch[16]; float sqv=0.f;
  { const float4* hg=(const float4*)(h_mv+(size_t)tt*128+o*16);
    #pragma unroll
    for(int r4=0;r4<4;r4++){ float4 v=hg[r4];
      hch[r4*4]=v.x+y[r4*4]; hch[r4*4+1]=v.y+y[r4*4+1];
      hch[r4*4+2]=v.z+y[r4*4+2]; hch[r4*4+3]=v.w+y[r4*4+3]; } }
  #pragma unroll
  for(int p=0;p<16;p++) sqv+=FINNER[p]*hch[p]*hch[p];
  sqv+=__shfl_xor(sqv,1); sqv+=__shfl_xor(sqv,2); sqv+=__shfl_xor(sqv,4);
  float dmv=rsqrtf(sqv*0.125f+0.01f);
  float hs3[3]; float ssq=0.f;
  #pragma unroll
  for(int jj=0;jj<3;jj++){
    float v=h_s[(size_t)tt*24+o*3+jj]+a3[jj];
    hs3[jj]=v; ssq+=v*v;
  }
  ssq+=__shfl_xor(ssq,1); ssq+=__shfl_xor(ssq,2); ssq+=__shfl_xor(ssq,4);
  float dss=rsqrtf(ssq*(1.f/24.f)+0.01f);

  float* nsbuf=&NS[tl*152];
  if(ih==0){
    #pragma unroll
    for(int p=0;p<16;p++) nsbuf[o*16+p]=hch[p]*dmv;
    #pragma unroll
    for(int jj=0;jj<3;jj++) nsbuf[128+o*3+jj]=hs3[jj]*dss;
  }
  __syncthreads();

  // m1: lane = output channel ln=0..15
  float u[16];
  #pragma unroll
  for(int p=0;p<16;p++) u[p]=0.f;
  for(int i=0;i<8;i++){
    float xi[16];
    const float4* xs4=(const float4*)&nsbuf[i*16];
    #pragma unroll
    for(int r4=0;r4<4;r4++){ float4 v=xs4[r4]; xi[r4*4]=v.x; xi[r4*4+1]=v.y; xi[r4*4+2]=v.z; xi[r4*4+3]=v.w; }
    const float* wi=w_m1_mv+ln*72+i*9;
    #pragma unroll
    for(int p=0;p<16;p++){
      u[p]+=wi[GRADE[p]]*xi[p];
      if(AUGK[p]>=0) u[p]+=wi[AUGK[p]]*xi[AUGS[p]];
    }
  }
  float e1=b_m1_mv[ln];
  for(int j2=0;j2<24;j2++) e1+=w_m1_s2mv[ln*24+j2]*nsbuf[128+j2];
  u[0]+=e1;
  { float* uu=&U[tl*264];
    #pragma unroll
    for(int p=0;p<16;p++) uu[ln*16+p]=u[p]; }
  if(ih==0){
    float s3[3];
    #pragma unroll
    for(int jj=0;jj<3;jj++) s3[jj]=b_m1_s[o*3+jj];
    for(int j2=0;j2<24;j2++){
      float s=nsbuf[128+j2];
      #pragma unroll
      for(int jj=0;jj<3;jj++) s3[jj]+=w_m1_s2s[(o*3+jj)*24+j2]*s;
    }
    for(int i=0;i<8;i++){
      float x0=nsbuf[i*16];
      #pragma unroll
      for(int jj=0;jj<3;jj++) s3[jj]+=w_m1_m2s[(o*3+jj)*8+i]*x0;
    }
    #pragma unroll
    for(int jj=0;jj<3;jj++) GSm[tl*24+o*3+jj]=gelu_f(s3[jj]);
  }
  __syncthreads();

  // GP (o<4) / JOIN (o>=4): product o, component half ih
  { const int*   TI=(o<4)? GPI : JNI;
    const float* TS=(o<4)? GPS : JNS;
    const float* uu=&U[tl*264];
    const float* lft=&uu[((o<4)? o : (4+o))*16];
    const float* rgt=&uu[((o<4)? (4+o) : (8+o))*16];
    float* gg=&G[tl*136];
    #pragma unroll
    for(int kk=0;kk<8;kk++){
      int k=ih*8+kk;
      float accv=0.f;
      #pragma unroll
      for(int e2=0;e2<16;e2++){
        int ij=TI[k*16+e2]; float sg=TS[k*16+e2];
        accv += sg * lft[ij&15] * rgt[ij>>4];
      }
      gg[o*16+k]=accv;
    }
  }
  __syncthreads();
  if(ih==0){
    float* gg=&G[tl*136];
    float gt=gelu_f(gg[o*16]);
    #pragma unroll
    for(int p=0;p<16;p++) gg[o*16+p]*=gt;
  }
  __syncthreads();

  // m2: channel o, i-half + j-half, combine
  float y2[16];
  #pragma unroll
  for(int p=0;p<16;p++) y2[p]=0.f;
  #pragma unroll
  for(int ii=0;ii<4;ii++){
    float xi[16];
    const float4* gi=(const float4*)&G[tl*136+(ih*4+ii)*16];
    #pragma unroll
    for(int r4=0;r4<4;r4++){ float4 v=gi[r4]; xi[r4*4]=v.x; xi[r4*4+1]=v.y; xi[r4*4+2]=v.z; xi[r4*4+3]=v.w; }
    const float* wi=w_m2_mv+o*72+(ih*4+ii)*9;
    #pragma unroll
    for(int p=0;p<16;p++){
      y2[p]+=wi[GRADE[p]]*xi[p];
      if(AUGK[p]>=0) y2[p]+=wi[AUGK[p]]*xi[AUGS[p]];
    }
  }
  float e2=(ih==0)? b_m2_mv[o] : 0.f;
  for(int j2=ih*12;j2<ih*12+12;j2++) e2+=w_m2_s2mv[o*24+j2]*GSm[tl*24+j2];
  y2[0]+=e2;
  #pragma unroll
  for(int p=0;p<16;p++) y2[p]+=__shfl_xor(y2[p],8);

  float hf[16];
  #pragma unroll
  for(int p=0;p<16;p++) hf[p]=hch[p]+y2[p];

  const float* wout=w_out_mv+o*9;
  float c5 =wout[2]*hf[5] +wout[6]*hf[2];
  float c6 =wout[2]*hf[6] +wout[6]*hf[3];
  float c7 =wout[2]*hf[7] +wout[6]*hf[4];
  float c11=wout[3]*hf[11]+wout[7]*hf[8];
  float c12=wout[3]*hf[12]+wout[7]*hf[9];
  float c13=wout[3]*hf[13]+wout[7]*hf[10];
  float c14=wout[3]*hf[14];
  #pragma unroll
  for(int mk=1; mk<8; mk<<=1){
    c5+=__shfl_xor(c5,mk); c6+=__shfl_xor(c6,mk); c7+=__shfl_xor(c7,mk);
    c11+=__shfl_xor(c11,mk); c12+=__shfl_xor(c12,mk);
    c13+=__shfl_xor(c13,mk); c14+=__shfl_xor(c14,mk);
  }
  if(ln==0){
    float dd=c14;
    dd=(fabsf(dd)>0.001f)? dd : (dd>=0.f? 0.001f : -0.001f);
    float* op=out+(size_t)tt*6;
    op[0]=-c13/dd; op[1]=c12/dd; op[2]=-c11/dd;
    op[3]=2.f*c5; op[4]=2.f*c6; op[5]=2.f*c7;
  }
}

extern "C" void kernel_launch(void* const* d_in, const int* in_sizes, int n_in,
                              void* d_out, int out_size, void* d_ws, size_t ws_size,
                              hipStream_t stream)
{
  (void)in_sizes; (void)n_in; (void)out_size; (void)ws_size;
  const float* x         =(const float*)d_in[0];
  const float* w_in_mv   =(const float*)d_in[1];
  const float* b_in_mv   =(const float*)d_in[2];
  const float* w_in_m2s  =(const float*)d_in[3];
  const float* b_in_s    =(const float*)d_in[4];
  const float* w_qkv_mv  =(const float*)d_in[5];
  const float* w_qkv_s2mv=(const float*)d_in[6];
  const float* w_qkv_m2s =(const float*)d_in[7];
  const float* w_qkv_s2s =(const float*)d_in[8];
  const float* w_ao_mv   =(const float*)d_in[9];
  const float* w_ao_s2mv =(const float*)d_in[10];
  const float* w_ao_m2s  =(const float*)d_in[11];
  const float* w_ao_s2s  =(const float*)d_in[12];
  const float* b_ao_mv   =(const float*)d_in[13];
  const float* b_ao_s    =(const float*)d_in[14];
  const float* w_m1_mv   =(const float*)d_in[15];
  const float* w_m1_s2mv =(const float*)d_in[16];
  const float* w_m1_m2s  =(const float*)d_in[17];
  const float* w_m1_s2s  =(const float*)d_in[18];
  const float* b_m1_mv   =(const float*)d_in[19];
  const float* b_m1_s    =(const float*)d_in[20];
  const float* w_m2_mv   =(const float*)d_in[21];
  const float* w_m2_s2mv =(const float*)d_in[22];
  const float* b_m2_mv   =(const float*)d_in[25];
  const float* w_out_mv  =(const float*)d_in[27];
  float* outp=(float*)d_out;

  float* ws=(float*)d_ws;
  size_t off=0;
  float* h_mv = ws+off; off+=(size_t)BTOK*128;
  float* h_s  = ws+off; off+=(size_t)BTOK*24;
  float* qpk  = ws+off; off+=(size_t)16*T_*12;
  float* kpk  = ws+off; off+=(size_t)16*T_*12;
  float* vpk  = ws+off; off+=(size_t)16*T_*20;
  float* part = ws+off; off+=(size_t)16*NSLOT*64*20;

  k_in  <<<BTOK/4,64,0,stream>>>(x,w_in_mv,b_in_mv,w_in_m2s,b_in_s,
                                 w_qkv_mv,w_qkv_s2mv,w_qkv_m2s,w_qkv_s2s,
                                 h_mv,h_s,qpk,kpk,vpk);
  k_attn<<<16*NSLOT,256,0,stream>>>(qpk,kpk,vpk,part);
  k_tail<<<BTOK/4,64,0,stream>>>(part,
                                 w_ao_mv,w_ao_s2mv,w_ao_m2s,w_ao_s2s,b_ao_mv,b_ao_s,
                                 h_mv,h_s,
                                 w_m1_mv,w_m1_s2mv,w_m1_m2s,w_m1_s2s,b_m1_mv,b_m1_s,
                                 w_m2_mv,w_m2_s2mv,b_m2_mv,w_out_mv,outp);
}

// Round 10
// 90.580 us; speedup vs baseline: 1.3546x; 1.3546x over previous
//
#include <hip/hip_runtime.h>
#include <math.h>

#define T_    2048
#define BTOK  4096   // B * T
#define KB    64
#define NSLOT 72     // sum over 16 strips of ceil((s+1)/2)

namespace {
constexpr int GRADE[16] = {0,1,1,1,1,2,2,2,2,2,2,3,3,3,3,4};
constexpr int AUGK[16]  = {-1,5,-1,-1,-1,6,6,6,-1,-1,-1,7,7,7,-1,8};
constexpr int AUGS[16]  = { 0,0, 0, 0, 0,2,3,4, 0, 0, 0,8,9,10,0,14};
constexpr float FINNER[16] = {1.f,0.f,1.f,1.f,1.f,0.f,0.f,0.f,1.f,1.f,1.f,0.f,0.f,0.f,1.f,0.f};
}

typedef _Float16 h2_t __attribute__((ext_vector_type(2)));

__device__ __forceinline__ unsigned pkh(float a, float b){
  return __builtin_bit_cast(unsigned, __builtin_amdgcn_cvt_pkrtz(a,b));
}
__device__ __forceinline__ float dot2h(unsigned a, unsigned b, float c){
#if __has_builtin(__builtin_amdgcn_fdot2)
  return __builtin_amdgcn_fdot2(__builtin_bit_cast(h2_t,a), __builtin_bit_cast(h2_t,b), c, false);
#else
  float r;
  asm("v_dot2_f32_f16 %0, %1, %2, %3" : "=v"(r) : "v"(a), "v"(b), "v"(c));
  return r;
#endif
}

__device__ __forceinline__ float gelu_f(float v){
  return 0.5f*v*(1.f + erff(v*0.70710678118654752f));
}

__device__ __forceinline__ int rsign_d(int a, int b){
  int s=0; a>>=1; while(a){ s += __popc(a&b); a>>=1; } return (s&1) ? -1 : 1;
}

// ---- K_A: embed + in-linear + norm + QKV projections + fp16 pack ---------
// 64 threads = 4 tokens x 16 lanes (8 channels x 2 input-halves).
// Q stays fp32 (12/token); K packed fp16 (16 halfs/key, 6 pairs used);
// V packed fp16 interleaved by KEY-PAIR: vph[pair][c] = half2(v_even[c], v_odd[c]).
__global__ void __launch_bounds__(64) k_in(
    const float* __restrict__ x,
    const float* __restrict__ w_in_mv, const float* __restrict__ b_in_mv,
    const float* __restrict__ w_in_m2s, const float* __restrict__ b_in_s,
    const float* __restrict__ w_mv, const float* __restrict__ w_s2mv,
    const float* __restrict__ w_m2s, const float* __restrict__ w_s2s,
    float* __restrict__ h_mv, float* __restrict__ h_s,
    float* __restrict__ qp_, unsigned* __restrict__ kph, unsigned* __restrict__ vph)
{
  __shared__ float NS[4*152];   // per token: n_mv 128 + n_s 24
  int tid=threadIdx.x, tl=tid>>4, ln=tid&15;
  int o=ln&7, ih=ln>>3;
  int tt=blockIdx.x*4+tl;
  int b=tt>>11, t=tt&(T_-1);
  const float* xp = x+(size_t)tt*6;
  float mv[16];
  #pragma unroll
  for(int p=0;p<16;p++) mv[p]=0.f;
  mv[0]=1.f; mv[14]=1.f;
  mv[13]=-xp[0]; mv[12]=xp[1]; mv[11]=-xp[2];
  mv[5]=0.5f*xp[3]; mv[6]=0.5f*xp[4]; mv[7]=0.5f*xp[5];

  const float* wo=w_in_mv+o*9;
  float h[16]; float sq=0.f;
  #pragma unroll
  for(int p=0;p<16;p++){
    float v=wo[GRADE[p]]*mv[p];
    if(AUGK[p]>=0) v+=wo[AUGK[p]]*mv[AUGS[p]];
    if(p==0) v+=b_in_mv[o];
    h[p]=v; sq+=FINNER[p]*v*v;
  }
  sq+=__shfl_xor(sq,1); sq+=__shfl_xor(sq,2); sq+=__shfl_xor(sq,4);
  float dmv=rsqrtf(sq*0.125f+0.01f);
  float hs[3]; float ssq=0.f;
  #pragma unroll
  for(int jj=0;jj<3;jj++){ float v=w_in_m2s[o*3+jj]+b_in_s[o*3+jj]; hs[jj]=v; ssq+=v*v; }
  ssq+=__shfl_xor(ssq,1); ssq+=__shfl_xor(ssq,2); ssq+=__shfl_xor(ssq,4);
  float dss=rsqrtf(ssq*(1.f/24.f)+0.01f);

  float* ns=&NS[tl*152];
  if(ih==0){
    float4* hg=(float4*)(h_mv+(size_t)tt*128+o*16);
    hg[0]=make_float4(h[0],h[1],h[2],h[3]);
    hg[1]=make_float4(h[4],h[5],h[6],h[7]);
    hg[2]=make_float4(h[8],h[9],h[10],h[11]);
    hg[3]=make_float4(h[12],h[13],h[14],h[15]);
    #pragma unroll
    for(int jj=0;jj<3;jj++) h_s[(size_t)tt*24+o*3+jj]=hs[jj];
    #pragma unroll
    for(int p=0;p<16;p++) ns[o*16+p]=h[p]*dmv;
    #pragma unroll
    for(int jj=0;jj<3;jj++) ns[128+o*3+jj]=hs[jj]*dss;
  }
  __syncthreads();

  float yq[16],yk[16],yv[16];
  #pragma unroll
  for(int p=0;p<16;p++){ yq[p]=0.f; yk[p]=0.f; yv[p]=0.f; }
  float nx0p[4];
  const float* wq=w_mv+o*72;
  #pragma unroll
  for(int ii=0;ii<4;ii++){
    int i=ih*4+ii;
    float xi[16];
    const float4* xs4=(const float4*)&ns[i*16];
    #pragma unroll
    for(int r4=0;r4<4;r4++){ float4 v=xs4[r4]; xi[r4*4]=v.x; xi[r4*4+1]=v.y; xi[r4*4+2]=v.z; xi[r4*4+3]=v.w; }
    nx0p[ii]=xi[0];
    const float* aq=wq+i*9; const float* ak=aq+576; const float* av=aq+1152;
    #pragma unroll
    for(int p=0;p<16;p++){
      float bb=xi[p];
      yq[p]+=aq[GRADE[p]]*bb; yk[p]+=ak[GRADE[p]]*bb; yv[p]+=av[GRADE[p]]*bb;
      if(AUGK[p]>=0){
        float au=xi[AUGS[p]];
        yq[p]+=aq[AUGK[p]]*au; yk[p]+=ak[AUGK[p]]*au; yv[p]+=av[AUGK[p]]*au;
      }
    }
  }
  float eq=0.f,ek=0.f,ev=0.f;
  float sq3[3]={0,0,0}, sk3[3]={0,0,0}, sv3[3]={0,0,0};
  for(int j=ih*12;j<ih*12+12;j++){
    float s=ns[128+j];
    eq+=w_s2mv[o*24+j]*s; ek+=w_s2mv[192+o*24+j]*s; ev+=w_s2mv[384+o*24+j]*s;
    #pragma unroll
    for(int jj=0;jj<3;jj++){
      int d=o*3+jj;
      sq3[jj]+=w_s2s[d*24+j]*s;
      sk3[jj]+=w_s2s[576+d*24+j]*s;
      sv3[jj]+=w_s2s[1152+d*24+j]*s;
    }
  }
  #pragma unroll
  for(int ii=0;ii<4;ii++){
    int i=ih*4+ii;
    #pragma unroll
    for(int jj=0;jj<3;jj++){
      int d=o*3+jj;
      sq3[jj]+=w_m2s[d*8+i]*nx0p[ii];
      sk3[jj]+=w_m2s[192+d*8+i]*nx0p[ii];
      sv3[jj]+=w_m2s[384+d*8+i]*nx0p[ii];
    }
  }
  yq[0]+=eq; yk[0]+=ek; yv[0]+=ev;
  #pragma unroll
  for(int p=0;p<16;p++){
    yq[p]+=__shfl_xor(yq[p],8);
    yk[p]+=__shfl_xor(yk[p],8);
    yv[p]+=__shfl_xor(yv[p],8);
  }
  #pragma unroll
  for(int jj=0;jj<3;jj++){
    sq3[jj]+=__shfl_xor(sq3[jj],8);
    sk3[jj]+=__shfl_xor(sk3[jj],8);
    sv3[jj]+=__shfl_xor(sv3[jj],8);
  }

  const float scale = 0.3015113445777636f;  // 1/sqrt(11)
  size_t rb=((size_t)(b*8+o)*T_+t);
  if(ih==0){
    float4* qr=(float4*)(qp_+rb*12);
    qr[0]=make_float4(yq[0]*scale, yq[2]*scale, yq[3]*scale, yq[4]*scale);
    qr[1]=make_float4(yq[8]*scale, yq[9]*scale, yq[10]*scale, yq[14]*scale);
    qr[2]=make_float4(sq3[0]*scale, sq3[1]*scale, sq3[2]*scale, 0.f);
  } else {
    // K fp16 pack: pairs (k0,k2)(k3,k4)(k8,k9)(k10,k14)(s0,s1)(s2,0) — must match Q pair order
    uint4 k0p, k1p;
    k0p.x=pkh(yk[0],yk[2]);  k0p.y=pkh(yk[3],yk[4]);
    k0p.z=pkh(yk[8],yk[9]);  k0p.w=pkh(yk[10],yk[14]);
    k1p.x=pkh(sk3[0],sk3[1]); k1p.y=pkh(sk3[2],0.f); k1p.z=0u; k1p.w=0u;
    uint4* kr=(uint4*)kph + rb*2;
    kr[0]=k0p; kr[1]=k1p;
  }
  // V fp16 interleave by key-pair: half2(v_even[c], v_odd[c]) via cross-token shfl
  {
    size_t vpb = ((size_t)(b*8+o)*(T_/2) + (t>>1))*20;
    bool even = ((tl&1)==0);
    if(ih==0){
      #pragma unroll
      for(int c=0;c<10;c++){
        float other=__shfl_xor(yv[c],16);
        if(even) vph[vpb+c]=pkh(yv[c],other);
      }
    } else {
      #pragma unroll
      for(int c=10;c<16;c++){
        float other=__shfl_xor(yv[c],16);
        if(even) vph[vpb+c]=pkh(yv[c],other);
      }
      #pragma unroll
      for(int jj=0;jj<3;jj++){
        float other=__shfl_xor(sv3[jj],16);
        if(even) vph[vpb+16+jj]=pkh(sv3[jj],other);
      }
      if(even) vph[vpb+19]=0u;
    }
  }
}

// ---- K_B: attention, no-max softmax, fp16 dot2, 4 queries/thread ---------
// 256 thr = 32 q-threads x 8 pair-lanes; 128-query strips, NSLOT=72 balanced
// slots (<=4 key-tiles). Key-PAIRS: lane ki handles pairs ki, ki+8, .. per tile.
// QK dot = 6 v_dot2_f32_f16; PV accumulate for 2 keys = 20 dot2 (c packed fp16).
// kend is a multiple of 16 so a pair never straddles the mask boundary.
__global__ void __launch_bounds__(256,1) k_attn(
    const float* __restrict__ qp_, const unsigned* __restrict__ kph,
    const unsigned* __restrict__ vph,
    float* __restrict__ part)
{
  int tid=threadIdx.x; int qi=tid>>3, ki=tid&7;
  int j=blockIdx.x;
  int bh=j&15;
  int z=NSLOT-1-(j>>4);          // ascending slot id; j ordered heavy-first
  int s=0, bse=0;
  while (bse + ((s+2)>>1) <= z){ bse += (s+2)>>1; s++; }
  int sp = z - bse;
  int c  = (s+2)>>1;
  int ntiles = 2*(s+1);
  int t0 = sp*ntiles/c, t1 = (sp+1)*ntiles/c;
  int q0 = s*128;

  unsigned qh[4][6]; int kendp[4];
  #pragma unroll
  for(int w=0;w<4;w++){
    int q=q0+qi+32*w;
    kendp[w]=((q&~15)+16)>>1;      // pair units
    const float4* p4=(const float4*)(qp_+((size_t)bh*T_+q)*12);
    float4 a=p4[0], b4=p4[1], c4=p4[2];
    qh[w][0]=pkh(a.x,a.y);  qh[w][1]=pkh(a.z,a.w);
    qh[w][2]=pkh(b4.x,b4.y); qh[w][3]=pkh(b4.z,b4.w);
    qh[w][4]=pkh(c4.x,c4.y); qh[w][5]=pkh(c4.z,0.f);
  }

  float acc[4][20];
  #pragma unroll
  for(int w=0;w<4;w++)
    #pragma unroll
    for(int p=0;p<20;p++) acc[w][p]=0.f;

  const uint4* gk=(const uint4*)kph + (size_t)bh*T_*2;    // 2 uint4/key
  const uint4* gv=(const uint4*)vph + (size_t)bh*(T_/2)*5; // 5 uint4/pair
  const unsigned ONE2 = 0x3C003C00u;  // half2(1,1)

  for(int tile=t0; tile<t1; ++tile){
    int p0=(tile*KB)>>1;
    #pragma unroll 2
    for(int it=0; it<4; ++it){
      int pr=p0+ki+it*8;
      uint4 ka0=gk[4*pr],   ka1=gk[4*pr+1];
      uint4 kb0=gk[4*pr+2], kb1=gk[4*pr+3];
      uint4 va=gv[pr*5], vb=gv[pr*5+1], vc=gv[pr*5+2], vd=gv[pr*5+3], ve=gv[pr*5+4];
      #pragma unroll
      for(int w=0;w<4;w++){
        float da = dot2h(qh[w][0],ka0.x, dot2h(qh[w][1],ka0.y,
                   dot2h(qh[w][2],ka0.z, dot2h(qh[w][3],ka0.w,
                   dot2h(qh[w][4],ka1.x, dot2h(qh[w][5],ka1.y, 0.f))))));
        float db = dot2h(qh[w][0],kb0.x, dot2h(qh[w][1],kb0.y,
                   dot2h(qh[w][2],kb0.z, dot2h(qh[w][3],kb0.w,
                   dot2h(qh[w][4],kb1.x, dot2h(qh[w][5],kb1.y, 0.f))))));
        float cA=fminf(__expf(da),60000.f);
        float cB=fminf(__expf(db),60000.f);
        unsigned c2 = pkh(cA,cB);
        c2 = (pr<kendp[w]) ? c2 : 0u;
        acc[w][0] =dot2h(c2,va.x,acc[w][0]);  acc[w][1] =dot2h(c2,va.y,acc[w][1]);
        acc[w][2] =dot2h(c2,va.z,acc[w][2]);  acc[w][3] =dot2h(c2,va.w,acc[w][3]);
        acc[w][4] =dot2h(c2,vb.x,acc[w][4]);  acc[w][5] =dot2h(c2,vb.y,acc[w][5]);
        acc[w][6] =dot2h(c2,vb.z,acc[w][6]);  acc[w][7] =dot2h(c2,vb.w,acc[w][7]);
        acc[w][8] =dot2h(c2,vc.x,acc[w][8]);  acc[w][9] =dot2h(c2,vc.y,acc[w][9]);
        acc[w][10]=dot2h(c2,vc.z,acc[w][10]); acc[w][11]=dot2h(c2,vc.w,acc[w][11]);
        acc[w][12]=dot2h(c2,vd.x,acc[w][12]); acc[w][13]=dot2h(c2,vd.y,acc[w][13]);
        acc[w][14]=dot2h(c2,vd.z,acc[w][14]); acc[w][15]=dot2h(c2,vd.w,acc[w][15]);
        acc[w][16]=dot2h(c2,ONE2,acc[w][16]);
        acc[w][17]=dot2h(c2,ve.x,acc[w][17]); acc[w][18]=dot2h(c2,ve.y,acc[w][18]);
        acc[w][19]=dot2h(c2,ve.z,acc[w][19]);
      }
    }
  }

  // butterfly sum across 8 pair-lanes (pure adds)
  #pragma unroll
  for(int mk=1; mk<8; mk<<=1){
    #pragma unroll
    for(int w=0;w<4;w++)
      #pragma unroll
      for(int p=0;p<20;p++) acc[w][p]+=__shfl_xor(acc[w][p],mk);
  }

  if(ki==0){
    #pragma unroll
    for(int w=0;w<4;w++){
      float* pr = part + ((size_t)(bh*NSLOT + z)*128 + qi + 32*w)*20;
      float4* p4=(float4*)pr;
      p4[0]=make_float4(acc[w][0],acc[w][1],acc[w][2],acc[w][3]);
      p4[1]=make_float4(acc[w][4],acc[w][5],acc[w][6],acc[w][7]);
      p4[2]=make_float4(acc[w][8],acc[w][9],acc[w][10],acc[w][11]);
      p4[3]=make_float4(acc[w][12],acc[w][13],acc[w][14],acc[w][15]);
      p4[4]=make_float4(acc[w][16],acc[w][17],acc[w][18],acc[w][19]);
    }
  }
}

// ---- K_C: combine partials + ao + norm + m1 + GP/join + m2 + out ---------
__global__ void __launch_bounds__(64) k_tail(
    const float* __restrict__ part,
    const float* __restrict__ w_ao_mv, const float* __restrict__ w_ao_s2mv,
    const float* __restrict__ w_ao_m2s, const float* __restrict__ w_ao_s2s,
    const float* __restrict__ b_ao_mv, const float* __restrict__ b_ao_s,
    const float* __restrict__ h_mv, const float* __restrict__ h_s,
    const float* __restrict__ w_m1_mv, const float* __restrict__ w_m1_s2mv,
    const float* __restrict__ w_m1_m2s, const float* __restrict__ w_m1_s2s,
    const float* __restrict__ b_m1_mv, const float* __restrict__ b_m1_s,
    const float* __restrict__ w_m2_mv, const float* __restrict__ w_m2_s2mv,
    const float* __restrict__ b_m2_mv,
    const float* __restrict__ w_out_mv,
    float* __restrict__ out)
{
  __shared__ int   GPI[256]; __shared__ float GPS[256];
  __shared__ int   JNI[256]; __shared__ float JNS[256];
  __shared__ float OS[4*152];
  __shared__ float NS[4*152];
  __shared__ float U[4*264];
  __shared__ float G[4*136];
  __shared__ float GSm[4*24];
  int tid=threadIdx.x, tl=tid>>4, ln=tid&15;
  int o=ln&7, ih=ln>>3;
  int tt=blockIdx.x*4+tl;

  { // build tables (threads 0..31)
    const int mask_of[16]={0,1,2,4,8,3,5,9,6,10,12,7,11,13,14,15};
    const int idx_of[16] ={0,1,2,5,3,6,8,11,4,7,9,12,10,13,14,15};
    if (tid<16){
      int k=tid, km=mask_of[k], slotn=0;
      for(int i=0;i<16;i++){
        int im=mask_of[i], jm=im^km;
        if(im & jm & 1) continue;
        GPI[k*16+slotn]=i|(idx_of[jm]<<4);
        GPS[k*16+slotn]=(float)rsign_d(im,jm);
        slotn++;
      }
      for(;slotn<16;slotn++){ GPI[k*16+slotn]=0; GPS[k*16+slotn]=0.f; }
    } else if (tid<32){
      int p=tid-16, pm=mask_of[p], rest=15&~pm, slotn=0;
      for(int u=0;u<16;u++){
        if(u & ~rest) continue;
        int am=pm|u, bm=pm|(rest&~u);
        float s=(float)( rsign_d(pm,15&~pm)*rsign_d(15&~am,15&~bm)
                        *rsign_d(am,15&~am)*rsign_d(bm,15&~bm) );
        JNI[p*16+slotn]=idx_of[am]|(idx_of[bm]<<4);
        JNS[p*16+slotn]=s;
        slotn++;
      }
      for(;slotn<16;slotn++){ JNI[p*16+slotn]=0; JNS[p*16+slotn]=0.f; }
    }
  }

  // combine attention partials: lane = (head h, comp-half); NSLOT=72 triangular map
  {
    int b=tt>>11, t=tt&(T_-1);
    int strip=t>>7, qil=t&127;
    int h=ln>>1, half=ln&1;
    int nsp=(strip+2)>>1;
    int kk=strip>>1;
    int rbase=(strip&1)? (kk+1)*(kk+1) : kk*kk+kk;
    const float* pb = part + ((size_t)((b*8+h)*NSLOT+rbase)*128 + qil)*20;
    float am[8]={0,0,0,0,0,0,0,0};
    float lv=0.f, s0=0.f, s1=0.f, s2=0.f;
    for(int spp=0; spp<nsp; ++spp){
      const float4* p4=(const float4*)(pb + (size_t)spp*128*20);
      float4 a4=p4[half*2], b4=p4[half*2+1], meta=p4[4];
      am[0]+=a4.x; am[1]+=a4.y; am[2]+=a4.z; am[3]+=a4.w;
      am[4]+=b4.x; am[5]+=b4.y; am[6]+=b4.z; am[7]+=b4.w;
      lv+=meta.x; s0+=meta.y; s1+=meta.z; s2+=meta.w;
    }
    float inv=1.f/lv;
    float* os=&OS[tl*152];
    #pragma unroll
    for(int p=0;p<8;p++) os[h*16+half*8+p]=am[p]*inv;
    if(half==1){ os[128+h*3]=s0*inv; os[128+h*3+1]=s1*inv; os[128+h*3+2]=s2*inv; }
  }
  __syncthreads();

  const float* os=&OS[tl*152];
  float xh[4][16];
  #pragma unroll
  for(int ii=0;ii<4;ii++){
    #pragma unroll
    for(int p=0;p<16;p++) xh[ii][p]=os[(ih*4+ii)*16+p];
  }
  float xs[24];
  #pragma unroll
  for(int jj=0;jj<24;jj++) xs[jj]=os[128+jj];

  // ao: channel o, partial over i-half and j-half
  float y[16];
  #pragma unroll
  for(int p=0;p<16;p++) y[p]=0.f;
  #pragma unroll
  for(int ii=0;ii<4;ii++){
    const float* wi=w_ao_mv+o*72+(ih*4+ii)*9;
    #pragma unroll
    for(int p=0;p<16;p++){
      y[p]+=wi[GRADE[p]]*xh[ii][p];
      if(AUGK[p]>=0) y[p]+=wi[AUGK[p]]*xh[ii][AUGS[p]];
    }
  }
  float e=(ih==0)? b_ao_mv[o] : 0.f;
  for(int j2=ih*12;j2<ih*12+12;j2++) e+=w_ao_s2mv[o*24+j2]*xs[j2];
  y[0]+=e;
  float a3[3];
  #pragma unroll
  for(int jj=0;jj<3;jj++) a3[jj]=(ih==0)? b_ao_s[o*3+jj] : 0.f;
  #pragma unroll
  for(int ii=0;ii<4;ii++){
    #pragma unroll
    for(int jj=0;jj<3;jj++) a3[jj]+=w_ao_m2s[(o*3+jj)*8+(ih*4+ii)]*xh[ii][0];
  }
  for(int j2=ih*12;j2<ih*12+12;j2++){
    #pragma unroll
    for(int jj=0;jj<3;jj++) a3[jj]+=w_ao_s2s[(o*3+jj)*24+j2]*xs[j2];
  }
  #pragma unroll
  for(int p=0;p<16;p++) y[p]+=__shfl_xor(y[p],8);
  #pragma unroll
  for(int jj=0;jj<3;jj++) a3[jj]+=__shfl_xor(a3[jj],8);

  // residual + norms
  float hch[16]; float sqv=0.f;
  { const float4* hg=(const float4*)(h_mv+(size_t)tt*128+o*16);
    #pragma unroll
    for(int r4=0;r4<4;r4++){ float4 v=hg[r4];
      hch[r4*4]=v.x+y[r4*4]; hch[r4*4+1]=v.y+y[r4*4+1];
      hch[r4*4+2]=v.z+y[r4*4+2]; hch[r4*4+3]=v.w+y[r4*4+3]; } }
  #pragma unroll
  for(int p=0;p<16;p++) sqv+=FINNER[p]*hch[p]*hch[p];
  sqv+=__shfl_xor(sqv,1); sqv+=__shfl_xor(sqv,2); sqv+=__shfl_xor(sqv,4);
  float dmv=rsqrtf(sqv*0.125f+0.01f);
  float hs3[3]; float ssq=0.f;
  #pragma unroll
  for(int jj=0;jj<3;jj++){
    float v=h_s[(size_t)tt*24+o*3+jj]+a3[jj];
    hs3[jj]=v; ssq+=v*v;
  }
  ssq+=__shfl_xor(ssq,1); ssq+=__shfl_xor(ssq,2); ssq+=__shfl_xor(ssq,4);
  float dss=rsqrtf(ssq*(1.f/24.f)+0.01f);

  float* nsbuf=&NS[tl*152];
  if(ih==0){
    #pragma unroll
    for(int p=0;p<16;p++) nsbuf[o*16+p]=hch[p]*dmv;
    #pragma unroll
    for(int jj=0;jj<3;jj++) nsbuf[128+o*3+jj]=hs3[jj]*dss;
  }
  __syncthreads();

  // m1: lane = output channel ln=0..15
  float u[16];
  #pragma unroll
  for(int p=0;p<16;p++) u[p]=0.f;
  for(int i=0;i<8;i++){
    float xi[16];
    const float4* xs4=(const float4*)&nsbuf[i*16];
    #pragma unroll
    for(int r4=0;r4<4;r4++){ float4 v=xs4[r4]; xi[r4*4]=v.x; xi[r4*4+1]=v.y; xi[r4*4+2]=v.z; xi[r4*4+3]=v.w; }
    const float* wi=w_m1_mv+ln*72+i*9;
    #pragma unroll
    for(int p=0;p<16;p++){
      u[p]+=wi[GRADE[p]]*xi[p];
      if(AUGK[p]>=0) u[p]+=wi[AUGK[p]]*xi[AUGS[p]];
    }
  }
  float e1=b_m1_mv[ln];
  for(int j2=0;j2<24;j2++) e1+=w_m1_s2mv[ln*24+j2]*nsbuf[128+j2];
  u[0]+=e1;
  { float* uu=&U[tl*264];
    #pragma unroll
    for(int p=0;p<16;p++) uu[ln*16+p]=u[p]; }
  if(ih==0){
    float s3[3];
    #pragma unroll
    for(int jj=0;jj<3;jj++) s3[jj]=b_m1_s[o*3+jj];
    for(int j2=0;j2<24;j2++){
      float s=nsbuf[128+j2];
      #pragma unroll
      for(int jj=0;jj<3;jj++) s3[jj]+=w_m1_s2s[(o*3+jj)*24+j2]*s;
    }
    for(int i=0;i<8;i++){
      float x0=nsbuf[i*16];
      #pragma unroll
      for(int jj=0;jj<3;jj++) s3[jj]+=w_m1_m2s[(o*3+jj)*8+i]*x0;
    }
    #pragma unroll
    for(int jj=0;jj<3;jj++) GSm[tl*24+o*3+jj]=gelu_f(s3[jj]);
  }
  __syncthreads();

  // GP (o<4) / JOIN (o>=4): product o, component half ih
  { const int*   TI=(o<4)? GPI : JNI;
    const float* TS=(o<4)? GPS : JNS;
    const float* uu=&U[tl*264];
    const float* lft=&uu[((o<4)? o : (4+o))*16];
    const float* rgt=&uu[((o<4)? (4+o) : (8+o))*16];
    float* gg=&G[tl*136];
    #pragma unroll
    for(int kk=0;kk<8;kk++){
      int k=ih*8+kk;
      float accv=0.f;
      #pragma unroll
      for(int e2=0;e2<16;e2++){
        int ij=TI[k*16+e2]; float sg=TS[k*16+e2];
        accv += sg * lft[ij&15] * rgt[ij>>4];
      }
      gg[o*16+k]=accv;
    }
  }
  __syncthreads();
  if(ih==0){
    float* gg=&G[tl*136];
    float gt=gelu_f(gg[o*16]);
    #pragma unroll
    for(int p=0;p<16;p++) gg[o*16+p]*=gt;
  }
  __syncthreads();

  // m2: channel o, i-half + j-half, combine
  float y2[16];
  #pragma unroll
  for(int p=0;p<16;p++) y2[p]=0.f;
  #pragma unroll
  for(int ii=0;ii<4;ii++){
    float xi[16];
    const float4* gi=(const float4*)&G[tl*136+(ih*4+ii)*16];
    #pragma unroll
    for(int r4=0;r4<4;r4++){ float4 v=gi[r4]; xi[r4*4]=v.x; xi[r4*4+1]=v.y; xi[r4*4+2]=v.z; xi[r4*4+3]=v.w; }
    const float* wi=w_m2_mv+o*72+(ih*4+ii)*9;
    #pragma unroll
    for(int p=0;p<16;p++){
      y2[p]+=wi[GRADE[p]]*xi[p];
      if(AUGK[p]>=0) y2[p]+=wi[AUGK[p]]*xi[AUGS[p]];
    }
  }
  float e2=(ih==0)? b_m2_mv[o] : 0.f;
  for(int j2=ih*12;j2<ih*12+12;j2++) e2+=w_m2_s2mv[o*24+j2]*GSm[tl*24+j2];
  y2[0]+=e2;
  #pragma unroll
  for(int p=0;p<16;p++) y2[p]+=__shfl_xor(y2[p],8);

  float hf[16];
  #pragma unroll
  for(int p=0;p<16;p++) hf[p]=hch[p]+y2[p];

  const float* wout=w_out_mv+o*9;
  float c5 =wout[2]*hf[5] +wout[6]*hf[2];
  float c6 =wout[2]*hf[6] +wout[6]*hf[3];
  float c7 =wout[2]*hf[7] +wout[6]*hf[4];
  float c11=wout[3]*hf[11]+wout[7]*hf[8];
  float c12=wout[3]*hf[12]+wout[7]*hf[9];
  float c13=wout[3]*hf[13]+wout[7]*hf[10];
  float c14=wout[3]*hf[14];
  #pragma unroll
  for(int mk=1; mk<8; mk<<=1){
    c5+=__shfl_xor(c5,mk); c6+=__shfl_xor(c6,mk); c7+=__shfl_xor(c7,mk);
    c11+=__shfl_xor(c11,mk); c12+=__shfl_xor(c12,mk);
    c13+=__shfl_xor(c13,mk); c14+=__shfl_xor(c14,mk);
  }
  if(ln==0){
    float dd=c14;
    dd=(fabsf(dd)>0.001f)? dd : (dd>=0.f? 0.001f : -0.001f);
    float* op=out+(size_t)tt*6;
    op[0]=-c13/dd; op[1]=c12/dd; op[2]=-c11/dd;
    op[3]=2.f*c5; op[4]=2.f*c6; op[5]=2.f*c7;
  }
}

extern "C" void kernel_launch(void* const* d_in, const int* in_sizes, int n_in,
                              void* d_out, int out_size, void* d_ws, size_t ws_size,
                              hipStream_t stream)
{
  (void)in_sizes; (void)n_in; (void)out_size; (void)ws_size;
  const float* x         =(const float*)d_in[0];
  const float* w_in_mv   =(const float*)d_in[1];
  const float* b_in_mv   =(const float*)d_in[2];
  const float* w_in_m2s  =(const float*)d_in[3];
  const float* b_in_s    =(const float*)d_in[4];
  const float* w_qkv_mv  =(const float*)d_in[5];
  const float* w_qkv_s2mv=(const float*)d_in[6];
  const float* w_qkv_m2s =(const float*)d_in[7];
  const float* w_qkv_s2s =(const float*)d_in[8];
  const float* w_ao_mv   =(const float*)d_in[9];
  const float* w_ao_s2mv =(const float*)d_in[10];
  const float* w_ao_m2s  =(const float*)d_in[11];
  const float* w_ao_s2s  =(const float*)d_in[12];
  const float* b_ao_mv   =(const float*)d_in[13];
  const float* b_ao_s    =(const float*)d_in[14];
  const float* w_m1_mv   =(const float*)d_in[15];
  const float* w_m1_s2mv =(const float*)d_in[16];
  const float* w_m1_m2s  =(const float*)d_in[17];
  const float* w_m1_s2s  =(const float*)d_in[18];
  const float* b_m1_mv   =(const float*)d_in[19];
  const float* b_m1_s    =(const float*)d_in[20];
  const float* w_m2_mv   =(const float*)d_in[21];
  const float* w_m2_s2mv =(const float*)d_in[22];
  const float* b_m2_mv   =(const float*)d_in[25];
  const float* w_out_mv  =(const float*)d_in[27];
  float* outp=(float*)d_out;

  float* ws=(float*)d_ws;
  size_t off=0;
  float* h_mv = ws+off; off+=(size_t)BTOK*128;
  float* h_s  = ws+off; off+=(size_t)BTOK*24;
  float* qpk  = ws+off; off+=(size_t)16*T_*12;
  unsigned* kph = (unsigned*)(ws+off); off+=(size_t)16*T_*8;       // 16 halfs/key
  unsigned* vph = (unsigned*)(ws+off); off+=(size_t)16*(T_/2)*20;  // 20 half2/pair
  float* part = ws+off; off+=(size_t)16*NSLOT*128*20;

  k_in  <<<BTOK/4,64,0,stream>>>(x,w_in_mv,b_in_mv,w_in_m2s,b_in_s,
                                 w_qkv_mv,w_qkv_s2mv,w_qkv_m2s,w_qkv_s2s,
                                 h_mv,h_s,qpk,kph,vph);
  k_attn<<<16*NSLOT,256,0,stream>>>(qpk,kph,vph,part);
  k_tail<<<BTOK/4,64,0,stream>>>(part,
                                 w_ao_mv,w_ao_s2mv,w_ao_m2s,w_ao_s2s,b_ao_mv,b_ao_s,
                                 h_mv,h_s,
                                 w_m1_mv,w_m1_s2mv,w_m1_m2s,w_m1_s2s,b_m1_mv,b_m1_s,
                                 w_m2_mv,w_m2_s2mv,b_m2_mv,w_out_mv,outp);
}

// Round 11
// 88.952 us; speedup vs baseline: 1.3793x; 1.0183x over previous
//
#include <hip/hip_runtime.h>
#include <math.h>

#define T_    2048
#define BTOK  4096   // B * T
#define KB    64
#define NSLOT 72     // sum over 16 strips of ceil((s+1)/2)

namespace {
constexpr int GRADE[16] = {0,1,1,1,1,2,2,2,2,2,2,3,3,3,3,4};
constexpr int AUGK[16]  = {-1,5,-1,-1,-1,6,6,6,-1,-1,-1,7,7,7,-1,8};
constexpr int AUGS[16]  = { 0,0, 0, 0, 0,2,3,4, 0, 0, 0,8,9,10,0,14};
constexpr float FINNER[16] = {1.f,0.f,1.f,1.f,1.f,0.f,0.f,0.f,1.f,1.f,1.f,0.f,0.f,0.f,1.f,0.f};
}

typedef _Float16 h2_t __attribute__((ext_vector_type(2)));

__device__ __forceinline__ unsigned pkh(float a, float b){
  return __builtin_bit_cast(unsigned, __builtin_amdgcn_cvt_pkrtz(a,b));
}
__device__ __forceinline__ float dot2h(unsigned a, unsigned b, float c){
#if __has_builtin(__builtin_amdgcn_fdot2)
  return __builtin_amdgcn_fdot2(__builtin_bit_cast(h2_t,a), __builtin_bit_cast(h2_t,b), c, false);
#else
  float r;
  asm("v_dot2_f32_f16 %0, %1, %2, %3" : "=v"(r) : "v"(a), "v"(b), "v"(c));
  return r;
#endif
}

__device__ __forceinline__ float gelu_f(float v){
  return 0.5f*v*(1.f + erff(v*0.70710678118654752f));
}

__device__ __forceinline__ int rsign_d(int a, int b){
  int s=0; a>>=1; while(a){ s += __popc(a&b); a>>=1; } return (s&1) ? -1 : 1;
}

// ---- K_A: embed + in-linear + norm + QKV projections + fp16 pack ---------
// 64 threads = 2 tokens x 32 lanes (8 channels x 4 input-quarters).
// 2048 waves = 2/SIMD (was 1/SIMD at 16 lanes/token).
__global__ void __launch_bounds__(64) k_in(
    const float* __restrict__ x,
    const float* __restrict__ w_in_mv, const float* __restrict__ b_in_mv,
    const float* __restrict__ w_in_m2s, const float* __restrict__ b_in_s,
    const float* __restrict__ w_mv, const float* __restrict__ w_s2mv,
    const float* __restrict__ w_m2s, const float* __restrict__ w_s2s,
    float* __restrict__ h_mv, float* __restrict__ h_s,
    float* __restrict__ qp_, unsigned* __restrict__ kph, unsigned* __restrict__ vph)
{
  __shared__ float NS[2*152];   // per token: n_mv 128 + n_s 24
  int tid=threadIdx.x, tl=tid>>5, ln=tid&31;
  int o=ln&7, iq=ln>>3;          // iq 0..3
  int tt=blockIdx.x*2+tl;
  int b=tt>>11, t=tt&(T_-1);
  const float* xp = x+(size_t)tt*6;
  float mv[16];
  #pragma unroll
  for(int p=0;p<16;p++) mv[p]=0.f;
  mv[0]=1.f; mv[14]=1.f;
  mv[13]=-xp[0]; mv[12]=xp[1]; mv[11]=-xp[2];
  mv[5]=0.5f*xp[3]; mv[6]=0.5f*xp[4]; mv[7]=0.5f*xp[5];

  const float* wo=w_in_mv+o*9;
  float h[16]; float sq=0.f;
  #pragma unroll
  for(int p=0;p<16;p++){
    float v=wo[GRADE[p]]*mv[p];
    if(AUGK[p]>=0) v+=wo[AUGK[p]]*mv[AUGS[p]];
    if(p==0) v+=b_in_mv[o];
    h[p]=v; sq+=FINNER[p]*v*v;
  }
  sq+=__shfl_xor(sq,1); sq+=__shfl_xor(sq,2); sq+=__shfl_xor(sq,4);
  float dmv=rsqrtf(sq*0.125f+0.01f);
  float hs[3]; float ssq=0.f;
  #pragma unroll
  for(int jj=0;jj<3;jj++){ float v=w_in_m2s[o*3+jj]+b_in_s[o*3+jj]; hs[jj]=v; ssq+=v*v; }
  ssq+=__shfl_xor(ssq,1); ssq+=__shfl_xor(ssq,2); ssq+=__shfl_xor(ssq,4);
  float dss=rsqrtf(ssq*(1.f/24.f)+0.01f);

  float* ns=&NS[tl*152];
  if(iq==0){
    float4* hg=(float4*)(h_mv+(size_t)tt*128+o*16);
    hg[0]=make_float4(h[0],h[1],h[2],h[3]);
    hg[1]=make_float4(h[4],h[5],h[6],h[7]);
    hg[2]=make_float4(h[8],h[9],h[10],h[11]);
    hg[3]=make_float4(h[12],h[13],h[14],h[15]);
    #pragma unroll
    for(int jj=0;jj<3;jj++) h_s[(size_t)tt*24+o*3+jj]=hs[jj];
    #pragma unroll
    for(int p=0;p<16;p++) ns[o*16+p]=h[p]*dmv;
    #pragma unroll
    for(int jj=0;jj<3;jj++) ns[128+o*3+jj]=hs[jj]*dss;
  }
  __syncthreads();

  // projections: lane (o,iq) does input channels iq*2..+1, scalar j iq*6..+5
  float yq[16],yk[16],yv[16];
  #pragma unroll
  for(int p=0;p<16;p++){ yq[p]=0.f; yk[p]=0.f; yv[p]=0.f; }
  float nx0p[2];
  const float* wq=w_mv+o*72;
  #pragma unroll
  for(int ii=0;ii<2;ii++){
    int i=iq*2+ii;
    float xi[16];
    const float4* xs4=(const float4*)&ns[i*16];
    #pragma unroll
    for(int r4=0;r4<4;r4++){ float4 v=xs4[r4]; xi[r4*4]=v.x; xi[r4*4+1]=v.y; xi[r4*4+2]=v.z; xi[r4*4+3]=v.w; }
    nx0p[ii]=xi[0];
    const float* aq=wq+i*9; const float* ak=aq+576; const float* av=aq+1152;
    #pragma unroll
    for(int p=0;p<16;p++){
      float bb=xi[p];
      yq[p]+=aq[GRADE[p]]*bb; yk[p]+=ak[GRADE[p]]*bb; yv[p]+=av[GRADE[p]]*bb;
      if(AUGK[p]>=0){
        float au=xi[AUGS[p]];
        yq[p]+=aq[AUGK[p]]*au; yk[p]+=ak[AUGK[p]]*au; yv[p]+=av[AUGK[p]]*au;
      }
    }
  }
  float eq=0.f,ek=0.f,ev=0.f;
  float sq3[3]={0,0,0}, sk3[3]={0,0,0}, sv3[3]={0,0,0};
  for(int j=iq*6;j<iq*6+6;j++){
    float s=ns[128+j];
    eq+=w_s2mv[o*24+j]*s; ek+=w_s2mv[192+o*24+j]*s; ev+=w_s2mv[384+o*24+j]*s;
    #pragma unroll
    for(int jj=0;jj<3;jj++){
      int d=o*3+jj;
      sq3[jj]+=w_s2s[d*24+j]*s;
      sk3[jj]+=w_s2s[576+d*24+j]*s;
      sv3[jj]+=w_s2s[1152+d*24+j]*s;
    }
  }
  #pragma unroll
  for(int ii=0;ii<2;ii++){
    int i=iq*2+ii;
    #pragma unroll
    for(int jj=0;jj<3;jj++){
      int d=o*3+jj;
      sq3[jj]+=w_m2s[d*8+i]*nx0p[ii];
      sk3[jj]+=w_m2s[192+d*8+i]*nx0p[ii];
      sv3[jj]+=w_m2s[384+d*8+i]*nx0p[ii];
    }
  }
  yq[0]+=eq; yk[0]+=ek; yv[0]+=ev;
  #pragma unroll
  for(int p=0;p<16;p++){
    yq[p]+=__shfl_xor(yq[p],8);  yq[p]+=__shfl_xor(yq[p],16);
    yk[p]+=__shfl_xor(yk[p],8);  yk[p]+=__shfl_xor(yk[p],16);
    yv[p]+=__shfl_xor(yv[p],8);  yv[p]+=__shfl_xor(yv[p],16);
  }
  #pragma unroll
  for(int jj=0;jj<3;jj++){
    sq3[jj]+=__shfl_xor(sq3[jj],8); sq3[jj]+=__shfl_xor(sq3[jj],16);
    sk3[jj]+=__shfl_xor(sk3[jj],8); sk3[jj]+=__shfl_xor(sk3[jj],16);
    sv3[jj]+=__shfl_xor(sv3[jj],8); sv3[jj]+=__shfl_xor(sv3[jj],16);
  }

  const float scale = 0.3015113445777636f;  // 1/sqrt(11)
  size_t rb=((size_t)(b*8+o)*T_+t);
  if(iq==0){
    float4* qr=(float4*)(qp_+rb*12);
    qr[0]=make_float4(yq[0]*scale, yq[2]*scale, yq[3]*scale, yq[4]*scale);
    qr[1]=make_float4(yq[8]*scale, yq[9]*scale, yq[10]*scale, yq[14]*scale);
    qr[2]=make_float4(sq3[0]*scale, sq3[1]*scale, sq3[2]*scale, 0.f);
  } else if(iq==1){
    // K fp16 pack: pairs (k0,k2)(k3,k4)(k8,k9)(k10,k14)(s0,s1)(s2,0)
    uint4 k0p, k1p;
    k0p.x=pkh(yk[0],yk[2]);  k0p.y=pkh(yk[3],yk[4]);
    k0p.z=pkh(yk[8],yk[9]);  k0p.w=pkh(yk[10],yk[14]);
    k1p.x=pkh(sk3[0],sk3[1]); k1p.y=pkh(sk3[2],0.f); k1p.z=0u; k1p.w=0u;
    uint4* kr=(uint4*)kph + rb*2;
    kr[0]=k0p; kr[1]=k1p;
  }
  // V fp16 interleave by key-pair via cross-token shfl (lane distance 32)
  {
    size_t vpb = ((size_t)(b*8+o)*(T_/2) + (t>>1))*20;
    bool even = (tl==0);
    if(iq==2){
      #pragma unroll
      for(int c=0;c<10;c++){
        float other=__shfl_xor(yv[c],32);
        if(even) vph[vpb+c]=pkh(yv[c],other);
      }
    } else if(iq==3){
      #pragma unroll
      for(int c=10;c<16;c++){
        float other=__shfl_xor(yv[c],32);
        if(even) vph[vpb+c]=pkh(yv[c],other);
      }
      #pragma unroll
      for(int jj=0;jj<3;jj++){
        float other=__shfl_xor(sv3[jj],32);
        if(even) vph[vpb+16+jj]=pkh(sv3[jj],other);
      }
      if(even) vph[vpb+19]=0u;
    }
  }
}

// ---- K_B: attention, no-max softmax, fp16 dot2, 4 queries/thread ---------
__global__ void __launch_bounds__(256,1) k_attn(
    const float* __restrict__ qp_, const unsigned* __restrict__ kph,
    const unsigned* __restrict__ vph,
    float* __restrict__ part)
{
  int tid=threadIdx.x; int qi=tid>>3, ki=tid&7;
  int j=blockIdx.x;
  int bh=j&15;
  int z=NSLOT-1-(j>>4);
  int s=0, bse=0;
  while (bse + ((s+2)>>1) <= z){ bse += (s+2)>>1; s++; }
  int sp = z - bse;
  int c  = (s+2)>>1;
  int ntiles = 2*(s+1);
  int t0 = sp*ntiles/c, t1 = (sp+1)*ntiles/c;
  int q0 = s*128;

  unsigned qh[4][6]; int kendp[4];
  #pragma unroll
  for(int w=0;w<4;w++){
    int q=q0+qi+32*w;
    kendp[w]=((q&~15)+16)>>1;
    const float4* p4=(const float4*)(qp_+((size_t)bh*T_+q)*12);
    float4 a=p4[0], b4=p4[1], c4=p4[2];
    qh[w][0]=pkh(a.x,a.y);  qh[w][1]=pkh(a.z,a.w);
    qh[w][2]=pkh(b4.x,b4.y); qh[w][3]=pkh(b4.z,b4.w);
    qh[w][4]=pkh(c4.x,c4.y); qh[w][5]=pkh(c4.z,0.f);
  }

  float acc[4][20];
  #pragma unroll
  for(int w=0;w<4;w++)
    #pragma unroll
    for(int p=0;p<20;p++) acc[w][p]=0.f;

  const uint4* gk=(const uint4*)kph + (size_t)bh*T_*2;
  const uint4* gv=(const uint4*)vph + (size_t)bh*(T_/2)*5;
  const unsigned ONE2 = 0x3C003C00u;

  for(int tile=t0; tile<t1; ++tile){
    int p0=(tile*KB)>>1;
    #pragma unroll
    for(int it=0; it<4; ++it){
      int pr=p0+ki+it*8;
      uint4 ka0=gk[4*pr],   ka1=gk[4*pr+1];
      uint4 kb0=gk[4*pr+2], kb1=gk[4*pr+3];
      uint4 va=gv[pr*5], vb=gv[pr*5+1], vc=gv[pr*5+2], vd=gv[pr*5+3], ve=gv[pr*5+4];
      #pragma unroll
      for(int w=0;w<4;w++){
        float da = dot2h(qh[w][0],ka0.x, dot2h(qh[w][1],ka0.y,
                   dot2h(qh[w][2],ka0.z, dot2h(qh[w][3],ka0.w,
                   dot2h(qh[w][4],ka1.x, dot2h(qh[w][5],ka1.y, 0.f))))));
        float db = dot2h(qh[w][0],kb0.x, dot2h(qh[w][1],kb0.y,
                   dot2h(qh[w][2],kb0.z, dot2h(qh[w][3],kb0.w,
                   dot2h(qh[w][4],kb1.x, dot2h(qh[w][5],kb1.y, 0.f))))));
        float cA=fminf(__expf(da),60000.f);
        float cB=fminf(__expf(db),60000.f);
        unsigned c2 = pkh(cA,cB);
        c2 = (pr<kendp[w]) ? c2 : 0u;
        acc[w][0] =dot2h(c2,va.x,acc[w][0]);  acc[w][1] =dot2h(c2,va.y,acc[w][1]);
        acc[w][2] =dot2h(c2,va.z,acc[w][2]);  acc[w][3] =dot2h(c2,va.w,acc[w][3]);
        acc[w][4] =dot2h(c2,vb.x,acc[w][4]);  acc[w][5] =dot2h(c2,vb.y,acc[w][5]);
        acc[w][6] =dot2h(c2,vb.z,acc[w][6]);  acc[w][7] =dot2h(c2,vb.w,acc[w][7]);
        acc[w][8] =dot2h(c2,vc.x,acc[w][8]);  acc[w][9] =dot2h(c2,vc.y,acc[w][9]);
        acc[w][10]=dot2h(c2,vc.z,acc[w][10]); acc[w][11]=dot2h(c2,vc.w,acc[w][11]);
        acc[w][12]=dot2h(c2,vd.x,acc[w][12]); acc[w][13]=dot2h(c2,vd.y,acc[w][13]);
        acc[w][14]=dot2h(c2,vd.z,acc[w][14]); acc[w][15]=dot2h(c2,vd.w,acc[w][15]);
        acc[w][16]=dot2h(c2,ONE2,acc[w][16]);
        acc[w][17]=dot2h(c2,ve.x,acc[w][17]); acc[w][18]=dot2h(c2,ve.y,acc[w][18]);
        acc[w][19]=dot2h(c2,ve.z,acc[w][19]);
      }
    }
  }

  #pragma unroll
  for(int mk=1; mk<8; mk<<=1){
    #pragma unroll
    for(int w=0;w<4;w++)
      #pragma unroll
      for(int p=0;p<20;p++) acc[w][p]+=__shfl_xor(acc[w][p],mk);
  }

  if(ki==0){
    #pragma unroll
    for(int w=0;w<4;w++){
      float* pr = part + ((size_t)(bh*NSLOT + z)*128 + qi + 32*w)*20;
      float4* p4=(float4*)pr;
      p4[0]=make_float4(acc[w][0],acc[w][1],acc[w][2],acc[w][3]);
      p4[1]=make_float4(acc[w][4],acc[w][5],acc[w][6],acc[w][7]);
      p4[2]=make_float4(acc[w][8],acc[w][9],acc[w][10],acc[w][11]);
      p4[3]=make_float4(acc[w][12],acc[w][13],acc[w][14],acc[w][15]);
      p4[4]=make_float4(acc[w][16],acc[w][17],acc[w][18],acc[w][19]);
    }
  }
}

// ---- K_C: combine partials + ao + norm + m1 + GP/join + m2 + out ---------
// 64 threads = 2 tokens x 32 lanes (8 channels x 4 quarters). 2048 waves.
__global__ void __launch_bounds__(64) k_tail(
    const float* __restrict__ part,
    const float* __restrict__ w_ao_mv, const float* __restrict__ w_ao_s2mv,
    const float* __restrict__ w_ao_m2s, const float* __restrict__ w_ao_s2s,
    const float* __restrict__ b_ao_mv, const float* __restrict__ b_ao_s,
    const float* __restrict__ h_mv, const float* __restrict__ h_s,
    const float* __restrict__ w_m1_mv, const float* __restrict__ w_m1_s2mv,
    const float* __restrict__ w_m1_m2s, const float* __restrict__ w_m1_s2s,
    const float* __restrict__ b_m1_mv, const float* __restrict__ b_m1_s,
    const float* __restrict__ w_m2_mv, const float* __restrict__ w_m2_s2mv,
    const float* __restrict__ b_m2_mv,
    const float* __restrict__ w_out_mv,
    float* __restrict__ out)
{
  __shared__ int   GPI[256]; __shared__ float GPS[256];
  __shared__ int   JNI[256]; __shared__ float JNS[256];
  __shared__ float OS[2*152];
  __shared__ float NS[2*152];
  __shared__ float U[2*264];
  __shared__ float G[2*136];
  __shared__ float GSm[2*24];
  int tid=threadIdx.x, tl=tid>>5, ln=tid&31;
  int o=ln&7, iq=ln>>3;          // iq 0..3
  int tt=blockIdx.x*2+tl;

  { // build tables (threads 0..31)
    const int mask_of[16]={0,1,2,4,8,3,5,9,6,10,12,7,11,13,14,15};
    const int idx_of[16] ={0,1,2,5,3,6,8,11,4,7,9,12,10,13,14,15};
    if (tid<16){
      int k=tid, km=mask_of[k], slotn=0;
      for(int i=0;i<16;i++){
        int im=mask_of[i], jm=im^km;
        if(im & jm & 1) continue;
        GPI[k*16+slotn]=i|(idx_of[jm]<<4);
        GPS[k*16+slotn]=(float)rsign_d(im,jm);
        slotn++;
      }
      for(;slotn<16;slotn++){ GPI[k*16+slotn]=0; GPS[k*16+slotn]=0.f; }
    } else if (tid<32){
      int p=tid-16, pm=mask_of[p], rest=15&~pm, slotn=0;
      for(int u=0;u<16;u++){
        if(u & ~rest) continue;
        int am=pm|u, bm=pm|(rest&~u);
        float s=(float)( rsign_d(pm,15&~pm)*rsign_d(15&~am,15&~bm)
                        *rsign_d(am,15&~am)*rsign_d(bm,15&~bm) );
        JNI[p*16+slotn]=idx_of[am]|(idx_of[bm]<<4);
        JNS[p*16+slotn]=s;
        slotn++;
      }
      for(;slotn<16;slotn++){ JNI[p*16+slotn]=0; JNS[p*16+slotn]=0.f; }
    }
  }

  // combine attention partials: lane = (head h=ln>>2, quarter qr=ln&3)
  {
    int b=tt>>11, t=tt&(T_-1);
    int strip=t>>7, qil=t&127;
    int h=ln>>2, qr=ln&3;
    int nsp=(strip+2)>>1;
    int kk=strip>>1;
    int rbase=(strip&1)? (kk+1)*(kk+1) : kk*kk+kk;
    const float* pb = part + ((size_t)((b*8+h)*NSLOT+rbase)*128 + qil)*20;
    float am[4]={0,0,0,0};
    float lv=0.f, s0=0.f, s1=0.f, s2=0.f;
    for(int spp=0; spp<nsp; ++spp){
      const float4* p4=(const float4*)(pb + (size_t)spp*128*20);
      float4 a4=p4[qr];
      am[0]+=a4.x; am[1]+=a4.y; am[2]+=a4.z; am[3]+=a4.w;
      if(qr==0){ float4 meta=p4[4]; lv+=meta.x; s0+=meta.y; s1+=meta.z; s2+=meta.w; }
    }
    float inv = (qr==0)? 1.f/lv : 0.f;
    inv = __shfl(inv, (tid & ~3));
    float* os=&OS[tl*152];
    #pragma unroll
    for(int p=0;p<4;p++) os[h*16+qr*4+p]=am[p]*inv;
    if(qr==0){ os[128+h*3]=s0*inv; os[128+h*3+1]=s1*inv; os[128+h*3+2]=s2*inv; }
  }
  __syncthreads();

  const float* os=&OS[tl*152];
  float xh[2][16];
  #pragma unroll
  for(int ii=0;ii<2;ii++){
    #pragma unroll
    for(int p=0;p<16;p++) xh[ii][p]=os[(iq*2+ii)*16+p];
  }
  float xs[24];
  #pragma unroll
  for(int jj=0;jj<24;jj++) xs[jj]=os[128+jj];

  // ao: channel o, input quarter iq
  float y[16];
  #pragma unroll
  for(int p=0;p<16;p++) y[p]=0.f;
  #pragma unroll
  for(int ii=0;ii<2;ii++){
    const float* wi=w_ao_mv+o*72+(iq*2+ii)*9;
    #pragma unroll
    for(int p=0;p<16;p++){
      y[p]+=wi[GRADE[p]]*xh[ii][p];
      if(AUGK[p]>=0) y[p]+=wi[AUGK[p]]*xh[ii][AUGS[p]];
    }
  }
  float e=(iq==0)? b_ao_mv[o] : 0.f;
  for(int j2=iq*6;j2<iq*6+6;j2++) e+=w_ao_s2mv[o*24+j2]*xs[j2];
  y[0]+=e;
  float a3[3];
  #pragma unroll
  for(int jj=0;jj<3;jj++) a3[jj]=(iq==0)? b_ao_s[o*3+jj] : 0.f;
  #pragma unroll
  for(int ii=0;ii<2;ii++){
    #pragma unroll
    for(int jj=0;jj<3;jj++) a3[jj]+=w_ao_m2s[(o*3+jj)*8+(iq*2+ii)]*xh[ii][0];
  }
  for(int j2=iq*6;j2<iq*6+6;j2++){
    #pragma unroll
    for(int jj=0;jj<3;jj++) a3[jj]+=w_ao_s2s[(o*3+jj)*24+j2]*xs[j2];
  }
  #pragma unroll
  for(int p=0;p<16;p++){ y[p]+=__shfl_xor(y[p],8); y[p]+=__shfl_xor(y[p],16); }
  #pragma unroll
  for(int jj=0;jj<3;jj++){ a3[jj]+=__shfl_xor(a3[jj],8); a3[jj]+=__shfl_xor(a3[jj],16); }

  // residual + norms (dup across iq; reduce over o via xor 1,2,4)
  float hch[16]; float sqv=0.f;
  { const float4* hg=(const float4*)(h_mv+(size_t)tt*128+o*16);
    #pragma unroll
    for(int r4=0;r4<4;r4++){ float4 v=hg[r4];
      hch[r4*4]=v.x+y[r4*4]; hch[r4*4+1]=v.y+y[r4*4+1];
      hch[r4*4+2]=v.z+y[r4*4+2]; hch[r4*4+3]=v.w+y[r4*4+3]; } }
  #pragma unroll
  for(int p=0;p<16;p++) sqv+=FINNER[p]*hch[p]*hch[p];
  sqv+=__shfl_xor(sqv,1); sqv+=__shfl_xor(sqv,2); sqv+=__shfl_xor(sqv,4);
  float dmv=rsqrtf(sqv*0.125f+0.01f);
  float hs3[3]; float ssq=0.f;
  #pragma unroll
  for(int jj=0;jj<3;jj++){
    float v=h_s[(size_t)tt*24+o*3+jj]+a3[jj];
    hs3[jj]=v; ssq+=v*v;
  }
  ssq+=__shfl_xor(ssq,1); ssq+=__shfl_xor(ssq,2); ssq+=__shfl_xor(ssq,4);
  float dss=rsqrtf(ssq*(1.f/24.f)+0.01f);

  float* nsbuf=&NS[tl*152];
  if(iq==0){
    #pragma unroll
    for(int p=0;p<16;p++) nsbuf[o*16+p]=hch[p]*dmv;
    #pragma unroll
    for(int jj=0;jj<3;jj++) nsbuf[128+o*3+jj]=hs3[jj]*dss;
  }
  __syncthreads();

  // m1: lane = (output channel ln16, input half mh)
  {
    int ln16=ln&15, mh=ln>>4;
    float u[16];
    #pragma unroll
    for(int p=0;p<16;p++) u[p]=0.f;
    for(int i=mh*4;i<mh*4+4;i++){
      float xi[16];
      const float4* xs4=(const float4*)&nsbuf[i*16];
      #pragma unroll
      for(int r4=0;r4<4;r4++){ float4 v=xs4[r4]; xi[r4*4]=v.x; xi[r4*4+1]=v.y; xi[r4*4+2]=v.z; xi[r4*4+3]=v.w; }
      const float* wi=w_m1_mv+ln16*72+i*9;
      #pragma unroll
      for(int p=0;p<16;p++){
        u[p]+=wi[GRADE[p]]*xi[p];
        if(AUGK[p]>=0) u[p]+=wi[AUGK[p]]*xi[AUGS[p]];
      }
    }
    float e1=(mh==0)? b_m1_mv[ln16] : 0.f;
    for(int j2=mh*12;j2<mh*12+12;j2++) e1+=w_m1_s2mv[ln16*24+j2]*nsbuf[128+j2];
    u[0]+=e1;
    #pragma unroll
    for(int p=0;p<16;p++) u[p]+=__shfl_xor(u[p],16);
    if(mh==0){
      float* uu=&U[tl*264];
      #pragma unroll
      for(int p=0;p<16;p++) uu[ln16*16+p]=u[p];
    }
  }
  if(ln<8){  // m1 scalar path, o=ln
    float s3[3];
    #pragma unroll
    for(int jj=0;jj<3;jj++) s3[jj]=b_m1_s[o*3+jj];
    for(int j2=0;j2<24;j2++){
      float s=nsbuf[128+j2];
      #pragma unroll
      for(int jj=0;jj<3;jj++) s3[jj]+=w_m1_s2s[(o*3+jj)*24+j2]*s;
    }
    for(int i=0;i<8;i++){
      float x0=nsbuf[i*16];
      #pragma unroll
      for(int jj=0;jj<3;jj++) s3[jj]+=w_m1_m2s[(o*3+jj)*8+i]*x0;
    }
    #pragma unroll
    for(int jj=0;jj<3;jj++) GSm[tl*24+o*3+jj]=gelu_f(s3[jj]);
  }
  __syncthreads();

  // GP (o<4) / JOIN (o>=4): product o, component quarter iq; gate via shfl
  {
    const int*   TI=(o<4)? GPI : JNI;
    const float* TS=(o<4)? GPS : JNS;
    const float* uu=&U[tl*264];
    const float* lft=&uu[((o<4)? o : (4+o))*16];
    const float* rgt=&uu[((o<4)? (4+o) : (8+o))*16];
    float g[4];
    #pragma unroll
    for(int kk=0;kk<4;kk++){
      int k=iq*4+kk;
      float accv=0.f;
      #pragma unroll
      for(int e2=0;e2<16;e2++){
        int ij=TI[k*16+e2]; float sg=TS[k*16+e2];
        accv += sg * lft[ij&15] * rgt[ij>>4];
      }
      g[kk]=accv;
    }
    float g0 = __shfl(g[0], (tid & ~0x18));   // comp0 lives on iq==0 lane
    float gt = gelu_f(g0);
    float* gg=&G[tl*136];
    #pragma unroll
    for(int kk=0;kk<4;kk++) gg[o*16+iq*4+kk]=g[kk]*gt;
  }
  __syncthreads();

  // m2: channel o, input quarter iq
  float y2[16];
  #pragma unroll
  for(int p=0;p<16;p++) y2[p]=0.f;
  #pragma unroll
  for(int ii=0;ii<2;ii++){
    float xi[16];
    const float4* gi=(const float4*)&G[tl*136+(iq*2+ii)*16];
    #pragma unroll
    for(int r4=0;r4<4;r4++){ float4 v=gi[r4]; xi[r4*4]=v.x; xi[r4*4+1]=v.y; xi[r4*4+2]=v.z; xi[r4*4+3]=v.w; }
    const float* wi=w_m2_mv+o*72+(iq*2+ii)*9;
    #pragma unroll
    for(int p=0;p<16;p++){
      y2[p]+=wi[GRADE[p]]*xi[p];
      if(AUGK[p]>=0) y2[p]+=wi[AUGK[p]]*xi[AUGS[p]];
    }
  }
  float e2=(iq==0)? b_m2_mv[o] : 0.f;
  for(int j2=iq*6;j2<iq*6+6;j2++) e2+=w_m2_s2mv[o*24+j2]*GSm[tl*24+j2];
  y2[0]+=e2;
  #pragma unroll
  for(int p=0;p<16;p++){ y2[p]+=__shfl_xor(y2[p],8); y2[p]+=__shfl_xor(y2[p],16); }

  float hf[16];
  #pragma unroll
  for(int p=0;p<16;p++) hf[p]=hch[p]+y2[p];

  const float* wout=w_out_mv+o*9;
  float c5 =wout[2]*hf[5] +wout[6]*hf[2];
  float c6 =wout[2]*hf[6] +wout[6]*hf[3];
  float c7 =wout[2]*hf[7] +wout[6]*hf[4];
  float c11=wout[3]*hf[11]+wout[7]*hf[8];
  float c12=wout[3]*hf[12]+wout[7]*hf[9];
  float c13=wout[3]*hf[13]+wout[7]*hf[10];
  float c14=wout[3]*hf[14];
  #pragma unroll
  for(int mk=1; mk<8; mk<<=1){
    c5+=__shfl_xor(c5,mk); c6+=__shfl_xor(c6,mk); c7+=__shfl_xor(c7,mk);
    c11+=__shfl_xor(c11,mk); c12+=__shfl_xor(c12,mk);
    c13+=__shfl_xor(c13,mk); c14+=__shfl_xor(c14,mk);
  }
  if(ln==0){
    float dd=c14;
    dd=(fabsf(dd)>0.001f)? dd : (dd>=0.f? 0.001f : -0.001f);
    float* op=out+(size_t)tt*6;
    op[0]=-c13/dd; op[1]=c12/dd; op[2]=-c11/dd;
    op[3]=2.f*c5; op[4]=2.f*c6; op[5]=2.f*c7;
  }
}

extern "C" void kernel_launch(void* const* d_in, const int* in_sizes, int n_in,
                              void* d_out, int out_size, void* d_ws, size_t ws_size,
                              hipStream_t stream)
{
  (void)in_sizes; (void)n_in; (void)out_size; (void)ws_size;
  const float* x         =(const float*)d_in[0];
  const float* w_in_mv   =(const float*)d_in[1];
  const float* b_in_mv   =(const float*)d_in[2];
  const float* w_in_m2s  =(const float*)d_in[3];
  const float* b_in_s    =(const float*)d_in[4];
  const float* w_qkv_mv  =(const float*)d_in[5];
  const float* w_qkv_s2mv=(const float*)d_in[6];
  const float* w_qkv_m2s =(const float*)d_in[7];
  const float* w_qkv_s2s =(const float*)d_in[8];
  const float* w_ao_mv   =(const float*)d_in[9];
  const float* w_ao_s2mv =(const float*)d_in[10];
  const float* w_ao_m2s  =(const float*)d_in[11];
  const float* w_ao_s2s  =(const float*)d_in[12];
  const float* b_ao_mv   =(const float*)d_in[13];
  const float* b_ao_s    =(const float*)d_in[14];
  const float* w_m1_mv   =(const float*)d_in[15];
  const float* w_m1_s2mv =(const float*)d_in[16];
  const float* w_m1_m2s  =(const float*)d_in[17];
  const float* w_m1_s2s  =(const float*)d_in[18];
  const float* b_m1_mv   =(const float*)d_in[19];
  const float* b_m1_s    =(const float*)d_in[20];
  const float* w_m2_mv   =(const float*)d_in[21];
  const float* w_m2_s2mv =(const float*)d_in[22];
  const float* b_m2_mv   =(const float*)d_in[25];
  const float* w_out_mv  =(const float*)d_in[27];
  float* outp=(float*)d_out;

  float* ws=(float*)d_ws;
  size_t off=0;
  float* h_mv = ws+off; off+=(size_t)BTOK*128;
  float* h_s  = ws+off; off+=(size_t)BTOK*24;
  float* qpk  = ws+off; off+=(size_t)16*T_*12;
  unsigned* kph = (unsigned*)(ws+off); off+=(size_t)16*T_*8;       // 16 halfs/key
  unsigned* vph = (unsigned*)(ws+off); off+=(size_t)16*(T_/2)*20;  // 20 half2/pair
  float* part = ws+off; off+=(size_t)16*NSLOT*128*20;

  k_in  <<<BTOK/2,64,0,stream>>>(x,w_in_mv,b_in_mv,w_in_m2s,b_in_s,
                                 w_qkv_mv,w_qkv_s2mv,w_qkv_m2s,w_qkv_s2s,
                                 h_mv,h_s,qpk,kph,vph);
  k_attn<<<16*NSLOT,256,0,stream>>>(qpk,kph,vph,part);
  k_tail<<<BTOK/2,64,0,stream>>>(part,
                                 w_ao_mv,w_ao_s2mv,w_ao_m2s,w_ao_s2s,b_ao_mv,b_ao_s,
                                 h_mv,h_s,
                                 w_m1_mv,w_m1_s2mv,w_m1_m2s,w_m1_s2s,b_m1_mv,b_m1_s,
                                 w_m2_mv,w_m2_s2mv,b_m2_mv,w_out_mv,outp);
}

// Round 12
// 88.628 us; speedup vs baseline: 1.3844x; 1.0037x over previous
//
#include <hip/hip_runtime.h>
#include <math.h>

#define T_    2048
#define BTOK  4096   // B * T
#define KB    64
#define NSLOT 72     // sum over 16 strips of ceil((s+1)/2)

namespace {
constexpr int GRADE[16] = {0,1,1,1,1,2,2,2,2,2,2,3,3,3,3,4};
constexpr int AUGK[16]  = {-1,5,-1,-1,-1,6,6,6,-1,-1,-1,7,7,7,-1,8};
constexpr int AUGS[16]  = { 0,0, 0, 0, 0,2,3,4, 0, 0, 0,8,9,10,0,14};
constexpr float FINNER[16] = {1.f,0.f,1.f,1.f,1.f,0.f,0.f,0.f,1.f,1.f,1.f,0.f,0.f,0.f,1.f,0.f};
}

typedef _Float16 h2_t __attribute__((ext_vector_type(2)));

__device__ __forceinline__ unsigned pkh(float a, float b){
  return __builtin_bit_cast(unsigned, __builtin_amdgcn_cvt_pkrtz(a,b));
}
__device__ __forceinline__ float dot2h(unsigned a, unsigned b, float c){
#if __has_builtin(__builtin_amdgcn_fdot2)
  return __builtin_amdgcn_fdot2(__builtin_bit_cast(h2_t,a), __builtin_bit_cast(h2_t,b), c, false);
#else
  float r;
  asm("v_dot2_f32_f16 %0, %1, %2, %3" : "=v"(r) : "v"(a), "v"(b), "v"(c));
  return r;
#endif
}

__device__ __forceinline__ float gelu_f(float v){
  return 0.5f*v*(1.f + erff(v*0.70710678118654752f));
}

__device__ __forceinline__ int rsign_d(int a, int b){
  int s=0; a>>=1; while(a){ s += __popc(a&b); a>>=1; } return (s&1) ? -1 : 1;
}

// ---- K_A: embed + in-linear + norm + QKV projections + fp16 pack ---------
// 64 threads = 2 tokens x 32 lanes (8 channels x 4 input-quarters).
// K pair-packed: 12 u32 per key-pair (6 per key, no pad).
__global__ void __launch_bounds__(64) k_in(
    const float* __restrict__ x,
    const float* __restrict__ w_in_mv, const float* __restrict__ b_in_mv,
    const float* __restrict__ w_in_m2s, const float* __restrict__ b_in_s,
    const float* __restrict__ w_mv, const float* __restrict__ w_s2mv,
    const float* __restrict__ w_m2s, const float* __restrict__ w_s2s,
    float* __restrict__ h_mv, float* __restrict__ h_s,
    float* __restrict__ qp_, unsigned* __restrict__ kph, unsigned* __restrict__ vph)
{
  __shared__ float NS[2*152];   // per token: n_mv 128 + n_s 24
  int tid=threadIdx.x, tl=tid>>5, ln=tid&31;
  int o=ln&7, iq=ln>>3;          // iq 0..3
  int tt=blockIdx.x*2+tl;
  int b=tt>>11, t=tt&(T_-1);
  const float* xp = x+(size_t)tt*6;
  float mv[16];
  #pragma unroll
  for(int p=0;p<16;p++) mv[p]=0.f;
  mv[0]=1.f; mv[14]=1.f;
  mv[13]=-xp[0]; mv[12]=xp[1]; mv[11]=-xp[2];
  mv[5]=0.5f*xp[3]; mv[6]=0.5f*xp[4]; mv[7]=0.5f*xp[5];

  const float* wo=w_in_mv+o*9;
  float h[16]; float sq=0.f;
  #pragma unroll
  for(int p=0;p<16;p++){
    float v=wo[GRADE[p]]*mv[p];
    if(AUGK[p]>=0) v+=wo[AUGK[p]]*mv[AUGS[p]];
    if(p==0) v+=b_in_mv[o];
    h[p]=v; sq+=FINNER[p]*v*v;
  }
  sq+=__shfl_xor(sq,1); sq+=__shfl_xor(sq,2); sq+=__shfl_xor(sq,4);
  float dmv=rsqrtf(sq*0.125f+0.01f);
  float hs[3]; float ssq=0.f;
  #pragma unroll
  for(int jj=0;jj<3;jj++){ float v=w_in_m2s[o*3+jj]+b_in_s[o*3+jj]; hs[jj]=v; ssq+=v*v; }
  ssq+=__shfl_xor(ssq,1); ssq+=__shfl_xor(ssq,2); ssq+=__shfl_xor(ssq,4);
  float dss=rsqrtf(ssq*(1.f/24.f)+0.01f);

  float* ns=&NS[tl*152];
  if(iq==0){
    float4* hg=(float4*)(h_mv+(size_t)tt*128+o*16);
    hg[0]=make_float4(h[0],h[1],h[2],h[3]);
    hg[1]=make_float4(h[4],h[5],h[6],h[7]);
    hg[2]=make_float4(h[8],h[9],h[10],h[11]);
    hg[3]=make_float4(h[12],h[13],h[14],h[15]);
    #pragma unroll
    for(int jj=0;jj<3;jj++) h_s[(size_t)tt*24+o*3+jj]=hs[jj];
    #pragma unroll
    for(int p=0;p<16;p++) ns[o*16+p]=h[p]*dmv;
    #pragma unroll
    for(int jj=0;jj<3;jj++) ns[128+o*3+jj]=hs[jj]*dss;
  }
  __syncthreads();

  // projections: lane (o,iq) does input channels iq*2..+1, scalar j iq*6..+5
  float yq[16],yk[16],yv[16];
  #pragma unroll
  for(int p=0;p<16;p++){ yq[p]=0.f; yk[p]=0.f; yv[p]=0.f; }
  float nx0p[2];
  const float* wq=w_mv+o*72;
  #pragma unroll
  for(int ii=0;ii<2;ii++){
    int i=iq*2+ii;
    float xi[16];
    const float4* xs4=(const float4*)&ns[i*16];
    #pragma unroll
    for(int r4=0;r4<4;r4++){ float4 v=xs4[r4]; xi[r4*4]=v.x; xi[r4*4+1]=v.y; xi[r4*4+2]=v.z; xi[r4*4+3]=v.w; }
    nx0p[ii]=xi[0];
    const float* aq=wq+i*9; const float* ak=aq+576; const float* av=aq+1152;
    #pragma unroll
    for(int p=0;p<16;p++){
      float bb=xi[p];
      yq[p]+=aq[GRADE[p]]*bb; yk[p]+=ak[GRADE[p]]*bb; yv[p]+=av[GRADE[p]]*bb;
      if(AUGK[p]>=0){
        float au=xi[AUGS[p]];
        yq[p]+=aq[AUGK[p]]*au; yk[p]+=ak[AUGK[p]]*au; yv[p]+=av[AUGK[p]]*au;
      }
    }
  }
  float eq=0.f,ek=0.f,ev=0.f;
  float sq3[3]={0,0,0}, sk3[3]={0,0,0}, sv3[3]={0,0,0};
  for(int j=iq*6;j<iq*6+6;j++){
    float s=ns[128+j];
    eq+=w_s2mv[o*24+j]*s; ek+=w_s2mv[192+o*24+j]*s; ev+=w_s2mv[384+o*24+j]*s;
    #pragma unroll
    for(int jj=0;jj<3;jj++){
      int d=o*3+jj;
      sq3[jj]+=w_s2s[d*24+j]*s;
      sk3[jj]+=w_s2s[576+d*24+j]*s;
      sv3[jj]+=w_s2s[1152+d*24+j]*s;
    }
  }
  #pragma unroll
  for(int ii=0;ii<2;ii++){
    int i=iq*2+ii;
    #pragma unroll
    for(int jj=0;jj<3;jj++){
      int d=o*3+jj;
      sq3[jj]+=w_m2s[d*8+i]*nx0p[ii];
      sk3[jj]+=w_m2s[192+d*8+i]*nx0p[ii];
      sv3[jj]+=w_m2s[384+d*8+i]*nx0p[ii];
    }
  }
  yq[0]+=eq; yk[0]+=ek; yv[0]+=ev;
  #pragma unroll
  for(int p=0;p<16;p++){
    yq[p]+=__shfl_xor(yq[p],8);  yq[p]+=__shfl_xor(yq[p],16);
    yk[p]+=__shfl_xor(yk[p],8);  yk[p]+=__shfl_xor(yk[p],16);
    yv[p]+=__shfl_xor(yv[p],8);  yv[p]+=__shfl_xor(yv[p],16);
  }
  #pragma unroll
  for(int jj=0;jj<3;jj++){
    sq3[jj]+=__shfl_xor(sq3[jj],8); sq3[jj]+=__shfl_xor(sq3[jj],16);
    sk3[jj]+=__shfl_xor(sk3[jj],8); sk3[jj]+=__shfl_xor(sk3[jj],16);
    sv3[jj]+=__shfl_xor(sv3[jj],8); sv3[jj]+=__shfl_xor(sv3[jj],16);
  }

  const float scale = 0.3015113445777636f;  // 1/sqrt(11)
  size_t rb=((size_t)(b*8+o)*T_+t);
  if(iq==0){
    float4* qr=(float4*)(qp_+rb*12);
    qr[0]=make_float4(yq[0]*scale, yq[2]*scale, yq[3]*scale, yq[4]*scale);
    qr[1]=make_float4(yq[8]*scale, yq[9]*scale, yq[10]*scale, yq[14]*scale);
    qr[2]=make_float4(sq3[0]*scale, sq3[1]*scale, sq3[2]*scale, 0.f);
  } else if(iq==1){
    // K pair-packed: record (t>>1)*12, even key u32[0..5], odd key u32[6..11]
    // pair order (k0,k2)(k3,k4)(k8,k9)(k10,k14)(s0,s1)(s2,0) matches Q
    unsigned kw0=pkh(yk[0],yk[2]),  kw1=pkh(yk[3],yk[4]),  kw2=pkh(yk[8],yk[9]);
    unsigned kw3=pkh(yk[10],yk[14]),kw4=pkh(sk3[0],sk3[1]),kw5=pkh(sk3[2],0.f);
    uint2* kd=(uint2*)(kph + ((size_t)(b*8+o)*(T_/2)+(t>>1))*12 + (size_t)(t&1)*6);
    kd[0]=make_uint2(kw0,kw1); kd[1]=make_uint2(kw2,kw3); kd[2]=make_uint2(kw4,kw5);
  }
  // V fp16 interleave by key-pair via cross-token shfl (lane distance 32)
  {
    size_t vpb = ((size_t)(b*8+o)*(T_/2) + (t>>1))*20;
    bool even = (tl==0);
    if(iq==2){
      #pragma unroll
      for(int c=0;c<10;c++){
        float other=__shfl_xor(yv[c],32);
        if(even) vph[vpb+c]=pkh(yv[c],other);
      }
    } else if(iq==3){
      #pragma unroll
      for(int c=10;c<16;c++){
        float other=__shfl_xor(yv[c],32);
        if(even) vph[vpb+c]=pkh(yv[c],other);
      }
      #pragma unroll
      for(int jj=0;jj<3;jj++){
        float other=__shfl_xor(sv3[jj],32);
        if(even) vph[vpb+16+jj]=pkh(sv3[jj],other);
      }
      if(even) vph[vpb+19]=0u;
    }
  }
}

// ---- K_B: attention, no-max softmax, fp16 dot2, 4 queries/thread ---------
// Flat pair-loop (pr = pp*8+ki, pp contiguous) -> compiler pipelines loads
// across former tile boundaries. K = 3 uint4/pair (48B), V = 5 uint4/pair.
__global__ void __launch_bounds__(256,1) k_attn(
    const float* __restrict__ qp_, const unsigned* __restrict__ kph,
    const unsigned* __restrict__ vph,
    float* __restrict__ part)
{
  int tid=threadIdx.x; int qi=tid>>3, ki=tid&7;
  int j=blockIdx.x;
  int bh=j&15;
  int z=NSLOT-1-(j>>4);
  int s=0, bse=0;
  while (bse + ((s+2)>>1) <= z){ bse += (s+2)>>1; s++; }
  int sp = z - bse;
  int c  = (s+2)>>1;
  int ntiles = 2*(s+1);
  int t0 = sp*ntiles/c, t1 = (sp+1)*ntiles/c;
  int q0 = s*128;

  unsigned qh[4][6]; int kendp[4];
  #pragma unroll
  for(int w=0;w<4;w++){
    int q=q0+qi+32*w;
    kendp[w]=((q&~15)+16)>>1;
    const float4* p4=(const float4*)(qp_+((size_t)bh*T_+q)*12);
    float4 a=p4[0], b4=p4[1], c4=p4[2];
    qh[w][0]=pkh(a.x,a.y);  qh[w][1]=pkh(a.z,a.w);
    qh[w][2]=pkh(b4.x,b4.y); qh[w][3]=pkh(b4.z,b4.w);
    qh[w][4]=pkh(c4.x,c4.y); qh[w][5]=pkh(c4.z,0.f);
  }

  float acc[4][20];
  #pragma unroll
  for(int w=0;w<4;w++)
    #pragma unroll
    for(int p=0;p<20;p++) acc[w][p]=0.f;

  const uint4* gk=(const uint4*)kph + (size_t)bh*(T_/2)*3;
  const uint4* gv=(const uint4*)vph + (size_t)bh*(T_/2)*5;
  const unsigned ONE2 = 0x3C003C00u;

  int pp0=t0*4, pp1=t1*4;
  #pragma unroll 4
  for(int pp=pp0; pp<pp1; ++pp){
    int pr=pp*8+ki;
    uint4 r0=gk[3*pr], r1=gk[3*pr+1], r2=gk[3*pr+2];
    uint4 va=gv[pr*5], vb=gv[pr*5+1], vc=gv[pr*5+2], vd=gv[pr*5+3], ve=gv[pr*5+4];
    #pragma unroll
    for(int w=0;w<4;w++){
      float da = dot2h(qh[w][0],r0.x, dot2h(qh[w][1],r0.y,
                 dot2h(qh[w][2],r0.z, dot2h(qh[w][3],r0.w,
                 dot2h(qh[w][4],r1.x, dot2h(qh[w][5],r1.y, 0.f))))));
      float db = dot2h(qh[w][0],r1.z, dot2h(qh[w][1],r1.w,
                 dot2h(qh[w][2],r2.x, dot2h(qh[w][3],r2.y,
                 dot2h(qh[w][4],r2.z, dot2h(qh[w][5],r2.w, 0.f))))));
      float cA=fminf(__expf(da),60000.f);
      float cB=fminf(__expf(db),60000.f);
      unsigned c2 = pkh(cA,cB);
      c2 = (pr<kendp[w]) ? c2 : 0u;
      acc[w][0] =dot2h(c2,va.x,acc[w][0]);  acc[w][1] =dot2h(c2,va.y,acc[w][1]);
      acc[w][2] =dot2h(c2,va.z,acc[w][2]);  acc[w][3] =dot2h(c2,va.w,acc[w][3]);
      acc[w][4] =dot2h(c2,vb.x,acc[w][4]);  acc[w][5] =dot2h(c2,vb.y,acc[w][5]);
      acc[w][6] =dot2h(c2,vb.z,acc[w][6]);  acc[w][7] =dot2h(c2,vb.w,acc[w][7]);
      acc[w][8] =dot2h(c2,vc.x,acc[w][8]);  acc[w][9] =dot2h(c2,vc.y,acc[w][9]);
      acc[w][10]=dot2h(c2,vc.z,acc[w][10]); acc[w][11]=dot2h(c2,vc.w,acc[w][11]);
      acc[w][12]=dot2h(c2,vd.x,acc[w][12]); acc[w][13]=dot2h(c2,vd.y,acc[w][13]);
      acc[w][14]=dot2h(c2,vd.z,acc[w][14]); acc[w][15]=dot2h(c2,vd.w,acc[w][15]);
      acc[w][16]=dot2h(c2,ONE2,acc[w][16]);
      acc[w][17]=dot2h(c2,ve.x,acc[w][17]); acc[w][18]=dot2h(c2,ve.y,acc[w][18]);
      acc[w][19]=dot2h(c2,ve.z,acc[w][19]);
    }
  }

  #pragma unroll
  for(int mk=1; mk<8; mk<<=1){
    #pragma unroll
    for(int w=0;w<4;w++)
      #pragma unroll
      for(int p=0;p<20;p++) acc[w][p]+=__shfl_xor(acc[w][p],mk);
  }

  if(ki==0){
    #pragma unroll
    for(int w=0;w<4;w++){
      float* pr = part + ((size_t)(bh*NSLOT + z)*128 + qi + 32*w)*20;
      float4* p4=(float4*)pr;
      p4[0]=make_float4(acc[w][0],acc[w][1],acc[w][2],acc[w][3]);
      p4[1]=make_float4(acc[w][4],acc[w][5],acc[w][6],acc[w][7]);
      p4[2]=make_float4(acc[w][8],acc[w][9],acc[w][10],acc[w][11]);
      p4[3]=make_float4(acc[w][12],acc[w][13],acc[w][14],acc[w][15]);
      p4[4]=make_float4(acc[w][16],acc[w][17],acc[w][18],acc[w][19]);
    }
  }
}

// ---- K_C: combine partials + ao + norm + m1 + GP/join + m2 + out ---------
// 64 threads = 2 tokens x 32 lanes (8 channels x 4 quarters).
__global__ void __launch_bounds__(64) k_tail(
    const float* __restrict__ part,
    const float* __restrict__ w_ao_mv, const float* __restrict__ w_ao_s2mv,
    const float* __restrict__ w_ao_m2s, const float* __restrict__ w_ao_s2s,
    const float* __restrict__ b_ao_mv, const float* __restrict__ b_ao_s,
    const float* __restrict__ h_mv, const float* __restrict__ h_s,
    const float* __restrict__ w_m1_mv, const float* __restrict__ w_m1_s2mv,
    const float* __restrict__ w_m1_m2s, const float* __restrict__ w_m1_s2s,
    const float* __restrict__ b_m1_mv, const float* __restrict__ b_m1_s,
    const float* __restrict__ w_m2_mv, const float* __restrict__ w_m2_s2mv,
    const float* __restrict__ b_m2_mv,
    const float* __restrict__ w_out_mv,
    float* __restrict__ out)
{
  __shared__ int   GPI[256]; __shared__ float GPS[256];
  __shared__ int   JNI[256]; __shared__ float JNS[256];
  __shared__ float OS[2*152];
  __shared__ float NS[2*152];
  __shared__ float U[2*264];
  __shared__ float G[2*136];
  __shared__ float GSm[2*24];
  int tid=threadIdx.x, tl=tid>>5, ln=tid&31;
  int o=ln&7, iq=ln>>3;          // iq 0..3
  int tt=blockIdx.x*2+tl;

  { // build tables (threads 0..31)
    const int mask_of[16]={0,1,2,4,8,3,5,9,6,10,12,7,11,13,14,15};
    const int idx_of[16] ={0,1,2,5,3,6,8,11,4,7,9,12,10,13,14,15};
    if (tid<16){
      int k=tid, km=mask_of[k], slotn=0;
      for(int i=0;i<16;i++){
        int im=mask_of[i], jm=im^km;
        if(im & jm & 1) continue;
        GPI[k*16+slotn]=i|(idx_of[jm]<<4);
        GPS[k*16+slotn]=(float)rsign_d(im,jm);
        slotn++;
      }
      for(;slotn<16;slotn++){ GPI[k*16+slotn]=0; GPS[k*16+slotn]=0.f; }
    } else if (tid<32){
      int p=tid-16, pm=mask_of[p], rest=15&~pm, slotn=0;
      for(int u=0;u<16;u++){
        if(u & ~rest) continue;
        int am=pm|u, bm=pm|(rest&~u);
        float s=(float)( rsign_d(pm,15&~pm)*rsign_d(15&~am,15&~bm)
                        *rsign_d(am,15&~am)*rsign_d(bm,15&~bm) );
        JNI[p*16+slotn]=idx_of[am]|(idx_of[bm]<<4);
        JNS[p*16+slotn]=s;
        slotn++;
      }
      for(;slotn<16;slotn++){ JNI[p*16+slotn]=0; JNS[p*16+slotn]=0.f; }
    }
  }

  // combine attention partials: lane = (head h=ln>>2, quarter qr=ln&3)
  {
    int b=tt>>11, t=tt&(T_-1);
    int strip=t>>7, qil=t&127;
    int h=ln>>2, qr=ln&3;
    int nsp=(strip+2)>>1;
    int kk=strip>>1;
    int rbase=(strip&1)? (kk+1)*(kk+1) : kk*kk+kk;
    const float* pb = part + ((size_t)((b*8+h)*NSLOT+rbase)*128 + qil)*20;
    float am[4]={0,0,0,0};
    float lv=0.f, s0=0.f, s1=0.f, s2=0.f;
    for(int spp=0; spp<nsp; ++spp){
      const float4* p4=(const float4*)(pb + (size_t)spp*128*20);
      float4 a4=p4[qr];
      am[0]+=a4.x; am[1]+=a4.y; am[2]+=a4.z; am[3]+=a4.w;
      if(qr==0){ float4 meta=p4[4]; lv+=meta.x; s0+=meta.y; s1+=meta.z; s2+=meta.w; }
    }
    float inv = (qr==0)? 1.f/lv : 0.f;
    inv = __shfl(inv, (tid & ~3));
    float* os=&OS[tl*152];
    #pragma unroll
    for(int p=0;p<4;p++) os[h*16+qr*4+p]=am[p]*inv;
    if(qr==0){ os[128+h*3]=s0*inv; os[128+h*3+1]=s1*inv; os[128+h*3+2]=s2*inv; }
  }
  __syncthreads();

  const float* os=&OS[tl*152];
  float xh[2][16];
  #pragma unroll
  for(int ii=0;ii<2;ii++){
    #pragma unroll
    for(int p=0;p<16;p++) xh[ii][p]=os[(iq*2+ii)*16+p];
  }
  float xs[24];
  #pragma unroll
  for(int jj=0;jj<24;jj++) xs[jj]=os[128+jj];

  // ao: channel o, input quarter iq
  float y[16];
  #pragma unroll
  for(int p=0;p<16;p++) y[p]=0.f;
  #pragma unroll
  for(int ii=0;ii<2;ii++){
    const float* wi=w_ao_mv+o*72+(iq*2+ii)*9;
    #pragma unroll
    for(int p=0;p<16;p++){
      y[p]+=wi[GRADE[p]]*xh[ii][p];
      if(AUGK[p]>=0) y[p]+=wi[AUGK[p]]*xh[ii][AUGS[p]];
    }
  }
  float e=(iq==0)? b_ao_mv[o] : 0.f;
  for(int j2=iq*6;j2<iq*6+6;j2++) e+=w_ao_s2mv[o*24+j2]*xs[j2];
  y[0]+=e;
  float a3[3];
  #pragma unroll
  for(int jj=0;jj<3;jj++) a3[jj]=(iq==0)? b_ao_s[o*3+jj] : 0.f;
  #pragma unroll
  for(int ii=0;ii<2;ii++){
    #pragma unroll
    for(int jj=0;jj<3;jj++) a3[jj]+=w_ao_m2s[(o*3+jj)*8+(iq*2+ii)]*xh[ii][0];
  }
  for(int j2=iq*6;j2<iq*6+6;j2++){
    #pragma unroll
    for(int jj=0;jj<3;jj++) a3[jj]+=w_ao_s2s[(o*3+jj)*24+j2]*xs[j2];
  }
  #pragma unroll
  for(int p=0;p<16;p++){ y[p]+=__shfl_xor(y[p],8); y[p]+=__shfl_xor(y[p],16); }
  #pragma unroll
  for(int jj=0;jj<3;jj++){ a3[jj]+=__shfl_xor(a3[jj],8); a3[jj]+=__shfl_xor(a3[jj],16); }

  // residual + norms (dup across iq; reduce over o via xor 1,2,4)
  float hch[16]; float sqv=0.f;
  { const float4* hg=(const float4*)(h_mv+(size_t)tt*128+o*16);
    #pragma unroll
    for(int r4=0;r4<4;r4++){ float4 v=hg[r4];
      hch[r4*4]=v.x+y[r4*4]; hch[r4*4+1]=v.y+y[r4*4+1];
      hch[r4*4+2]=v.z+y[r4*4+2]; hch[r4*4+3]=v.w+y[r4*4+3]; } }
  #pragma unroll
  for(int p=0;p<16;p++) sqv+=FINNER[p]*hch[p]*hch[p];
  sqv+=__shfl_xor(sqv,1); sqv+=__shfl_xor(sqv,2); sqv+=__shfl_xor(sqv,4);
  float dmv=rsqrtf(sqv*0.125f+0.01f);
  float hs3[3]; float ssq=0.f;
  #pragma unroll
  for(int jj=0;jj<3;jj++){
    float v=h_s[(size_t)tt*24+o*3+jj]+a3[jj];
    hs3[jj]=v; ssq+=v*v;
  }
  ssq+=__shfl_xor(ssq,1); ssq+=__shfl_xor(ssq,2); ssq+=__shfl_xor(ssq,4);
  float dss=rsqrtf(ssq*(1.f/24.f)+0.01f);

  float* nsbuf=&NS[tl*152];
  if(iq==0){
    #pragma unroll
    for(int p=0;p<16;p++) nsbuf[o*16+p]=hch[p]*dmv;
    #pragma unroll
    for(int jj=0;jj<3;jj++) nsbuf[128+o*3+jj]=hs3[jj]*dss;
  }
  __syncthreads();

  // m1: lane = (output channel ln16, input half mh)
  {
    int ln16=ln&15, mh=ln>>4;
    float u[16];
    #pragma unroll
    for(int p=0;p<16;p++) u[p]=0.f;
    for(int i=mh*4;i<mh*4+4;i++){
      float xi[16];
      const float4* xs4=(const float4*)&nsbuf[i*16];
      #pragma unroll
      for(int r4=0;r4<4;r4++){ float4 v=xs4[r4]; xi[r4*4]=v.x; xi[r4*4+1]=v.y; xi[r4*4+2]=v.z; xi[r4*4+3]=v.w; }
      const float* wi=w_m1_mv+ln16*72+i*9;
      #pragma unroll
      for(int p=0;p<16;p++){
        u[p]+=wi[GRADE[p]]*xi[p];
        if(AUGK[p]>=0) u[p]+=wi[AUGK[p]]*xi[AUGS[p]];
      }
    }
    float e1=(mh==0)? b_m1_mv[ln16] : 0.f;
    for(int j2=mh*12;j2<mh*12+12;j2++) e1+=w_m1_s2mv[ln16*24+j2]*nsbuf[128+j2];
    u[0]+=e1;
    #pragma unroll
    for(int p=0;p<16;p++) u[p]+=__shfl_xor(u[p],16);
    if(mh==0){
      float* uu=&U[tl*264];
      #pragma unroll
      for(int p=0;p<16;p++) uu[ln16*16+p]=u[p];
    }
  }
  if(ln<8){  // m1 scalar path, o=ln
    float s3[3];
    #pragma unroll
    for(int jj=0;jj<3;jj++) s3[jj]=b_m1_s[o*3+jj];
    for(int j2=0;j2<24;j2++){
      float s=nsbuf[128+j2];
      #pragma unroll
      for(int jj=0;jj<3;jj++) s3[jj]+=w_m1_s2s[(o*3+jj)*24+j2]*s;
    }
    for(int i=0;i<8;i++){
      float x0=nsbuf[i*16];
      #pragma unroll
      for(int jj=0;jj<3;jj++) s3[jj]+=w_m1_m2s[(o*3+jj)*8+i]*x0;
    }
    #pragma unroll
    for(int jj=0;jj<3;jj++) GSm[tl*24+o*3+jj]=gelu_f(s3[jj]);
  }
  __syncthreads();

  // GP (o<4) / JOIN (o>=4): product o, component quarter iq; gate via shfl
  {
    const int*   TI=(o<4)? GPI : JNI;
    const float* TS=(o<4)? GPS : JNS;
    const float* uu=&U[tl*264];
    const float* lft=&uu[((o<4)? o : (4+o))*16];
    const float* rgt=&uu[((o<4)? (4+o) : (8+o))*16];
    float g[4];
    #pragma unroll
    for(int kk=0;kk<4;kk++){
      int k=iq*4+kk;
      float accv=0.f;
      #pragma unroll
      for(int e2=0;e2<16;e2++){
        int ij=TI[k*16+e2]; float sg=TS[k*16+e2];
        accv += sg * lft[ij&15] * rgt[ij>>4];
      }
      g[kk]=accv;
    }
    float g0 = __shfl(g[0], (tid & ~0x18));   // comp0 lives on iq==0 lane
    float gt = gelu_f(g0);
    float* gg=&G[tl*136];
    #pragma unroll
    for(int kk=0;kk<4;kk++) gg[o*16+iq*4+kk]=g[kk]*gt;
  }
  __syncthreads();

  // m2: channel o, input quarter iq
  float y2[16];
  #pragma unroll
  for(int p=0;p<16;p++) y2[p]=0.f;
  #pragma unroll
  for(int ii=0;ii<2;ii++){
    float xi[16];
    const float4* gi=(const float4*)&G[tl*136+(iq*2+ii)*16];
    #pragma unroll
    for(int r4=0;r4<4;r4++){ float4 v=gi[r4]; xi[r4*4]=v.x; xi[r4*4+1]=v.y; xi[r4*4+2]=v.z; xi[r4*4+3]=v.w; }
    const float* wi=w_m2_mv+o*72+(iq*2+ii)*9;
    #pragma unroll
    for(int p=0;p<16;p++){
      y2[p]+=wi[GRADE[p]]*xi[p];
      if(AUGK[p]>=0) y2[p]+=wi[AUGK[p]]*xi[AUGS[p]];
    }
  }
  float e2=(iq==0)? b_m2_mv[o] : 0.f;
  for(int j2=iq*6;j2<iq*6+6;j2++) e2+=w_m2_s2mv[o*24+j2]*GSm[tl*24+j2];
  y2[0]+=e2;
  #pragma unroll
  for(int p=0;p<16;p++){ y2[p]+=__shfl_xor(y2[p],8); y2[p]+=__shfl_xor(y2[p],16); }

  float hf[16];
  #pragma unroll
  for(int p=0;p<16;p++) hf[p]=hch[p]+y2[p];

  const float* wout=w_out_mv+o*9;
  float c5 =wout[2]*hf[5] +wout[6]*hf[2];
  float c6 =wout[2]*hf[6] +wout[6]*hf[3];
  float c7 =wout[2]*hf[7] +wout[6]*hf[4];
  float c11=wout[3]*hf[11]+wout[7]*hf[8];
  float c12=wout[3]*hf[12]+wout[7]*hf[9];
  float c13=wout[3]*hf[13]+wout[7]*hf[10];
  float c14=wout[3]*hf[14];
  #pragma unroll
  for(int mk=1; mk<8; mk<<=1){
    c5+=__shfl_xor(c5,mk); c6+=__shfl_xor(c6,mk); c7+=__shfl_xor(c7,mk);
    c11+=__shfl_xor(c11,mk); c12+=__shfl_xor(c12,mk);
    c13+=__shfl_xor(c13,mk); c14+=__shfl_xor(c14,mk);
  }
  if(ln==0){
    float dd=c14;
    dd=(fabsf(dd)>0.001f)? dd : (dd>=0.f? 0.001f : -0.001f);
    float* op=out+(size_t)tt*6;
    op[0]=-c13/dd; op[1]=c12/dd; op[2]=-c11/dd;
    op[3]=2.f*c5; op[4]=2.f*c6; op[5]=2.f*c7;
  }
}

extern "C" void kernel_launch(void* const* d_in, const int* in_sizes, int n_in,
                              void* d_out, int out_size, void* d_ws, size_t ws_size,
                              hipStream_t stream)
{
  (void)in_sizes; (void)n_in; (void)out_size; (void)ws_size;
  const float* x         =(const float*)d_in[0];
  const float* w_in_mv   =(const float*)d_in[1];
  const float* b_in_mv   =(const float*)d_in[2];
  const float* w_in_m2s  =(const float*)d_in[3];
  const float* b_in_s    =(const float*)d_in[4];
  const float* w_qkv_mv  =(const float*)d_in[5];
  const float* w_qkv_s2mv=(const float*)d_in[6];
  const float* w_qkv_m2s =(const float*)d_in[7];
  const float* w_qkv_s2s =(const float*)d_in[8];
  const float* w_ao_mv   =(const float*)d_in[9];
  const float* w_ao_s2mv =(const float*)d_in[10];
  const float* w_ao_m2s  =(const float*)d_in[11];
  const float* w_ao_s2s  =(const float*)d_in[12];
  const float* b_ao_mv   =(const float*)d_in[13];
  const float* b_ao_s    =(const float*)d_in[14];
  const float* w_m1_mv   =(const float*)d_in[15];
  const float* w_m1_s2mv =(const float*)d_in[16];
  const float* w_m1_m2s  =(const float*)d_in[17];
  const float* w_m1_s2s  =(const float*)d_in[18];
  const float* b_m1_mv   =(const float*)d_in[19];
  const float* b_m1_s    =(const float*)d_in[20];
  const float* w_m2_mv   =(const float*)d_in[21];
  const float* w_m2_s2mv =(const float*)d_in[22];
  const float* b_m2_mv   =(const float*)d_in[25];
  const float* w_out_mv  =(const float*)d_in[27];
  float* outp=(float*)d_out;

  float* ws=(float*)d_ws;
  size_t off=0;
  float* h_mv = ws+off; off+=(size_t)BTOK*128;
  float* h_s  = ws+off; off+=(size_t)BTOK*24;
  float* qpk  = ws+off; off+=(size_t)16*T_*12;
  unsigned* kph = (unsigned*)(ws+off); off+=(size_t)16*(T_/2)*12; // 12 u32/pair
  unsigned* vph = (unsigned*)(ws+off); off+=(size_t)16*(T_/2)*20; // 20 half2/pair
  float* part = ws+off; off+=(size_t)16*NSLOT*128*20;

  k_in  <<<BTOK/2,64,0,stream>>>(x,w_in_mv,b_in_mv,w_in_m2s,b_in_s,
                                 w_qkv_mv,w_qkv_s2mv,w_qkv_m2s,w_qkv_s2s,
                                 h_mv,h_s,qpk,kph,vph);
  k_attn<<<16*NSLOT,256,0,stream>>>(qpk,kph,vph,part);
  k_tail<<<BTOK/2,64,0,stream>>>(part,
                                 w_ao_mv,w_ao_s2mv,w_ao_m2s,w_ao_s2s,b_ao_mv,b_ao_s,
                                 h_mv,h_s,
                                 w_m1_mv,w_m1_s2mv,w_m1_m2s,w_m1_s2s,b_m1_mv,b_m1_s,
                                 w_m2_mv,w_m2_s2mv,b_m2_mv,w_out_mv,outp);
}

// Round 13
// 88.185 us; speedup vs baseline: 1.3913x; 1.0050x over previous
//
#include <hip/hip_runtime.h>
#include <math.h>

#define T_    2048
#define BTOK  4096   // B * T
#define NSLOT 144    // sum over 32 strips of ceil((s+1)/4)

namespace {
constexpr int GRADE[16] = {0,1,1,1,1,2,2,2,2,2,2,3,3,3,3,4};
constexpr int AUGK[16]  = {-1,5,-1,-1,-1,6,6,6,-1,-1,-1,7,7,7,-1,8};
constexpr int AUGS[16]  = { 0,0, 0, 0, 0,2,3,4, 0, 0, 0,8,9,10,0,14};
constexpr float FINNER[16] = {1.f,0.f,1.f,1.f,1.f,0.f,0.f,0.f,1.f,1.f,1.f,0.f,0.f,0.f,1.f,0.f};
}

typedef __attribute__((ext_vector_type(4))) _Float16 h4_t;
typedef __attribute__((ext_vector_type(4))) float    f4_t;

__device__ __forceinline__ unsigned pkh(float a, float b){
  return __builtin_bit_cast(unsigned, __builtin_amdgcn_cvt_pkrtz(a,b));
}
__device__ __forceinline__ f4_t mfma16(h4_t a, h4_t b, f4_t c){
  return __builtin_amdgcn_mfma_f32_16x16x16f16(a,b,c,0,0,0);
}

__device__ __forceinline__ float gelu_f(float v){
  return 0.5f*v*(1.f + erff(v*0.70710678118654752f));
}

__device__ __forceinline__ int rsign_d(int a, int b){
  int s=0; a>>=1; while(a){ s += __popc(a&b); a>>=1; } return (s&1) ? -1 : 1;
}

// ---- K_A: embed + in-linear + norm + QKV projections + fp16 pack ---------
// 64 threads = 2 tokens x 32 lanes (8 heads x 4 input-quarters).
// Q/K: 16 halfs/token (dims: k0,k2,k3,k4,k8,k9,k10,k14,s0,s1,s2,0,0,0,0,0).
// V^T: [bh][comp 0..31][key-pair] u32 = half2(v[2p][c], v[2p+1][c]);
//      comp 19 = half2(1,1) (accumulates l); comps 20..31 = 0.
__global__ void __launch_bounds__(64) k_in(
    const float* __restrict__ x,
    const float* __restrict__ w_in_mv, const float* __restrict__ b_in_mv,
    const float* __restrict__ w_in_m2s, const float* __restrict__ b_in_s,
    const float* __restrict__ w_mv, const float* __restrict__ w_s2mv,
    const float* __restrict__ w_m2s, const float* __restrict__ w_s2s,
    float* __restrict__ h_mv, float* __restrict__ h_s,
    unsigned* __restrict__ qph, unsigned* __restrict__ kph, unsigned* __restrict__ vph)
{
  __shared__ float NS[2*152];   // per token: n_mv 128 + n_s 24
  int tid=threadIdx.x, tl=tid>>5, ln=tid&31;
  int o=ln&7, iq=ln>>3;          // iq 0..3
  int tt=blockIdx.x*2+tl;
  int b=tt>>11, t=tt&(T_-1);
  const float* xp = x+(size_t)tt*6;
  float mv[16];
  #pragma unroll
  for(int p=0;p<16;p++) mv[p]=0.f;
  mv[0]=1.f; mv[14]=1.f;
  mv[13]=-xp[0]; mv[12]=xp[1]; mv[11]=-xp[2];
  mv[5]=0.5f*xp[3]; mv[6]=0.5f*xp[4]; mv[7]=0.5f*xp[5];

  const float* wo=w_in_mv+o*9;
  float h[16]; float sq=0.f;
  #pragma unroll
  for(int p=0;p<16;p++){
    float v=wo[GRADE[p]]*mv[p];
    if(AUGK[p]>=0) v+=wo[AUGK[p]]*mv[AUGS[p]];
    if(p==0) v+=b_in_mv[o];
    h[p]=v; sq+=FINNER[p]*v*v;
  }
  sq+=__shfl_xor(sq,1); sq+=__shfl_xor(sq,2); sq+=__shfl_xor(sq,4);
  float dmv=rsqrtf(sq*0.125f+0.01f);
  float hs[3]; float ssq=0.f;
  #pragma unroll
  for(int jj=0;jj<3;jj++){ float v=w_in_m2s[o*3+jj]+b_in_s[o*3+jj]; hs[jj]=v; ssq+=v*v; }
  ssq+=__shfl_xor(ssq,1); ssq+=__shfl_xor(ssq,2); ssq+=__shfl_xor(ssq,4);
  float dss=rsqrtf(ssq*(1.f/24.f)+0.01f);

  float* ns=&NS[tl*152];
  if(iq==0){
    float4* hg=(float4*)(h_mv+(size_t)tt*128+o*16);
    hg[0]=make_float4(h[0],h[1],h[2],h[3]);
    hg[1]=make_float4(h[4],h[5],h[6],h[7]);
    hg[2]=make_float4(h[8],h[9],h[10],h[11]);
    hg[3]=make_float4(h[12],h[13],h[14],h[15]);
    #pragma unroll
    for(int jj=0;jj<3;jj++) h_s[(size_t)tt*24+o*3+jj]=hs[jj];
    #pragma unroll
    for(int p=0;p<16;p++) ns[o*16+p]=h[p]*dmv;
    #pragma unroll
    for(int jj=0;jj<3;jj++) ns[128+o*3+jj]=hs[jj]*dss;
  }
  __syncthreads();

  // projections: lane (o,iq) does input channels iq*2..+1, scalar j iq*6..+5
  float yq[16],yk[16],yv[16];
  #pragma unroll
  for(int p=0;p<16;p++){ yq[p]=0.f; yk[p]=0.f; yv[p]=0.f; }
  float nx0p[2];
  const float* wq=w_mv+o*72;
  #pragma unroll
  for(int ii=0;ii<2;ii++){
    int i=iq*2+ii;
    float xi[16];
    const float4* xs4=(const float4*)&ns[i*16];
    #pragma unroll
    for(int r4=0;r4<4;r4++){ float4 v=xs4[r4]; xi[r4*4]=v.x; xi[r4*4+1]=v.y; xi[r4*4+2]=v.z; xi[r4*4+3]=v.w; }
    nx0p[ii]=xi[0];
    const float* aq=wq+i*9; const float* ak=aq+576; const float* av=aq+1152;
    #pragma unroll
    for(int p=0;p<16;p++){
      float bb=xi[p];
      yq[p]+=aq[GRADE[p]]*bb; yk[p]+=ak[GRADE[p]]*bb; yv[p]+=av[GRADE[p]]*bb;
      if(AUGK[p]>=0){
        float au=xi[AUGS[p]];
        yq[p]+=aq[AUGK[p]]*au; yk[p]+=ak[AUGK[p]]*au; yv[p]+=av[AUGK[p]]*au;
      }
    }
  }
  float sq3[3]={0,0,0}, sk3[3]={0,0,0}, sv3[3]={0,0,0};
  float eq=0.f,ek=0.f,ev=0.f;
  for(int j=iq*6;j<iq*6+6;j++){
    float s=ns[128+j];
    eq+=w_s2mv[o*24+j]*s; ek+=w_s2mv[192+o*24+j]*s; ev+=w_s2mv[384+o*24+j]*s;
    #pragma unroll
    for(int jj=0;jj<3;jj++){
      int d=o*3+jj;
      sq3[jj]+=w_s2s[d*24+j]*s;
      sk3[jj]+=w_s2s[576+d*24+j]*s;
      sv3[jj]+=w_s2s[1152+d*24+j]*s;
    }
  }
  #pragma unroll
  for(int ii=0;ii<2;ii++){
    int i=iq*2+ii;
    #pragma unroll
    for(int jj=0;jj<3;jj++){
      int d=o*3+jj;
      sq3[jj]+=w_m2s[d*8+i]*nx0p[ii];
      sk3[jj]+=w_m2s[192+d*8+i]*nx0p[ii];
      sv3[jj]+=w_m2s[384+d*8+i]*nx0p[ii];
    }
  }
  yq[0]+=eq; yk[0]+=ek; yv[0]+=ev;
  #pragma unroll
  for(int p=0;p<16;p++){
    yq[p]+=__shfl_xor(yq[p],8);  yq[p]+=__shfl_xor(yq[p],16);
    yk[p]+=__shfl_xor(yk[p],8);  yk[p]+=__shfl_xor(yk[p],16);
    yv[p]+=__shfl_xor(yv[p],8);  yv[p]+=__shfl_xor(yv[p],16);
  }
  #pragma unroll
  for(int jj=0;jj<3;jj++){
    sq3[jj]+=__shfl_xor(sq3[jj],8); sq3[jj]+=__shfl_xor(sq3[jj],16);
    sk3[jj]+=__shfl_xor(sk3[jj],8); sk3[jj]+=__shfl_xor(sk3[jj],16);
    sv3[jj]+=__shfl_xor(sv3[jj],8); sv3[jj]+=__shfl_xor(sv3[jj],16);
  }

  const float scale = 0.3015113445777636f;  // 1/sqrt(11)
  size_t rb=((size_t)(b*8+o)*T_+t);
  if(iq==0){
    uint4 qa,qb;
    qa.x=pkh(yq[0]*scale, yq[2]*scale);  qa.y=pkh(yq[3]*scale, yq[4]*scale);
    qa.z=pkh(yq[8]*scale, yq[9]*scale);  qa.w=pkh(yq[10]*scale, yq[14]*scale);
    qb.x=pkh(sq3[0]*scale, sq3[1]*scale); qb.y=pkh(sq3[2]*scale, 0.f); qb.z=0u; qb.w=0u;
    uint4* qr4=(uint4*)qph + rb*2; qr4[0]=qa; qr4[1]=qb;
  } else if(iq==1){
    uint4 ka,kb;
    ka.x=pkh(yk[0],yk[2]);  ka.y=pkh(yk[3],yk[4]);
    ka.z=pkh(yk[8],yk[9]);  ka.w=pkh(yk[10],yk[14]);
    kb.x=pkh(sk3[0],sk3[1]); kb.y=pkh(sk3[2],0.f); kb.z=0u; kb.w=0u;
    uint4* kr4=(uint4*)kph + rb*2; kr4[0]=ka; kr4[1]=kb;
  }
  // V^T fp16 interleave by key-pair via cross-token shfl (lane distance 32)
  {
    size_t vbase = (size_t)(b*8+o)*32;
    size_t pair  = (size_t)(t>>1);
    bool even = (tl==0);
    if(iq==2){
      #pragma unroll
      for(int c=0;c<10;c++){
        float other=__shfl_xor(yv[c],32);
        if(even) vph[(vbase+c)*(T_/2)+pair]=pkh(yv[c],other);
      }
    } else if(iq==3){
      #pragma unroll
      for(int c=10;c<16;c++){
        float other=__shfl_xor(yv[c],32);
        if(even) vph[(vbase+c)*(T_/2)+pair]=pkh(yv[c],other);
      }
      #pragma unroll
      for(int jj=0;jj<3;jj++){
        float other=__shfl_xor(sv3[jj],32);
        if(even) vph[(vbase+16+jj)*(T_/2)+pair]=pkh(sv3[jj],other);
      }
      if(even) vph[(vbase+19)*(T_/2)+pair]=0x3C003C00u;  // half2(1,1) -> l
    }
    if(even){  // zero-fill comps 20..31 (poison safety)
      int c0=20+iq*3;
      #pragma unroll
      for(int cc=0;cc<3;cc++) vph[(vbase+c0+cc)*(T_/2)+pair]=0u;
    }
  }
}

// ---- K_B: MFMA attention, no-max softmax, additive partials --------------
// Block = 4 waves x 16 queries (64-query strip piece). Per 16-key chunk:
//   S^T = mfma16(A=K, B=Q)  (A,B read straight from 32B/token records)
//   P   = exp(S^T) packed to f16 = PV's B operand (D-layout == B-layout)
//   O^T += mfma16(A=V^T[c0..15]) ; mfma16(A=V^T[c16..31])  (c19=1 -> l)
// Block-causal mask aligns with 16-key chunks -> chunks all-valid or skipped.
__global__ void __launch_bounds__(256) k_attn(
    const unsigned* __restrict__ qph, const unsigned* __restrict__ kph,
    const unsigned* __restrict__ vph,
    float* __restrict__ part)
{
  int tid=threadIdx.x;
  int wave=tid>>6, lane=tid&63;
  int col=lane&15, rowb=lane>>4;   // mfma col / k-block
  int j=blockIdx.x;
  int bh=j&15;
  int z=NSLOT-1-(j>>4);            // heavy slots first
  int a=0;
  while (2*(a+1)*(a+2) <= z) a++;
  int rem = z - 2*a*(a+1);
  int bqd = rem/(a+1);
  int sp  = rem - bqd*(a+1);
  int strip = 4*a + bqd;
  int c     = a+1;
  int nchunk = (strip+1)*4;        // 16-key chunks in [0,(strip+1)*64)
  int t0 = sp*nchunk/c, t1 = (sp+1)*nchunk/c;
  int chend = strip*4 + wave + 1;  // causal cap for this wave's 16-query tile
  if (t1 < chend) chend = t1;

  int q0 = strip*64 + wave*16;
  const h4_t* qh4=(const h4_t*)qph;
  const h4_t* kh4=(const h4_t*)kph;
  const h4_t* vh4=(const h4_t*)vph;

  // B=Q operand: lane holds Q[q0+col][d=4*rowb+i]
  h4_t bq = qh4[((size_t)bh*T_ + q0 + col)*4 + rowb];

  f4_t acc0={0.f,0.f,0.f,0.f}, acc1={0.f,0.f,0.f,0.f};
  size_t v0base = ((size_t)bh*32 + col)*(T_/2/2);      // h4 units: T/2 u32 = T/4 h4
  size_t v1base = ((size_t)bh*32 + 16 + col)*(T_/2/2);

  for(int ch=t0; ch<chend; ++ch){
    // A=K operand: lane holds K[16ch+col][d=4*rowb+i]
    h4_t ak = kh4[((size_t)bh*T_ + 16*ch + col)*4 + rowb];
    f4_t zz={0.f,0.f,0.f,0.f};
    f4_t st = mfma16(ak, bq, zz);    // S^T[key=4*rowb+r][q=col]
    float c0=fminf(__expf(st[0]),60000.f);
    float c1=fminf(__expf(st[1]),60000.f);
    float c2=fminf(__expf(st[2]),60000.f);
    float c3=fminf(__expf(st[3]),60000.f);
    h4_t bp = __builtin_bit_cast(h4_t, make_uint2(pkh(c0,c1), pkh(c2,c3)));
    // A=V^T operands: lane holds V^T[c][key=16ch+4*rowb+i]
    h4_t av0 = vh4[v0base + (size_t)ch*4 + rowb];
    h4_t av1 = vh4[v1base + (size_t)ch*4 + rowb];
    acc0 = mfma16(av0, bp, acc0);
    acc1 = mfma16(av1, bp, acc1);
  }

  // write partials: O^T[comp=4*rowb+r][q=q0w+col]; comps 16..19 from acc1 (rowb==0)
  float* rec = part + (((size_t)bh*NSLOT + z)*64 + wave*16 + col)*20;
  ((float4*)rec)[rowb] = make_float4(acc0[0],acc0[1],acc0[2],acc0[3]);
  if(rowb==0) ((float4*)rec)[4] = make_float4(acc1[0],acc1[1],acc1[2],acc1[3]);
}

// ---- K_C: combine partials + ao + norm + m1 + GP/join + m2 + out ---------
// 64 threads = 2 tokens x 32 lanes (8 channels x 4 quarters).
__global__ void __launch_bounds__(64) k_tail(
    const float* __restrict__ part,
    const float* __restrict__ w_ao_mv, const float* __restrict__ w_ao_s2mv,
    const float* __restrict__ w_ao_m2s, const float* __restrict__ w_ao_s2s,
    const float* __restrict__ b_ao_mv, const float* __restrict__ b_ao_s,
    const float* __restrict__ h_mv, const float* __restrict__ h_s,
    const float* __restrict__ w_m1_mv, const float* __restrict__ w_m1_s2mv,
    const float* __restrict__ w_m1_m2s, const float* __restrict__ w_m1_s2s,
    const float* __restrict__ b_m1_mv, const float* __restrict__ b_m1_s,
    const float* __restrict__ w_m2_mv, const float* __restrict__ w_m2_s2mv,
    const float* __restrict__ b_m2_mv,
    const float* __restrict__ w_out_mv,
    float* __restrict__ out)
{
  __shared__ int   GPI[256]; __shared__ float GPS[256];
  __shared__ int   JNI[256]; __shared__ float JNS[256];
  __shared__ float OS[2*152];
  __shared__ float NS[2*152];
  __shared__ float U[2*264];
  __shared__ float G[2*136];
  __shared__ float GSm[2*24];
  int tid=threadIdx.x, tl=tid>>5, ln=tid&31;
  int o=ln&7, iq=ln>>3;          // iq 0..3
  int tt=blockIdx.x*2+tl;

  { // build tables (threads 0..31)
    const int mask_of[16]={0,1,2,4,8,3,5,9,6,10,12,7,11,13,14,15};
    const int idx_of[16] ={0,1,2,5,3,6,8,11,4,7,9,12,10,13,14,15};
    if (tid<16){
      int k=tid, km=mask_of[k], slotn=0;
      for(int i=0;i<16;i++){
        int im=mask_of[i], jm=im^km;
        if(im & jm & 1) continue;
        GPI[k*16+slotn]=i|(idx_of[jm]<<4);
        GPS[k*16+slotn]=(float)rsign_d(im,jm);
        slotn++;
      }
      for(;slotn<16;slotn++){ GPI[k*16+slotn]=0; GPS[k*16+slotn]=0.f; }
    } else if (tid<32){
      int p=tid-16, pm=mask_of[p], rest=15&~pm, slotn=0;
      for(int u=0;u<16;u++){
        if(u & ~rest) continue;
        int am=pm|u, bm=pm|(rest&~u);
        float s=(float)( rsign_d(pm,15&~pm)*rsign_d(15&~am,15&~bm)
                        *rsign_d(am,15&~am)*rsign_d(bm,15&~bm) );
        JNI[p*16+slotn]=idx_of[am]|(idx_of[bm]<<4);
        JNS[p*16+slotn]=s;
        slotn++;
      }
      for(;slotn<16;slotn++){ JNI[p*16+slotn]=0; JNS[p*16+slotn]=0.f; }
    }
  }

  // combine attention partials: lane = (head h=ln>>2, quarter qr=ln&3)
  // strips of 64 queries; base(s)=(a+1)(2a+b), nsp=a+1 (a=s>>2,b=s&3)
  {
    int b=tt>>11, t=tt&(T_-1);
    int strip=t>>6, qil=t&63;
    int h=ln>>2, qr=ln&3;
    int aa=strip>>2, bb2=strip&3;
    int nsp=aa+1;
    int rbase=(aa+1)*(2*aa+bb2);
    const float* pb = part + ((size_t)((b*8+h)*NSLOT+rbase)*64 + qil)*20;
    float am[4]={0,0,0,0};
    float lv=0.f, s0=0.f, s1=0.f, s2=0.f;
    for(int spp=0; spp<nsp; ++spp){
      const float4* p4=(const float4*)(pb + (size_t)spp*64*20);
      float4 a4=p4[qr];
      am[0]+=a4.x; am[1]+=a4.y; am[2]+=a4.z; am[3]+=a4.w;
      if(qr==0){ float4 meta=p4[4]; s0+=meta.x; s1+=meta.y; s2+=meta.z; lv+=meta.w; }
    }
    float inv = (qr==0)? 1.f/lv : 0.f;
    inv = __shfl(inv, (tid & ~3));
    float* os=&OS[tl*152];
    #pragma unroll
    for(int p=0;p<4;p++) os[h*16+qr*4+p]=am[p]*inv;
    if(qr==0){ os[128+h*3]=s0*inv; os[128+h*3+1]=s1*inv; os[128+h*3+2]=s2*inv; }
  }
  __syncthreads();

  const float* os=&OS[tl*152];
  float xh[2][16];
  #pragma unroll
  for(int ii=0;ii<2;ii++){
    #pragma unroll
    for(int p=0;p<16;p++) xh[ii][p]=os[(iq*2+ii)*16+p];
  }
  float xs[24];
  #pragma unroll
  for(int jj=0;jj<24;jj++) xs[jj]=os[128+jj];

  // ao: channel o, input quarter iq
  float y[16];
  #pragma unroll
  for(int p=0;p<16;p++) y[p]=0.f;
  #pragma unroll
  for(int ii=0;ii<2;ii++){
    const float* wi=w_ao_mv+o*72+(iq*2+ii)*9;
    #pragma unroll
    for(int p=0;p<16;p++){
      y[p]+=wi[GRADE[p]]*xh[ii][p];
      if(AUGK[p]>=0) y[p]+=wi[AUGK[p]]*xh[ii][AUGS[p]];
    }
  }
  float e=(iq==0)? b_ao_mv[o] : 0.f;
  for(int j2=iq*6;j2<iq*6+6;j2++) e+=w_ao_s2mv[o*24+j2]*xs[j2];
  y[0]+=e;
  float a3[3];
  #pragma unroll
  for(int jj=0;jj<3;jj++) a3[jj]=(iq==0)? b_ao_s[o*3+jj] : 0.f;
  #pragma unroll
  for(int ii=0;ii<2;ii++){
    #pragma unroll
    for(int jj=0;jj<3;jj++) a3[jj]+=w_ao_m2s[(o*3+jj)*8+(iq*2+ii)]*xh[ii][0];
  }
  for(int j2=iq*6;j2<iq*6+6;j2++){
    #pragma unroll
    for(int jj=0;jj<3;jj++) a3[jj]+=w_ao_s2s[(o*3+jj)*24+j2]*xs[j2];
  }
  #pragma unroll
  for(int p=0;p<16;p++){ y[p]+=__shfl_xor(y[p],8); y[p]+=__shfl_xor(y[p],16); }
  #pragma unroll
  for(int jj=0;jj<3;jj++){ a3[jj]+=__shfl_xor(a3[jj],8); a3[jj]+=__shfl_xor(a3[jj],16); }

  // residual + norms (dup across iq; reduce over o via xor 1,2,4)
  float hch[16]; float sqv=0.f;
  { const float4* hg=(const float4*)(h_mv+(size_t)tt*128+o*16);
    #pragma unroll
    for(int r4=0;r4<4;r4++){ float4 v=hg[r4];
      hch[r4*4]=v.x+y[r4*4]; hch[r4*4+1]=v.y+y[r4*4+1];
      hch[r4*4+2]=v.z+y[r4*4+2]; hch[r4*4+3]=v.w+y[r4*4+3]; } }
  #pragma unroll
  for(int p=0;p<16;p++) sqv+=FINNER[p]*hch[p]*hch[p];
  sqv+=__shfl_xor(sqv,1); sqv+=__shfl_xor(sqv,2); sqv+=__shfl_xor(sqv,4);
  float dmv=rsqrtf(sqv*0.125f+0.01f);
  float hs3[3]; float ssq=0.f;
  #pragma unroll
  for(int jj=0;jj<3;jj++){
    float v=h_s[(size_t)tt*24+o*3+jj]+a3[jj];
    hs3[jj]=v; ssq+=v*v;
  }
  ssq+=__shfl_xor(ssq,1); ssq+=__shfl_xor(ssq,2); ssq+=__shfl_xor(ssq,4);
  float dss=rsqrtf(ssq*(1.f/24.f)+0.01f);

  float* nsbuf=&NS[tl*152];
  if(iq==0){
    #pragma unroll
    for(int p=0;p<16;p++) nsbuf[o*16+p]=hch[p]*dmv;
    #pragma unroll
    for(int jj=0;jj<3;jj++) nsbuf[128+o*3+jj]=hs3[jj]*dss;
  }
  __syncthreads();

  // m1: lane = (output channel ln16, input half mh)
  {
    int ln16=ln&15, mh=ln>>4;
    float u[16];
    #pragma unroll
    for(int p=0;p<16;p++) u[p]=0.f;
    for(int i=mh*4;i<mh*4+4;i++){
      float xi[16];
      const float4* xs4=(const float4*)&nsbuf[i*16];
      #pragma unroll
      for(int r4=0;r4<4;r4++){ float4 v=xs4[r4]; xi[r4*4]=v.x; xi[r4*4+1]=v.y; xi[r4*4+2]=v.z; xi[r4*4+3]=v.w; }
      const float* wi=w_m1_mv+ln16*72+i*9;
      #pragma unroll
      for(int p=0;p<16;p++){
        u[p]+=wi[GRADE[p]]*xi[p];
        if(AUGK[p]>=0) u[p]+=wi[AUGK[p]]*xi[AUGS[p]];
      }
    }
    float e1=(mh==0)? b_m1_mv[ln16] : 0.f;
    for(int j2=mh*12;j2<mh*12+12;j2++) e1+=w_m1_s2mv[ln16*24+j2]*nsbuf[128+j2];
    u[0]+=e1;
    #pragma unroll
    for(int p=0;p<16;p++) u[p]+=__shfl_xor(u[p],16);
    if(mh==0){
      float* uu=&U[tl*264];
      #pragma unroll
      for(int p=0;p<16;p++) uu[ln16*16+p]=u[p];
    }
  }
  if(ln<8){  // m1 scalar path, o=ln
    float s3[3];
    #pragma unroll
    for(int jj=0;jj<3;jj++) s3[jj]=b_m1_s[o*3+jj];
    for(int j2=0;j2<24;j2++){
      float s=nsbuf[128+j2];
      #pragma unroll
      for(int jj=0;jj<3;jj++) s3[jj]+=w_m1_s2s[(o*3+jj)*24+j2]*s;
    }
    for(int i=0;i<8;i++){
      float x0=nsbuf[i*16];
      #pragma unroll
      for(int jj=0;jj<3;jj++) s3[jj]+=w_m1_m2s[(o*3+jj)*8+i]*x0;
    }
    #pragma unroll
    for(int jj=0;jj<3;jj++) GSm[tl*24+o*3+jj]=gelu_f(s3[jj]);
  }
  __syncthreads();

  // GP (o<4) / JOIN (o>=4): product o, component quarter iq; gate via shfl
  {
    const int*   TI=(o<4)? GPI : JNI;
    const float* TS=(o<4)? GPS : JNS;
    const float* uu=&U[tl*264];
    const float* lft=&uu[((o<4)? o : (4+o))*16];
    const float* rgt=&uu[((o<4)? (4+o) : (8+o))*16];
    float g[4];
    #pragma unroll
    for(int kk=0;kk<4;kk++){
      int k=iq*4+kk;
      float accv=0.f;
      #pragma unroll
      for(int e2=0;e2<16;e2++){
        int ij=TI[k*16+e2]; float sg=TS[k*16+e2];
        accv += sg * lft[ij&15] * rgt[ij>>4];
      }
      g[kk]=accv;
    }
    float g0 = __shfl(g[0], (tid & ~0x18));   // comp0 lives on iq==0 lane
    float gt = gelu_f(g0);
    float* gg=&G[tl*136];
    #pragma unroll
    for(int kk=0;kk<4;kk++) gg[o*16+iq*4+kk]=g[kk]*gt;
  }
  __syncthreads();

  // m2: channel o, input quarter iq
  float y2[16];
  #pragma unroll
  for(int p=0;p<16;p++) y2[p]=0.f;
  #pragma unroll
  for(int ii=0;ii<2;ii++){
    float xi[16];
    const float4* gi=(const float4*)&G[tl*136+(iq*2+ii)*16];
    #pragma unroll
    for(int r4=0;r4<4;r4++){ float4 v=gi[r4]; xi[r4*4]=v.x; xi[r4*4+1]=v.y; xi[r4*4+2]=v.z; xi[r4*4+3]=v.w; }
    const float* wi=w_m2_mv+o*72+(iq*2+ii)*9;
    #pragma unroll
    for(int p=0;p<16;p++){
      y2[p]+=wi[GRADE[p]]*xi[p];
      if(AUGK[p]>=0) y2[p]+=wi[AUGK[p]]*xi[AUGS[p]];
    }
  }
  float e2=(iq==0)? b_m2_mv[o] : 0.f;
  for(int j2=iq*6;j2<iq*6+6;j2++) e2+=w_m2_s2mv[o*24+j2]*GSm[tl*24+j2];
  y2[0]+=e2;
  #pragma unroll
  for(int p=0;p<16;p++){ y2[p]+=__shfl_xor(y2[p],8); y2[p]+=__shfl_xor(y2[p],16); }

  float hf[16];
  #pragma unroll
  for(int p=0;p<16;p++) hf[p]=hch[p]+y2[p];

  const float* wout=w_out_mv+o*9;
  float c5 =wout[2]*hf[5] +wout[6]*hf[2];
  float c6 =wout[2]*hf[6] +wout[6]*hf[3];
  float c7 =wout[2]*hf[7] +wout[6]*hf[4];
  float c11=wout[3]*hf[11]+wout[7]*hf[8];
  float c12=wout[3]*hf[12]+wout[7]*hf[9];
  float c13=wout[3]*hf[13]+wout[7]*hf[10];
  float c14=wout[3]*hf[14];
  #pragma unroll
  for(int mk=1; mk<8; mk<<=1){
    c5+=__shfl_xor(c5,mk); c6+=__shfl_xor(c6,mk); c7+=__shfl_xor(c7,mk);
    c11+=__shfl_xor(c11,mk); c12+=__shfl_xor(c12,mk);
    c13+=__shfl_xor(c13,mk); c14+=__shfl_xor(c14,mk);
  }
  if(ln==0){
    float dd=c14;
    dd=(fabsf(dd)>0.001f)? dd : (dd>=0.f? 0.001f : -0.001f);
    float* op=out+(size_t)tt*6;
    op[0]=-c13/dd; op[1]=c12/dd; op[2]=-c11/dd;
    op[3]=2.f*c5; op[4]=2.f*c6; op[5]=2.f*c7;
  }
}

extern "C" void kernel_launch(void* const* d_in, const int* in_sizes, int n_in,
                              void* d_out, int out_size, void* d_ws, size_t ws_size,
                              hipStream_t stream)
{
  (void)in_sizes; (void)n_in; (void)out_size; (void)ws_size;
  const float* x         =(const float*)d_in[0];
  const float* w_in_mv   =(const float*)d_in[1];
  const float* b_in_mv   =(const float*)d_in[2];
  const float* w_in_m2s  =(const float*)d_in[3];
  const float* b_in_s    =(const float*)d_in[4];
  const float* w_qkv_mv  =(const float*)d_in[5];
  const float* w_qkv_s2mv=(const float*)d_in[6];
  const float* w_qkv_m2s =(const float*)d_in[7];
  const float* w_qkv_s2s =(const float*)d_in[8];
  const float* w_ao_mv   =(const float*)d_in[9];
  const float* w_ao_s2mv =(const float*)d_in[10];
  const float* w_ao_m2s  =(const float*)d_in[11];
  const float* w_ao_s2s  =(const float*)d_in[12];
  const float* b_ao_mv   =(const float*)d_in[13];
  const float* b_ao_s    =(const float*)d_in[14];
  const float* w_m1_mv   =(const float*)d_in[15];
  const float* w_m1_s2mv =(const float*)d_in[16];
  const float* w_m1_m2s  =(const float*)d_in[17];
  const float* w_m1_s2s  =(const float*)d_in[18];
  const float* b_m1_mv   =(const float*)d_in[19];
  const float* b_m1_s    =(const float*)d_in[20];
  const float* w_m2_mv   =(const float*)d_in[21];
  const float* w_m2_s2mv =(const float*)d_in[22];
  const float* b_m2_mv   =(const float*)d_in[25];
  const float* w_out_mv  =(const float*)d_in[27];
  float* outp=(float*)d_out;

  float* ws=(float*)d_ws;
  size_t off=0;
  float* h_mv = ws+off; off+=(size_t)BTOK*128;
  float* h_s  = ws+off; off+=(size_t)BTOK*24;
  unsigned* qph = (unsigned*)(ws+off); off+=(size_t)16*T_*8;      // 16 halfs/token
  unsigned* kph = (unsigned*)(ws+off); off+=(size_t)16*T_*8;      // 16 halfs/token
  unsigned* vph = (unsigned*)(ws+off); off+=(size_t)16*32*(T_/2); // V^T: 32 comps x T/2 pairs
  float* part = ws+off; off+=(size_t)16*NSLOT*64*20;

  k_in  <<<BTOK/2,64,0,stream>>>(x,w_in_mv,b_in_mv,w_in_m2s,b_in_s,
                                 w_qkv_mv,w_qkv_s2mv,w_qkv_m2s,w_qkv_s2s,
                                 h_mv,h_s,qph,kph,vph);
  k_attn<<<16*NSLOT,256,0,stream>>>(qph,kph,vph,part);
  k_tail<<<BTOK/2,64,0,stream>>>(part,
                                 w_ao_mv,w_ao_s2mv,w_ao_m2s,w_ao_s2s,b_ao_mv,b_ao_s,
                                 h_mv,h_s,
                                 w_m1_mv,w_m1_s2mv,w_m1_m2s,w_m1_s2s,b_m1_mv,b_m1_s,
                                 w_m2_mv,w_m2_s2mv,b_m2_mv,w_out_mv,outp);
}

// Round 14
// 80.896 us; speedup vs baseline: 1.5167x; 1.0901x over previous
//
#include <hip/hip_runtime.h>
#include <math.h>

#define T_    2048
#define BTOK  4096   // B * T
#define NSLOT 80     // sum over 32 strips of ceil((s+1)/8)

namespace {
constexpr int GRADE[16] = {0,1,1,1,1,2,2,2,2,2,2,3,3,3,3,4};
constexpr int AUGK[16]  = {-1,5,-1,-1,-1,6,6,6,-1,-1,-1,7,7,7,-1,8};
constexpr int AUGS[16]  = { 0,0, 0, 0, 0,2,3,4, 0, 0, 0,8,9,10,0,14};
constexpr float FINNER[16] = {1.f,0.f,1.f,1.f,1.f,0.f,0.f,0.f,1.f,1.f,1.f,0.f,0.f,0.f,1.f,0.f};
}

typedef __attribute__((ext_vector_type(4))) _Float16 h4_t;
typedef __attribute__((ext_vector_type(4))) float    f4_t;

__device__ __forceinline__ unsigned pkh(float a, float b){
  return __builtin_bit_cast(unsigned, __builtin_amdgcn_cvt_pkrtz(a,b));
}
__device__ __forceinline__ f4_t mfma16(h4_t a, h4_t b, f4_t c){
  return __builtin_amdgcn_mfma_f32_16x16x16f16(a,b,c,0,0,0);
}

__device__ __forceinline__ float gelu_f(float v){
  return 0.5f*v*(1.f + erff(v*0.70710678118654752f));
}

__device__ __forceinline__ int rsign_d(int a, int b){
  int s=0; a>>=1; while(a){ s += __popc(a&b); a>>=1; } return (s&1) ? -1 : 1;
}

// ---- K_A: embed + in-linear + norm + QKV projections + fp16 pack ---------
// 64 threads = 2 tokens x 32 lanes (8 heads x 4 input-quarters).
// Q/K: 16 halfs/token; V^T: [bh][comp 0..31][key-pair] (comp19 = half2(1,1)).
__global__ void __launch_bounds__(64) k_in(
    const float* __restrict__ x,
    const float* __restrict__ w_in_mv, const float* __restrict__ b_in_mv,
    const float* __restrict__ w_in_m2s, const float* __restrict__ b_in_s,
    const float* __restrict__ w_mv, const float* __restrict__ w_s2mv,
    const float* __restrict__ w_m2s, const float* __restrict__ w_s2s,
    float* __restrict__ h_mv, float* __restrict__ h_s,
    unsigned* __restrict__ qph, unsigned* __restrict__ kph, unsigned* __restrict__ vph)
{
  __shared__ float NS[2*152];   // per token: n_mv 128 + n_s 24
  int tid=threadIdx.x, tl=tid>>5, ln=tid&31;
  int o=ln&7, iq=ln>>3;          // iq 0..3
  int tt=blockIdx.x*2+tl;
  int b=tt>>11, t=tt&(T_-1);
  const float* xp = x+(size_t)tt*6;
  float mv[16];
  #pragma unroll
  for(int p=0;p<16;p++) mv[p]=0.f;
  mv[0]=1.f; mv[14]=1.f;
  mv[13]=-xp[0]; mv[12]=xp[1]; mv[11]=-xp[2];
  mv[5]=0.5f*xp[3]; mv[6]=0.5f*xp[4]; mv[7]=0.5f*xp[5];

  const float* wo=w_in_mv+o*9;
  float h[16]; float sq=0.f;
  #pragma unroll
  for(int p=0;p<16;p++){
    float v=wo[GRADE[p]]*mv[p];
    if(AUGK[p]>=0) v+=wo[AUGK[p]]*mv[AUGS[p]];
    if(p==0) v+=b_in_mv[o];
    h[p]=v; sq+=FINNER[p]*v*v;
  }
  sq+=__shfl_xor(sq,1); sq+=__shfl_xor(sq,2); sq+=__shfl_xor(sq,4);
  float dmv=rsqrtf(sq*0.125f+0.01f);
  float hs[3]; float ssq=0.f;
  #pragma unroll
  for(int jj=0;jj<3;jj++){ float v=w_in_m2s[o*3+jj]+b_in_s[o*3+jj]; hs[jj]=v; ssq+=v*v; }
  ssq+=__shfl_xor(ssq,1); ssq+=__shfl_xor(ssq,2); ssq+=__shfl_xor(ssq,4);
  float dss=rsqrtf(ssq*(1.f/24.f)+0.01f);

  float* ns=&NS[tl*152];
  if(iq==0){
    float4* hg=(float4*)(h_mv+(size_t)tt*128+o*16);
    hg[0]=make_float4(h[0],h[1],h[2],h[3]);
    hg[1]=make_float4(h[4],h[5],h[6],h[7]);
    hg[2]=make_float4(h[8],h[9],h[10],h[11]);
    hg[3]=make_float4(h[12],h[13],h[14],h[15]);
    #pragma unroll
    for(int jj=0;jj<3;jj++) h_s[(size_t)tt*24+o*3+jj]=hs[jj];
    #pragma unroll
    for(int p=0;p<16;p++) ns[o*16+p]=h[p]*dmv;
    #pragma unroll
    for(int jj=0;jj<3;jj++) ns[128+o*3+jj]=hs[jj]*dss;
  }
  __syncthreads();

  // projections: lane (o,iq) does input channels iq*2..+1, scalar j iq*6..+5
  float yq[16],yk[16],yv[16];
  #pragma unroll
  for(int p=0;p<16;p++){ yq[p]=0.f; yk[p]=0.f; yv[p]=0.f; }
  float nx0p[2];
  const float* wq=w_mv+o*72;
  #pragma unroll
  for(int ii=0;ii<2;ii++){
    int i=iq*2+ii;
    float xi[16];
    const float4* xs4=(const float4*)&ns[i*16];
    #pragma unroll
    for(int r4=0;r4<4;r4++){ float4 v=xs4[r4]; xi[r4*4]=v.x; xi[r4*4+1]=v.y; xi[r4*4+2]=v.z; xi[r4*4+3]=v.w; }
    nx0p[ii]=xi[0];
    const float* aq=wq+i*9; const float* ak=aq+576; const float* av=aq+1152;
    #pragma unroll
    for(int p=0;p<16;p++){
      float bb=xi[p];
      yq[p]+=aq[GRADE[p]]*bb; yk[p]+=ak[GRADE[p]]*bb; yv[p]+=av[GRADE[p]]*bb;
      if(AUGK[p]>=0){
        float au=xi[AUGS[p]];
        yq[p]+=aq[AUGK[p]]*au; yk[p]+=ak[AUGK[p]]*au; yv[p]+=av[AUGK[p]]*au;
      }
    }
  }
  float sq3[3]={0,0,0}, sk3[3]={0,0,0}, sv3[3]={0,0,0};
  float eq=0.f,ek=0.f,ev=0.f;
  for(int j=iq*6;j<iq*6+6;j++){
    float s=ns[128+j];
    eq+=w_s2mv[o*24+j]*s; ek+=w_s2mv[192+o*24+j]*s; ev+=w_s2mv[384+o*24+j]*s;
    #pragma unroll
    for(int jj=0;jj<3;jj++){
      int d=o*3+jj;
      sq3[jj]+=w_s2s[d*24+j]*s;
      sk3[jj]+=w_s2s[576+d*24+j]*s;
      sv3[jj]+=w_s2s[1152+d*24+j]*s;
    }
  }
  #pragma unroll
  for(int ii=0;ii<2;ii++){
    int i=iq*2+ii;
    #pragma unroll
    for(int jj=0;jj<3;jj++){
      int d=o*3+jj;
      sq3[jj]+=w_m2s[d*8+i]*nx0p[ii];
      sk3[jj]+=w_m2s[192+d*8+i]*nx0p[ii];
      sv3[jj]+=w_m2s[384+d*8+i]*nx0p[ii];
    }
  }
  yq[0]+=eq; yk[0]+=ek; yv[0]+=ev;
  #pragma unroll
  for(int p=0;p<16;p++){
    yq[p]+=__shfl_xor(yq[p],8);  yq[p]+=__shfl_xor(yq[p],16);
    yk[p]+=__shfl_xor(yk[p],8);  yk[p]+=__shfl_xor(yk[p],16);
    yv[p]+=__shfl_xor(yv[p],8);  yv[p]+=__shfl_xor(yv[p],16);
  }
  #pragma unroll
  for(int jj=0;jj<3;jj++){
    sq3[jj]+=__shfl_xor(sq3[jj],8); sq3[jj]+=__shfl_xor(sq3[jj],16);
    sk3[jj]+=__shfl_xor(sk3[jj],8); sk3[jj]+=__shfl_xor(sk3[jj],16);
    sv3[jj]+=__shfl_xor(sv3[jj],8); sv3[jj]+=__shfl_xor(sv3[jj],16);
  }

  const float scale = 0.3015113445777636f;  // 1/sqrt(11)
  size_t rb=((size_t)(b*8+o)*T_+t);
  if(iq==0){
    uint4 qa,qb;
    qa.x=pkh(yq[0]*scale, yq[2]*scale);  qa.y=pkh(yq[3]*scale, yq[4]*scale);
    qa.z=pkh(yq[8]*scale, yq[9]*scale);  qa.w=pkh(yq[10]*scale, yq[14]*scale);
    qb.x=pkh(sq3[0]*scale, sq3[1]*scale); qb.y=pkh(sq3[2]*scale, 0.f); qb.z=0u; qb.w=0u;
    uint4* qr4=(uint4*)qph + rb*2; qr4[0]=qa; qr4[1]=qb;
  } else if(iq==1){
    uint4 ka,kb;
    ka.x=pkh(yk[0],yk[2]);  ka.y=pkh(yk[3],yk[4]);
    ka.z=pkh(yk[8],yk[9]);  ka.w=pkh(yk[10],yk[14]);
    kb.x=pkh(sk3[0],sk3[1]); kb.y=pkh(sk3[2],0.f); kb.z=0u; kb.w=0u;
    uint4* kr4=(uint4*)kph + rb*2; kr4[0]=ka; kr4[1]=kb;
  }
  // V^T fp16 interleave by key-pair via cross-token shfl (lane distance 32)
  {
    size_t vbase = (size_t)(b*8+o)*32;
    size_t pair  = (size_t)(t>>1);
    bool even = (tl==0);
    if(iq==2){
      #pragma unroll
      for(int c=0;c<10;c++){
        float other=__shfl_xor(yv[c],32);
        if(even) vph[(vbase+c)*(T_/2)+pair]=pkh(yv[c],other);
      }
    } else if(iq==3){
      #pragma unroll
      for(int c=10;c<16;c++){
        float other=__shfl_xor(yv[c],32);
        if(even) vph[(vbase+c)*(T_/2)+pair]=pkh(yv[c],other);
      }
      #pragma unroll
      for(int jj=0;jj<3;jj++){
        float other=__shfl_xor(sv3[jj],32);
        if(even) vph[(vbase+16+jj)*(T_/2)+pair]=pkh(sv3[jj],other);
      }
      if(even) vph[(vbase+19)*(T_/2)+pair]=0x3C003C00u;  // half2(1,1) -> l
    }
    if(even){  // zero-fill comps 20..31 (poison safety)
      int c0=20+iq*3;
      #pragma unroll
      for(int cc=0;cc<3;cc++) vph[(vbase+c0+cc)*(T_/2)+pair]=0u;
    }
  }
}

// ---- K_B: MFMA attention, no-max softmax, additive partials --------------
// Block = 4 waves x 16 queries (64-query strip piece). NSLOT=80:
// c(s)=ceil((s+1)/8) -> up to 32 chunks/wave (deep loop pipelines loads).
__global__ void __launch_bounds__(256) k_attn(
    const unsigned* __restrict__ qph, const unsigned* __restrict__ kph,
    const unsigned* __restrict__ vph,
    float* __restrict__ part)
{
  int tid=threadIdx.x;
  int wave=tid>>6, lane=tid&63;
  int col=lane&15, rowb=lane>>4;   // mfma col / k-block
  int j=blockIdx.x;
  int bh=j&15;
  int z=NSLOT-1-(j>>4);            // heavy slots first
  int a=0;
  while (4*(a+1)*(a+2) <= z) a++;  // groups of 8 strips share c=a+1
  int rem = z - 4*a*(a+1);
  int bqd = rem/(a+1);
  int sp  = rem - bqd*(a+1);
  int strip = 8*a + bqd;
  int c     = a+1;
  int nchunk = (strip+1)*4;        // 16-key chunks in [0,(strip+1)*64)
  int t0 = sp*nchunk/c, t1 = (sp+1)*nchunk/c;
  int chend = strip*4 + wave + 1;  // causal cap for this wave's 16-query tile
  if (t1 < chend) chend = t1;

  int q0 = strip*64 + wave*16;
  const h4_t* qh4=(const h4_t*)qph;
  const h4_t* kh4=(const h4_t*)kph;
  const h4_t* vh4=(const h4_t*)vph;

  // B=Q operand: lane holds Q[q0+col][d=4*rowb+i]
  h4_t bq = qh4[((size_t)bh*T_ + q0 + col)*4 + rowb];

  f4_t acc0={0.f,0.f,0.f,0.f}, acc1={0.f,0.f,0.f,0.f};
  size_t v0base = ((size_t)bh*32 + col)*(T_/2/2);      // h4 units
  size_t v1base = ((size_t)bh*32 + 16 + col)*(T_/2/2);

  #pragma unroll 4
  for(int ch=t0; ch<chend; ++ch){
    // A=K operand: lane holds K[16ch+col][d=4*rowb+i]
    h4_t ak = kh4[((size_t)bh*T_ + 16*ch + col)*4 + rowb];
    f4_t zz={0.f,0.f,0.f,0.f};
    f4_t st = mfma16(ak, bq, zz);    // S^T[key=4*rowb+r][q=col]
    float c0=fminf(__expf(st[0]),60000.f);
    float c1=fminf(__expf(st[1]),60000.f);
    float c2=fminf(__expf(st[2]),60000.f);
    float c3=fminf(__expf(st[3]),60000.f);
    h4_t bp = __builtin_bit_cast(h4_t, make_uint2(pkh(c0,c1), pkh(c2,c3)));
    // A=V^T operands: lane holds V^T[c][key=16ch+4*rowb+i]
    h4_t av0 = vh4[v0base + (size_t)ch*4 + rowb];
    h4_t av1 = vh4[v1base + (size_t)ch*4 + rowb];
    acc0 = mfma16(av0, bp, acc0);
    acc1 = mfma16(av1, bp, acc1);
  }

  // write partials: O^T[comp=4*rowb+r][q=q0w+col]; comps 16..19 from acc1 (rowb==0)
  float* rec = part + (((size_t)bh*NSLOT + z)*64 + wave*16 + col)*20;
  ((float4*)rec)[rowb] = make_float4(acc0[0],acc0[1],acc0[2],acc0[3]);
  if(rowb==0) ((float4*)rec)[4] = make_float4(acc1[0],acc1[1],acc1[2],acc1[3]);
}

// ---- K_C: combine partials + ao + norm + m1 + GP/join + m2 + out ---------
// 64 threads = 2 tokens x 32 lanes (8 channels x 4 quarters).
__global__ void __launch_bounds__(64) k_tail(
    const float* __restrict__ part,
    const float* __restrict__ w_ao_mv, const float* __restrict__ w_ao_s2mv,
    const float* __restrict__ w_ao_m2s, const float* __restrict__ w_ao_s2s,
    const float* __restrict__ b_ao_mv, const float* __restrict__ b_ao_s,
    const float* __restrict__ h_mv, const float* __restrict__ h_s,
    const float* __restrict__ w_m1_mv, const float* __restrict__ w_m1_s2mv,
    const float* __restrict__ w_m1_m2s, const float* __restrict__ w_m1_s2s,
    const float* __restrict__ b_m1_mv, const float* __restrict__ b_m1_s,
    const float* __restrict__ w_m2_mv, const float* __restrict__ w_m2_s2mv,
    const float* __restrict__ b_m2_mv,
    const float* __restrict__ w_out_mv,
    float* __restrict__ out)
{
  __shared__ int   GPI[256]; __shared__ float GPS[256];
  __shared__ int   JNI[256]; __shared__ float JNS[256];
  __shared__ float OS[2*152];
  __shared__ float NS[2*152];
  __shared__ float U[2*264];
  __shared__ float G[2*136];
  __shared__ float GSm[2*24];
  int tid=threadIdx.x, tl=tid>>5, ln=tid&31;
  int o=ln&7, iq=ln>>3;          // iq 0..3
  int tt=blockIdx.x*2+tl;

  { // build tables (threads 0..31)
    const int mask_of[16]={0,1,2,4,8,3,5,9,6,10,12,7,11,13,14,15};
    const int idx_of[16] ={0,1,2,5,3,6,8,11,4,7,9,12,10,13,14,15};
    if (tid<16){
      int k=tid, km=mask_of[k], slotn=0;
      for(int i=0;i<16;i++){
        int im=mask_of[i], jm=im^km;
        if(im & jm & 1) continue;
        GPI[k*16+slotn]=i|(idx_of[jm]<<4);
        GPS[k*16+slotn]=(float)rsign_d(im,jm);
        slotn++;
      }
      for(;slotn<16;slotn++){ GPI[k*16+slotn]=0; GPS[k*16+slotn]=0.f; }
    } else if (tid<32){
      int p=tid-16, pm=mask_of[p], rest=15&~pm, slotn=0;
      for(int u=0;u<16;u++){
        if(u & ~rest) continue;
        int am=pm|u, bm=pm|(rest&~u);
        float s=(float)( rsign_d(pm,15&~pm)*rsign_d(15&~am,15&~bm)
                        *rsign_d(am,15&~am)*rsign_d(bm,15&~bm) );
        JNI[p*16+slotn]=idx_of[am]|(idx_of[bm]<<4);
        JNS[p*16+slotn]=s;
        slotn++;
      }
      for(;slotn<16;slotn++){ JNI[p*16+slotn]=0; JNS[p*16+slotn]=0.f; }
    }
  }

  // combine attention partials: lane = (head h=ln>>2, quarter qr=ln&3)
  // strips of 64 queries; aa=strip>>3, nsp=aa+1, rbase=4aa(aa+1)+(strip&7)(aa+1)
  {
    int b=tt>>11, t=tt&(T_-1);
    int strip=t>>6, qil=t&63;
    int h=ln>>2, qr=ln&3;
    int aa=strip>>3;
    int nsp=aa+1;
    int rbase=4*aa*(aa+1)+(strip&7)*(aa+1);
    const float* pb = part + ((size_t)((b*8+h)*NSLOT+rbase)*64 + qil)*20;
    float am[4]={0,0,0,0};
    float lv=0.f, s0=0.f, s1=0.f, s2=0.f;
    for(int spp=0; spp<nsp; ++spp){
      const float4* p4=(const float4*)(pb + (size_t)spp*64*20);
      float4 a4=p4[qr];
      am[0]+=a4.x; am[1]+=a4.y; am[2]+=a4.z; am[3]+=a4.w;
      if(qr==0){ float4 meta=p4[4]; s0+=meta.x; s1+=meta.y; s2+=meta.z; lv+=meta.w; }
    }
    float inv = (qr==0)? 1.f/lv : 0.f;
    inv = __shfl(inv, (tid & ~3));
    float* os=&OS[tl*152];
    #pragma unroll
    for(int p=0;p<4;p++) os[h*16+qr*4+p]=am[p]*inv;
    if(qr==0){ os[128+h*3]=s0*inv; os[128+h*3+1]=s1*inv; os[128+h*3+2]=s2*inv; }
  }
  __syncthreads();

  const float* os=&OS[tl*152];
  float xh[2][16];
  #pragma unroll
  for(int ii=0;ii<2;ii++){
    #pragma unroll
    for(int p=0;p<16;p++) xh[ii][p]=os[(iq*2+ii)*16+p];
  }
  float xs[24];
  #pragma unroll
  for(int jj=0;jj<24;jj++) xs[jj]=os[128+jj];

  // ao: channel o, input quarter iq
  float y[16];
  #pragma unroll
  for(int p=0;p<16;p++) y[p]=0.f;
  #pragma unroll
  for(int ii=0;ii<2;ii++){
    const float* wi=w_ao_mv+o*72+(iq*2+ii)*9;
    #pragma unroll
    for(int p=0;p<16;p++){
      y[p]+=wi[GRADE[p]]*xh[ii][p];
      if(AUGK[p]>=0) y[p]+=wi[AUGK[p]]*xh[ii][AUGS[p]];
    }
  }
  float e=(iq==0)? b_ao_mv[o] : 0.f;
  for(int j2=iq*6;j2<iq*6+6;j2++) e+=w_ao_s2mv[o*24+j2]*xs[j2];
  y[0]+=e;
  float a3[3];
  #pragma unroll
  for(int jj=0;jj<3;jj++) a3[jj]=(iq==0)? b_ao_s[o*3+jj] : 0.f;
  #pragma unroll
  for(int ii=0;ii<2;ii++){
    #pragma unroll
    for(int jj=0;jj<3;jj++) a3[jj]+=w_ao_m2s[(o*3+jj)*8+(iq*2+ii)]*xh[ii][0];
  }
  for(int j2=iq*6;j2<iq*6+6;j2++){
    #pragma unroll
    for(int jj=0;jj<3;jj++) a3[jj]+=w_ao_s2s[(o*3+jj)*24+j2]*xs[j2];
  }
  #pragma unroll
  for(int p=0;p<16;p++){ y[p]+=__shfl_xor(y[p],8); y[p]+=__shfl_xor(y[p],16); }
  #pragma unroll
  for(int jj=0;jj<3;jj++){ a3[jj]+=__shfl_xor(a3[jj],8); a3[jj]+=__shfl_xor(a3[jj],16); }

  // residual + norms (dup across iq; reduce over o via xor 1,2,4)
  float hch[16]; float sqv=0.f;
  { const float4* hg=(const float4*)(h_mv+(size_t)tt*128+o*16);
    #pragma unroll
    for(int r4=0;r4<4;r4++){ float4 v=hg[r4];
      hch[r4*4]=v.x+y[r4*4]; hch[r4*4+1]=v.y+y[r4*4+1];
      hch[r4*4+2]=v.z+y[r4*4+2]; hch[r4*4+3]=v.w+y[r4*4+3]; } }
  #pragma unroll
  for(int p=0;p<16;p++) sqv+=FINNER[p]*hch[p]*hch[p];
  sqv+=__shfl_xor(sqv,1); sqv+=__shfl_xor(sqv,2); sqv+=__shfl_xor(sqv,4);
  float dmv=rsqrtf(sqv*0.125f+0.01f);
  float hs3[3]; float ssq=0.f;
  #pragma unroll
  for(int jj=0;jj<3;jj++){
    float v=h_s[(size_t)tt*24+o*3+jj]+a3[jj];
    hs3[jj]=v; ssq+=v*v;
  }
  ssq+=__shfl_xor(ssq,1); ssq+=__shfl_xor(ssq,2); ssq+=__shfl_xor(ssq,4);
  float dss=rsqrtf(ssq*(1.f/24.f)+0.01f);

  float* nsbuf=&NS[tl*152];
  if(iq==0){
    #pragma unroll
    for(int p=0;p<16;p++) nsbuf[o*16+p]=hch[p]*dmv;
    #pragma unroll
    for(int jj=0;jj<3;jj++) nsbuf[128+o*3+jj]=hs3[jj]*dss;
  }
  __syncthreads();

  // m1: lane = (output channel ln16, input half mh)
  {
    int ln16=ln&15, mh=ln>>4;
    float u[16];
    #pragma unroll
    for(int p=0;p<16;p++) u[p]=0.f;
    for(int i=mh*4;i<mh*4+4;i++){
      float xi[16];
      const float4* xs4=(const float4*)&nsbuf[i*16];
      #pragma unroll
      for(int r4=0;r4<4;r4++){ float4 v=xs4[r4]; xi[r4*4]=v.x; xi[r4*4+1]=v.y; xi[r4*4+2]=v.z; xi[r4*4+3]=v.w; }
      const float* wi=w_m1_mv+ln16*72+i*9;
      #pragma unroll
      for(int p=0;p<16;p++){
        u[p]+=wi[GRADE[p]]*xi[p];
        if(AUGK[p]>=0) u[p]+=wi[AUGK[p]]*xi[AUGS[p]];
      }
    }
    float e1=(mh==0)? b_m1_mv[ln16] : 0.f;
    for(int j2=mh*12;j2<mh*12+12;j2++) e1+=w_m1_s2mv[ln16*24+j2]*nsbuf[128+j2];
    u[0]+=e1;
    #pragma unroll
    for(int p=0;p<16;p++) u[p]+=__shfl_xor(u[p],16);
    if(mh==0){
      float* uu=&U[tl*264];
      #pragma unroll
      for(int p=0;p<16;p++) uu[ln16*16+p]=u[p];
    }
  }
  if(ln<8){  // m1 scalar path, o=ln
    float s3[3];
    #pragma unroll
    for(int jj=0;jj<3;jj++) s3[jj]=b_m1_s[o*3+jj];
    for(int j2=0;j2<24;j2++){
      float s=nsbuf[128+j2];
      #pragma unroll
      for(int jj=0;jj<3;jj++) s3[jj]+=w_m1_s2s[(o*3+jj)*24+j2]*s;
    }
    for(int i=0;i<8;i++){
      float x0=nsbuf[i*16];
      #pragma unroll
      for(int jj=0;jj<3;jj++) s3[jj]+=w_m1_m2s[(o*3+jj)*8+i]*x0;
    }
    #pragma unroll
    for(int jj=0;jj<3;jj++) GSm[tl*24+o*3+jj]=gelu_f(s3[jj]);
  }
  __syncthreads();

  // GP (o<4) / JOIN (o>=4): product o, component quarter iq; gate via shfl
  {
    const int*   TI=(o<4)? GPI : JNI;
    const float* TS=(o<4)? GPS : JNS;
    const float* uu=&U[tl*264];
    const float* lft=&uu[((o<4)? o : (4+o))*16];
    const float* rgt=&uu[((o<4)? (4+o) : (8+o))*16];
    float g[4];
    #pragma unroll
    for(int kk=0;kk<4;kk++){
      int k=iq*4+kk;
      float accv=0.f;
      #pragma unroll
      for(int e2=0;e2<16;e2++){
        int ij=TI[k*16+e2]; float sg=TS[k*16+e2];
        accv += sg * lft[ij&15] * rgt[ij>>4];
      }
      g[kk]=accv;
    }
    float g0 = __shfl(g[0], (tid & ~0x18));   // comp0 lives on iq==0 lane
    float gt = gelu_f(g0);
    float* gg=&G[tl*136];
    #pragma unroll
    for(int kk=0;kk<4;kk++) gg[o*16+iq*4+kk]=g[kk]*gt;
  }
  __syncthreads();

  // m2: channel o, input quarter iq
  float y2[16];
  #pragma unroll
  for(int p=0;p<16;p++) y2[p]=0.f;
  #pragma unroll
  for(int ii=0;ii<2;ii++){
    float xi[16];
    const float4* gi=(const float4*)&G[tl*136+(iq*2+ii)*16];
    #pragma unroll
    for(int r4=0;r4<4;r4++){ float4 v=gi[r4]; xi[r4*4]=v.x; xi[r4*4+1]=v.y; xi[r4*4+2]=v.z; xi[r4*4+3]=v.w; }
    const float* wi=w_m2_mv+o*72+(iq*2+ii)*9;
    #pragma unroll
    for(int p=0;p<16;p++){
      y2[p]+=wi[GRADE[p]]*xi[p];
      if(AUGK[p]>=0) y2[p]+=wi[AUGK[p]]*xi[AUGS[p]];
    }
  }
  float e2=(iq==0)? b_m2_mv[o] : 0.f;
  for(int j2=iq*6;j2<iq*6+6;j2++) e2+=w_m2_s2mv[o*24+j2]*GSm[tl*24+j2];
  y2[0]+=e2;
  #pragma unroll
  for(int p=0;p<16;p++){ y2[p]+=__shfl_xor(y2[p],8); y2[p]+=__shfl_xor(y2[p],16); }

  float hf[16];
  #pragma unroll
  for(int p=0;p<16;p++) hf[p]=hch[p]+y2[p];

  const float* wout=w_out_mv+o*9;
  float c5 =wout[2]*hf[5] +wout[6]*hf[2];
  float c6 =wout[2]*hf[6] +wout[6]*hf[3];
  float c7 =wout[2]*hf[7] +wout[6]*hf[4];
  float c11=wout[3]*hf[11]+wout[7]*hf[8];
  float c12=wout[3]*hf[12]+wout[7]*hf[9];
  float c13=wout[3]*hf[13]+wout[7]*hf[10];
  float c14=wout[3]*hf[14];
  #pragma unroll
  for(int mk=1; mk<8; mk<<=1){
    c5+=__shfl_xor(c5,mk); c6+=__shfl_xor(c6,mk); c7+=__shfl_xor(c7,mk);
    c11+=__shfl_xor(c11,mk); c12+=__shfl_xor(c12,mk);
    c13+=__shfl_xor(c13,mk); c14+=__shfl_xor(c14,mk);
  }
  if(ln==0){
    float dd=c14;
    dd=(fabsf(dd)>0.001f)? dd : (dd>=0.f? 0.001f : -0.001f);
    float* op=out+(size_t)tt*6;
    op[0]=-c13/dd; op[1]=c12/dd; op[2]=-c11/dd;
    op[3]=2.f*c5; op[4]=2.f*c6; op[5]=2.f*c7;
  }
}

extern "C" void kernel_launch(void* const* d_in, const int* in_sizes, int n_in,
                              void* d_out, int out_size, void* d_ws, size_t ws_size,
                              hipStream_t stream)
{
  (void)in_sizes; (void)n_in; (void)out_size; (void)ws_size;
  const float* x         =(const float*)d_in[0];
  const float* w_in_mv   =(const float*)d_in[1];
  const float* b_in_mv   =(const float*)d_in[2];
  const float* w_in_m2s  =(const float*)d_in[3];
  const float* b_in_s    =(const float*)d_in[4];
  const float* w_qkv_mv  =(const float*)d_in[5];
  const float* w_qkv_s2mv=(const float*)d_in[6];
  const float* w_qkv_m2s =(const float*)d_in[7];
  const float* w_qkv_s2s =(const float*)d_in[8];
  const float* w_ao_mv   =(const float*)d_in[9];
  const float* w_ao_s2mv =(const float*)d_in[10];
  const float* w_ao_m2s  =(const float*)d_in[11];
  const float* w_ao_s2s  =(const float*)d_in[12];
  const float* b_ao_mv   =(const float*)d_in[13];
  const float* b_ao_s    =(const float*)d_in[14];
  const float* w_m1_mv   =(const float*)d_in[15];
  const float* w_m1_s2mv =(const float*)d_in[16];
  const float* w_m1_m2s  =(const float*)d_in[17];
  const float* w_m1_s2s  =(const float*)d_in[18];
  const float* b_m1_mv   =(const float*)d_in[19];
  const float* b_m1_s    =(const float*)d_in[20];
  const float* w_m2_mv   =(const float*)d_in[21];
  const float* w_m2_s2mv =(const float*)d_in[22];
  const float* b_m2_mv   =(const float*)d_in[25];
  const float* w_out_mv  =(const float*)d_in[27];
  float* outp=(float*)d_out;

  float* ws=(float*)d_ws;
  size_t off=0;
  float* h_mv = ws+off; off+=(size_t)BTOK*128;
  float* h_s  = ws+off; off+=(size_t)BTOK*24;
  unsigned* qph = (unsigned*)(ws+off); off+=(size_t)16*T_*8;      // 16 halfs/token
  unsigned* kph = (unsigned*)(ws+off); off+=(size_t)16*T_*8;      // 16 halfs/token
  unsigned* vph = (unsigned*)(ws+off); off+=(size_t)16*32*(T_/2); // V^T: 32 comps x T/2 pairs
  float* part = ws+off; off+=(size_t)16*NSLOT*64*20;

  k_in  <<<BTOK/2,64,0,stream>>>(x,w_in_mv,b_in_mv,w_in_m2s,b_in_s,
                                 w_qkv_mv,w_qkv_s2mv,w_qkv_m2s,w_qkv_s2s,
                                 h_mv,h_s,qph,kph,vph);
  k_attn<<<16*NSLOT,256,0,stream>>>(qph,kph,vph,part);
  k_tail<<<BTOK/2,64,0,stream>>>(part,
                                 w_ao_mv,w_ao_s2mv,w_ao_m2s,w_ao_s2s,b_ao_mv,b_ao_s,
                                 h_mv,h_s,
                                 w_m1_mv,w_m1_s2mv,w_m1_m2s,w_m1_s2s,b_m1_mv,b_m1_s,
                                 w_m2_mv,w_m2_s2mv,b_m2_mv,w_out_mv,outp);
}

// Round 15
// 58.348 us; speedup vs baseline: 2.1028x; 1.3864x over previous
//
#include <hip/hip_runtime.h>
#include <math.h>

#define T_    2048
#define BTOK  4096   // B * T
#define NSLOT 80     // sum over 32 strips of ceil((s+1)/8)

namespace {
constexpr int GRADE[16] = {0,1,1,1,1,2,2,2,2,2,2,3,3,3,3,4};
constexpr int AUGK[16]  = {-1,5,-1,-1,-1,6,6,6,-1,-1,-1,7,7,7,-1,8};
constexpr int AUGS[16]  = { 0,0, 0, 0, 0,2,3,4, 0, 0, 0,8,9,10,0,14};
constexpr float FINNER[16] = {1.f,0.f,1.f,1.f,1.f,0.f,0.f,0.f,1.f,1.f,1.f,0.f,0.f,0.f,1.f,0.f};
}

typedef __attribute__((ext_vector_type(4))) _Float16 h4_t;
typedef __attribute__((ext_vector_type(4))) float    f4_t;

__device__ __forceinline__ unsigned pkh(float a, float b){
  return __builtin_bit_cast(unsigned, __builtin_amdgcn_cvt_pkrtz(a,b));
}
__device__ __forceinline__ f4_t mfma16(h4_t a, h4_t b, f4_t c){
  return __builtin_amdgcn_mfma_f32_16x16x16f16(a,b,c,0,0,0);
}

__device__ __forceinline__ float gelu_f(float v){
  return 0.5f*v*(1.f + erff(v*0.70710678118654752f));
}

__device__ __forceinline__ int rsign_d(int a, int b){
  int s=0; a>>=1; while(a){ s += __popc(a&b); a>>=1; } return (s&1) ? -1 : 1;
}

// ---- K_A: embed + in-linear + norm + QKV projections + fp16 pack ---------
// 64 threads = 2 tokens x 32 lanes (8 heads x 4 input-quarters).
// Q/K: 16 halfs/token.
// V^T chunk-tiled: [bh][chunk=key/16][comp 0..31][8 pairs] u32 -> a wave's
// PV operand load is one contiguous 512B region (was 16 x 4KB-strided rows).
__global__ void __launch_bounds__(64) k_in(
    const float* __restrict__ x,
    const float* __restrict__ w_in_mv, const float* __restrict__ b_in_mv,
    const float* __restrict__ w_in_m2s, const float* __restrict__ b_in_s,
    const float* __restrict__ w_mv, const float* __restrict__ w_s2mv,
    const float* __restrict__ w_m2s, const float* __restrict__ w_s2s,
    float* __restrict__ h_mv, float* __restrict__ h_s,
    unsigned* __restrict__ qph, unsigned* __restrict__ kph, unsigned* __restrict__ vph)
{
  __shared__ float NS[2*152];   // per token: n_mv 128 + n_s 24
  int tid=threadIdx.x, tl=tid>>5, ln=tid&31;
  int o=ln&7, iq=ln>>3;          // iq 0..3
  int tt=blockIdx.x*2+tl;
  int b=tt>>11, t=tt&(T_-1);
  const float* xp = x+(size_t)tt*6;
  float mv[16];
  #pragma unroll
  for(int p=0;p<16;p++) mv[p]=0.f;
  mv[0]=1.f; mv[14]=1.f;
  mv[13]=-xp[0]; mv[12]=xp[1]; mv[11]=-xp[2];
  mv[5]=0.5f*xp[3]; mv[6]=0.5f*xp[4]; mv[7]=0.5f*xp[5];

  const float* wo=w_in_mv+o*9;
  float h[16]; float sq=0.f;
  #pragma unroll
  for(int p=0;p<16;p++){
    float v=wo[GRADE[p]]*mv[p];
    if(AUGK[p]>=0) v+=wo[AUGK[p]]*mv[AUGS[p]];
    if(p==0) v+=b_in_mv[o];
    h[p]=v; sq+=FINNER[p]*v*v;
  }
  sq+=__shfl_xor(sq,1); sq+=__shfl_xor(sq,2); sq+=__shfl_xor(sq,4);
  float dmv=rsqrtf(sq*0.125f+0.01f);
  float hs[3]; float ssq=0.f;
  #pragma unroll
  for(int jj=0;jj<3;jj++){ float v=w_in_m2s[o*3+jj]+b_in_s[o*3+jj]; hs[jj]=v; ssq+=v*v; }
  ssq+=__shfl_xor(ssq,1); ssq+=__shfl_xor(ssq,2); ssq+=__shfl_xor(ssq,4);
  float dss=rsqrtf(ssq*(1.f/24.f)+0.01f);

  float* ns=&NS[tl*152];
  if(iq==0){
    float4* hg=(float4*)(h_mv+(size_t)tt*128+o*16);
    hg[0]=make_float4(h[0],h[1],h[2],h[3]);
    hg[1]=make_float4(h[4],h[5],h[6],h[7]);
    hg[2]=make_float4(h[8],h[9],h[10],h[11]);
    hg[3]=make_float4(h[12],h[13],h[14],h[15]);
    #pragma unroll
    for(int jj=0;jj<3;jj++) h_s[(size_t)tt*24+o*3+jj]=hs[jj];
    #pragma unroll
    for(int p=0;p<16;p++) ns[o*16+p]=h[p]*dmv;
    #pragma unroll
    for(int jj=0;jj<3;jj++) ns[128+o*3+jj]=hs[jj]*dss;
  }
  __syncthreads();

  // projections: lane (o,iq) does input channels iq*2..+1, scalar j iq*6..+5
  float yq[16],yk[16],yv[16];
  #pragma unroll
  for(int p=0;p<16;p++){ yq[p]=0.f; yk[p]=0.f; yv[p]=0.f; }
  float nx0p[2];
  const float* wq=w_mv+o*72;
  #pragma unroll
  for(int ii=0;ii<2;ii++){
    int i=iq*2+ii;
    float xi[16];
    const float4* xs4=(const float4*)&ns[i*16];
    #pragma unroll
    for(int r4=0;r4<4;r4++){ float4 v=xs4[r4]; xi[r4*4]=v.x; xi[r4*4+1]=v.y; xi[r4*4+2]=v.z; xi[r4*4+3]=v.w; }
    nx0p[ii]=xi[0];
    const float* aq=wq+i*9; const float* ak=aq+576; const float* av=aq+1152;
    #pragma unroll
    for(int p=0;p<16;p++){
      float bb=xi[p];
      yq[p]+=aq[GRADE[p]]*bb; yk[p]+=ak[GRADE[p]]*bb; yv[p]+=av[GRADE[p]]*bb;
      if(AUGK[p]>=0){
        float au=xi[AUGS[p]];
        yq[p]+=aq[AUGK[p]]*au; yk[p]+=ak[AUGK[p]]*au; yv[p]+=av[AUGK[p]]*au;
      }
    }
  }
  float sq3[3]={0,0,0}, sk3[3]={0,0,0}, sv3[3]={0,0,0};
  float eq=0.f,ek=0.f,ev=0.f;
  for(int j=iq*6;j<iq*6+6;j++){
    float s=ns[128+j];
    eq+=w_s2mv[o*24+j]*s; ek+=w_s2mv[192+o*24+j]*s; ev+=w_s2mv[384+o*24+j]*s;
    #pragma unroll
    for(int jj=0;jj<3;jj++){
      int d=o*3+jj;
      sq3[jj]+=w_s2s[d*24+j]*s;
      sk3[jj]+=w_s2s[576+d*24+j]*s;
      sv3[jj]+=w_s2s[1152+d*24+j]*s;
    }
  }
  #pragma unroll
  for(int ii=0;ii<2;ii++){
    int i=iq*2+ii;
    #pragma unroll
    for(int jj=0;jj<3;jj++){
      int d=o*3+jj;
      sq3[jj]+=w_m2s[d*8+i]*nx0p[ii];
      sk3[jj]+=w_m2s[192+d*8+i]*nx0p[ii];
      sv3[jj]+=w_m2s[384+d*8+i]*nx0p[ii];
    }
  }
  yq[0]+=eq; yk[0]+=ek; yv[0]+=ev;
  #pragma unroll
  for(int p=0;p<16;p++){
    yq[p]+=__shfl_xor(yq[p],8);  yq[p]+=__shfl_xor(yq[p],16);
    yk[p]+=__shfl_xor(yk[p],8);  yk[p]+=__shfl_xor(yk[p],16);
    yv[p]+=__shfl_xor(yv[p],8);  yv[p]+=__shfl_xor(yv[p],16);
  }
  #pragma unroll
  for(int jj=0;jj<3;jj++){
    sq3[jj]+=__shfl_xor(sq3[jj],8); sq3[jj]+=__shfl_xor(sq3[jj],16);
    sk3[jj]+=__shfl_xor(sk3[jj],8); sk3[jj]+=__shfl_xor(sk3[jj],16);
    sv3[jj]+=__shfl_xor(sv3[jj],8); sv3[jj]+=__shfl_xor(sv3[jj],16);
  }

  const float scale = 0.3015113445777636f;  // 1/sqrt(11)
  size_t rb=((size_t)(b*8+o)*T_+t);
  if(iq==0){
    uint4 qa,qb;
    qa.x=pkh(yq[0]*scale, yq[2]*scale);  qa.y=pkh(yq[3]*scale, yq[4]*scale);
    qa.z=pkh(yq[8]*scale, yq[9]*scale);  qa.w=pkh(yq[10]*scale, yq[14]*scale);
    qb.x=pkh(sq3[0]*scale, sq3[1]*scale); qb.y=pkh(sq3[2]*scale, 0.f); qb.z=0u; qb.w=0u;
    uint4* qr4=(uint4*)qph + rb*2; qr4[0]=qa; qr4[1]=qb;
  } else if(iq==1){
    uint4 ka,kb;
    ka.x=pkh(yk[0],yk[2]);  ka.y=pkh(yk[3],yk[4]);
    ka.z=pkh(yk[8],yk[9]);  ka.w=pkh(yk[10],yk[14]);
    kb.x=pkh(sk3[0],sk3[1]); kb.y=pkh(sk3[2],0.f); kb.z=0u; kb.w=0u;
    uint4* kr4=(uint4*)kph + rb*2; kr4[0]=ka; kr4[1]=kb;
  }
  // V^T chunk-tiled write: tile = 256 u32 = [comp][8 pairs]
  {
    size_t vbase2 = (size_t)(b*8+o)*(T_/16)*256;   // per-bh: T/16 chunk tiles
    size_t cidx   = (size_t)(t>>4);                // chunk index
    int    wp     = (t>>1)&7;                      // pair within chunk
    size_t tb     = vbase2 + cidx*256;
    bool even = (tl==0);
    if(iq==2){
      #pragma unroll
      for(int c=0;c<10;c++){
        float other=__shfl_xor(yv[c],32);
        if(even) vph[tb + c*8 + wp]=pkh(yv[c],other);
      }
    } else if(iq==3){
      #pragma unroll
      for(int c=10;c<16;c++){
        float other=__shfl_xor(yv[c],32);
        if(even) vph[tb + c*8 + wp]=pkh(yv[c],other);
      }
      #pragma unroll
      for(int jj=0;jj<3;jj++){
        float other=__shfl_xor(sv3[jj],32);
        if(even) vph[tb + (16+jj)*8 + wp]=pkh(sv3[jj],other);
      }
      if(even) vph[tb + 19*8 + wp]=0x3C003C00u;  // half2(1,1) -> l
    }
    if(even){  // zero-fill comps 20..31 (poison safety)
      int c0=20+iq*3;
      #pragma unroll
      for(int cc=0;cc<3;cc++) vph[tb + (c0+cc)*8 + wp]=0u;
    }
  }
}

// ---- K_B: MFMA attention, no-max softmax, additive partials --------------
// Block = 4 waves x 16 queries. V^T chunk-tiled: per-wave PV operand loads
// are contiguous 512B (comps 0-15) + 512B (comps 16-31) per chunk.
__global__ void __launch_bounds__(256) k_attn(
    const unsigned* __restrict__ qph, const unsigned* __restrict__ kph,
    const unsigned* __restrict__ vph,
    float* __restrict__ part)
{
  int tid=threadIdx.x;
  int wave=tid>>6, lane=tid&63;
  int col=lane&15, rowb=lane>>4;   // mfma col / k-block
  int j=blockIdx.x;
  int bh=j&15;
  int z=NSLOT-1-(j>>4);            // heavy slots first
  int a=0;
  while (4*(a+1)*(a+2) <= z) a++;  // groups of 8 strips share c=a+1
  int rem = z - 4*a*(a+1);
  int bqd = rem/(a+1);
  int sp  = rem - bqd*(a+1);
  int strip = 8*a + bqd;
  int c     = a+1;
  int nchunk = (strip+1)*4;        // 16-key chunks in [0,(strip+1)*64)
  int t0 = sp*nchunk/c, t1 = (sp+1)*nchunk/c;
  int chend = strip*4 + wave + 1;  // causal cap for this wave's 16-query tile
  if (t1 < chend) chend = t1;

  int q0 = strip*64 + wave*16;
  const h4_t* qh4=(const h4_t*)qph;
  const h4_t* kh4=(const h4_t*)kph;
  const h4_t* vh4=(const h4_t*)vph;

  // B=Q operand: lane holds Q[q0+col][d=4*rowb+i]
  h4_t bq = qh4[((size_t)bh*T_ + q0 + col)*4 + rowb];

  f4_t acc0={0.f,0.f,0.f,0.f}, acc1={0.f,0.f,0.f,0.f};
  size_t vtile = (size_t)bh*(T_/16)*128;   // h4 units: 128 h4 per chunk tile
  int voff0 = col*4 + rowb;                // comps 0..15
  int voff1 = 64 + col*4 + rowb;           // comps 16..31

  #pragma unroll 4
  for(int ch=t0; ch<chend; ++ch){
    // A=K operand: lane holds K[16ch+col][d=4*rowb+i]
    h4_t ak = kh4[((size_t)bh*T_ + 16*ch + col)*4 + rowb];
    f4_t zz={0.f,0.f,0.f,0.f};
    f4_t st = mfma16(ak, bq, zz);    // S^T[key=4*rowb+r][q=col]
    float c0=fminf(__expf(st[0]),60000.f);
    float c1=fminf(__expf(st[1]),60000.f);
    float c2=fminf(__expf(st[2]),60000.f);
    float c3=fminf(__expf(st[3]),60000.f);
    h4_t bp = __builtin_bit_cast(h4_t, make_uint2(pkh(c0,c1), pkh(c2,c3)));
    // A=V^T operands: contiguous per-chunk tiles
    h4_t av0 = vh4[vtile + (size_t)ch*128 + voff0];
    h4_t av1 = vh4[vtile + (size_t)ch*128 + voff1];
    acc0 = mfma16(av0, bp, acc0);
    acc1 = mfma16(av1, bp, acc1);
  }

  // write partials: O^T[comp=4*rowb+r][q=q0w+col]; comps 16..19 from acc1 (rowb==0)
  float* rec = part + (((size_t)bh*NSLOT + z)*64 + wave*16 + col)*20;
  ((float4*)rec)[rowb] = make_float4(acc0[0],acc0[1],acc0[2],acc0[3]);
  if(rowb==0) ((float4*)rec)[4] = make_float4(acc1[0],acc1[1],acc1[2],acc1[3]);
}

// ---- K_C: combine partials + ao + norm + m1 + GP/join + m2 + out ---------
// 64 threads = 2 tokens x 32 lanes (8 channels x 4 quarters).
__global__ void __launch_bounds__(64) k_tail(
    const float* __restrict__ part,
    const float* __restrict__ w_ao_mv, const float* __restrict__ w_ao_s2mv,
    const float* __restrict__ w_ao_m2s, const float* __restrict__ w_ao_s2s,
    const float* __restrict__ b_ao_mv, const float* __restrict__ b_ao_s,
    const float* __restrict__ h_mv, const float* __restrict__ h_s,
    const float* __restrict__ w_m1_mv, const float* __restrict__ w_m1_s2mv,
    const float* __restrict__ w_m1_m2s, const float* __restrict__ w_m1_s2s,
    const float* __restrict__ b_m1_mv, const float* __restrict__ b_m1_s,
    const float* __restrict__ w_m2_mv, const float* __restrict__ w_m2_s2mv,
    const float* __restrict__ b_m2_mv,
    const float* __restrict__ w_out_mv,
    float* __restrict__ out)
{
  __shared__ int   GPI[256]; __shared__ float GPS[256];
  __shared__ int   JNI[256]; __shared__ float JNS[256];
  __shared__ float OS[2*152];
  __shared__ float NS[2*152];
  __shared__ float U[2*264];
  __shared__ float G[2*136];
  __shared__ float GSm[2*24];
  int tid=threadIdx.x, tl=tid>>5, ln=tid&31;
  int o=ln&7, iq=ln>>3;          // iq 0..3
  int tt=blockIdx.x*2+tl;

  { // build tables (threads 0..31)
    const int mask_of[16]={0,1,2,4,8,3,5,9,6,10,12,7,11,13,14,15};
    const int idx_of[16] ={0,1,2,5,3,6,8,11,4,7,9,12,10,13,14,15};
    if (tid<16){
      int k=tid, km=mask_of[k], slotn=0;
      for(int i=0;i<16;i++){
        int im=mask_of[i], jm=im^km;
        if(im & jm & 1) continue;
        GPI[k*16+slotn]=i|(idx_of[jm]<<4);
        GPS[k*16+slotn]=(float)rsign_d(im,jm);
        slotn++;
      }
      for(;slotn<16;slotn++){ GPI[k*16+slotn]=0; GPS[k*16+slotn]=0.f; }
    } else if (tid<32){
      int p=tid-16, pm=mask_of[p], rest=15&~pm, slotn=0;
      for(int u=0;u<16;u++){
        if(u & ~rest) continue;
        int am=pm|u, bm=pm|(rest&~u);
        float s=(float)( rsign_d(pm,15&~pm)*rsign_d(15&~am,15&~bm)
                        *rsign_d(am,15&~am)*rsign_d(bm,15&~bm) );
        JNI[p*16+slotn]=idx_of[am]|(idx_of[bm]<<4);
        JNS[p*16+slotn]=s;
        slotn++;
      }
      for(;slotn<16;slotn++){ JNI[p*16+slotn]=0; JNS[p*16+slotn]=0.f; }
    }
  }

  // combine attention partials: lane = (head h=ln>>2, quarter qr=ln&3)
  // strips of 64 queries; aa=strip>>3, nsp=aa+1, rbase=4aa(aa+1)+(strip&7)(aa+1)
  {
    int b=tt>>11, t=tt&(T_-1);
    int strip=t>>6, qil=t&63;
    int h=ln>>2, qr=ln&3;
    int aa=strip>>3;
    int nsp=aa+1;
    int rbase=4*aa*(aa+1)+(strip&7)*(aa+1);
    const float* pb = part + ((size_t)((b*8+h)*NSLOT+rbase)*64 + qil)*20;
    float am[4]={0,0,0,0};
    float lv=0.f, s0=0.f, s1=0.f, s2=0.f;
    for(int spp=0; spp<nsp; ++spp){
      const float4* p4=(const float4*)(pb + (size_t)spp*64*20);
      float4 a4=p4[qr];
      am[0]+=a4.x; am[1]+=a4.y; am[2]+=a4.z; am[3]+=a4.w;
      if(qr==0){ float4 meta=p4[4]; s0+=meta.x; s1+=meta.y; s2+=meta.z; lv+=meta.w; }
    }
    float inv = (qr==0)? 1.f/lv : 0.f;
    inv = __shfl(inv, (tid & ~3));
    float* os=&OS[tl*152];
    #pragma unroll
    for(int p=0;p<4;p++) os[h*16+qr*4+p]=am[p]*inv;
    if(qr==0){ os[128+h*3]=s0*inv; os[128+h*3+1]=s1*inv; os[128+h*3+2]=s2*inv; }
  }
  __syncthreads();

  const float* os=&OS[tl*152];
  float xh[2][16];
  #pragma unroll
  for(int ii=0;ii<2;ii++){
    #pragma unroll
    for(int p=0;p<16;p++) xh[ii][p]=os[(iq*2+ii)*16+p];
  }
  float xs[24];
  #pragma unroll
  for(int jj=0;jj<24;jj++) xs[jj]=os[128+jj];

  // ao: channel o, input quarter iq
  float y[16];
  #pragma unroll
  for(int p=0;p<16;p++) y[p]=0.f;
  #pragma unroll
  for(int ii=0;ii<2;ii++){
    const float* wi=w_ao_mv+o*72+(iq*2+ii)*9;
    #pragma unroll
    for(int p=0;p<16;p++){
      y[p]+=wi[GRADE[p]]*xh[ii][p];
      if(AUGK[p]>=0) y[p]+=wi[AUGK[p]]*xh[ii][AUGS[p]];
    }
  }
  float e=(iq==0)? b_ao_mv[o] : 0.f;
  for(int j2=iq*6;j2<iq*6+6;j2++) e+=w_ao_s2mv[o*24+j2]*xs[j2];
  y[0]+=e;
  float a3[3];
  #pragma unroll
  for(int jj=0;jj<3;jj++) a3[jj]=(iq==0)? b_ao_s[o*3+jj] : 0.f;
  #pragma unroll
  for(int ii=0;ii<2;ii++){
    #pragma unroll
    for(int jj=0;jj<3;jj++) a3[jj]+=w_ao_m2s[(o*3+jj)*8+(iq*2+ii)]*xh[ii][0];
  }
  for(int j2=iq*6;j2<iq*6+6;j2++){
    #pragma unroll
    for(int jj=0;jj<3;jj++) a3[jj]+=w_ao_s2s[(o*3+jj)*24+j2]*xs[j2];
  }
  #pragma unroll
  for(int p=0;p<16;p++){ y[p]+=__shfl_xor(y[p],8); y[p]+=__shfl_xor(y[p],16); }
  #pragma unroll
  for(int jj=0;jj<3;jj++){ a3[jj]+=__shfl_xor(a3[jj],8); a3[jj]+=__shfl_xor(a3[jj],16); }

  // residual + norms (dup across iq; reduce over o via xor 1,2,4)
  float hch[16]; float sqv=0.f;
  { const float4* hg=(const float4*)(h_mv+(size_t)tt*128+o*16);
    #pragma unroll
    for(int r4=0;r4<4;r4++){ float4 v=hg[r4];
      hch[r4*4]=v.x+y[r4*4]; hch[r4*4+1]=v.y+y[r4*4+1];
      hch[r4*4+2]=v.z+y[r4*4+2]; hch[r4*4+3]=v.w+y[r4*4+3]; } }
  #pragma unroll
  for(int p=0;p<16;p++) sqv+=FINNER[p]*hch[p]*hch[p];
  sqv+=__shfl_xor(sqv,1); sqv+=__shfl_xor(sqv,2); sqv+=__shfl_xor(sqv,4);
  float dmv=rsqrtf(sqv*0.125f+0.01f);
  float hs3[3]; float ssq=0.f;
  #pragma unroll
  for(int jj=0;jj<3;jj++){
    float v=h_s[(size_t)tt*24+o*3+jj]+a3[jj];
    hs3[jj]=v; ssq+=v*v;
  }
  ssq+=__shfl_xor(ssq,1); ssq+=__shfl_xor(ssq,2); ssq+=__shfl_xor(ssq,4);
  float dss=rsqrtf(ssq*(1.f/24.f)+0.01f);

  float* nsbuf=&NS[tl*152];
  if(iq==0){
    #pragma unroll
    for(int p=0;p<16;p++) nsbuf[o*16+p]=hch[p]*dmv;
    #pragma unroll
    for(int jj=0;jj<3;jj++) nsbuf[128+o*3+jj]=hs3[jj]*dss;
  }
  __syncthreads();

  // m1: lane = (output channel ln16, input half mh)
  {
    int ln16=ln&15, mh=ln>>4;
    float u[16];
    #pragma unroll
    for(int p=0;p<16;p++) u[p]=0.f;
    for(int i=mh*4;i<mh*4+4;i++){
      float xi[16];
      const float4* xs4=(const float4*)&nsbuf[i*16];
      #pragma unroll
      for(int r4=0;r4<4;r4++){ float4 v=xs4[r4]; xi[r4*4]=v.x; xi[r4*4+1]=v.y; xi[r4*4+2]=v.z; xi[r4*4+3]=v.w; }
      const float* wi=w_m1_mv+ln16*72+i*9;
      #pragma unroll
      for(int p=0;p<16;p++){
        u[p]+=wi[GRADE[p]]*xi[p];
        if(AUGK[p]>=0) u[p]+=wi[AUGK[p]]*xi[AUGS[p]];
      }
    }
    float e1=(mh==0)? b_m1_mv[ln16] : 0.f;
    for(int j2=mh*12;j2<mh*12+12;j2++) e1+=w_m1_s2mv[ln16*24+j2]*nsbuf[128+j2];
    u[0]+=e1;
    #pragma unroll
    for(int p=0;p<16;p++) u[p]+=__shfl_xor(u[p],16);
    if(mh==0){
      float* uu=&U[tl*264];
      #pragma unroll
      for(int p=0;p<16;p++) uu[ln16*16+p]=u[p];
    }
  }
  if(ln<8){  // m1 scalar path, o=ln
    float s3[3];
    #pragma unroll
    for(int jj=0;jj<3;jj++) s3[jj]=b_m1_s[o*3+jj];
    for(int j2=0;j2<24;j2++){
      float s=nsbuf[128+j2];
      #pragma unroll
      for(int jj=0;jj<3;jj++) s3[jj]+=w_m1_s2s[(o*3+jj)*24+j2]*s;
    }
    for(int i=0;i<8;i++){
      float x0=nsbuf[i*16];
      #pragma unroll
      for(int jj=0;jj<3;jj++) s3[jj]+=w_m1_m2s[(o*3+jj)*8+i]*x0;
    }
    #pragma unroll
    for(int jj=0;jj<3;jj++) GSm[tl*24+o*3+jj]=gelu_f(s3[jj]);
  }
  __syncthreads();

  // GP (o<4) / JOIN (o>=4): product o, component quarter iq; gate via shfl
  {
    const int*   TI=(o<4)? GPI : JNI;
    const float* TS=(o<4)? GPS : JNS;
    const float* uu=&U[tl*264];
    const float* lft=&uu[((o<4)? o : (4+o))*16];
    const float* rgt=&uu[((o<4)? (4+o) : (8+o))*16];
    float g[4];
    #pragma unroll
    for(int kk=0;kk<4;kk++){
      int k=iq*4+kk;
      float accv=0.f;
      #pragma unroll
      for(int e2=0;e2<16;e2++){
        int ij=TI[k*16+e2]; float sg=TS[k*16+e2];
        accv += sg * lft[ij&15] * rgt[ij>>4];
      }
      g[kk]=accv;
    }
    float g0 = __shfl(g[0], (tid & ~0x18));   // comp0 lives on iq==0 lane
    float gt = gelu_f(g0);
    float* gg=&G[tl*136];
    #pragma unroll
    for(int kk=0;kk<4;kk++) gg[o*16+iq*4+kk]=g[kk]*gt;
  }
  __syncthreads();

  // m2: channel o, input quarter iq
  float y2[16];
  #pragma unroll
  for(int p=0;p<16;p++) y2[p]=0.f;
  #pragma unroll
  for(int ii=0;ii<2;ii++){
    float xi[16];
    const float4* gi=(const float4*)&G[tl*136+(iq*2+ii)*16];
    #pragma unroll
    for(int r4=0;r4<4;r4++){ float4 v=gi[r4]; xi[r4*4]=v.x; xi[r4*4+1]=v.y; xi[r4*4+2]=v.z; xi[r4*4+3]=v.w; }
    const float* wi=w_m2_mv+o*72+(iq*2+ii)*9;
    #pragma unroll
    for(int p=0;p<16;p++){
      y2[p]+=wi[GRADE[p]]*xi[p];
      if(AUGK[p]>=0) y2[p]+=wi[AUGK[p]]*xi[AUGS[p]];
    }
  }
  float e2=(iq==0)? b_m2_mv[o] : 0.f;
  for(int j2=iq*6;j2<iq*6+6;j2++) e2+=w_m2_s2mv[o*24+j2]*GSm[tl*24+j2];
  y2[0]+=e2;
  #pragma unroll
  for(int p=0;p<16;p++){ y2[p]+=__shfl_xor(y2[p],8); y2[p]+=__shfl_xor(y2[p],16); }

  float hf[16];
  #pragma unroll
  for(int p=0;p<16;p++) hf[p]=hch[p]+y2[p];

  const float* wout=w_out_mv+o*9;
  float c5 =wout[2]*hf[5] +wout[6]*hf[2];
  float c6 =wout[2]*hf[6] +wout[6]*hf[3];
  float c7 =wout[2]*hf[7] +wout[6]*hf[4];
  float c11=wout[3]*hf[11]+wout[7]*hf[8];
  float c12=wout[3]*hf[12]+wout[7]*hf[9];
  float c13=wout[3]*hf[13]+wout[7]*hf[10];
  float c14=wout[3]*hf[14];
  #pragma unroll
  for(int mk=1; mk<8; mk<<=1){
    c5+=__shfl_xor(c5,mk); c6+=__shfl_xor(c6,mk); c7+=__shfl_xor(c7,mk);
    c11+=__shfl_xor(c11,mk); c12+=__shfl_xor(c12,mk);
    c13+=__shfl_xor(c13,mk); c14+=__shfl_xor(c14,mk);
  }
  if(ln==0){
    float dd=c14;
    dd=(fabsf(dd)>0.001f)? dd : (dd>=0.f? 0.001f : -0.001f);
    float* op=out+(size_t)tt*6;
    op[0]=-c13/dd; op[1]=c12/dd; op[2]=-c11/dd;
    op[3]=2.f*c5; op[4]=2.f*c6; op[5]=2.f*c7;
  }
}

extern "C" void kernel_launch(void* const* d_in, const int* in_sizes, int n_in,
                              void* d_out, int out_size, void* d_ws, size_t ws_size,
                              hipStream_t stream)
{
  (void)in_sizes; (void)n_in; (void)out_size; (void)ws_size;
  const float* x         =(const float*)d_in[0];
  const float* w_in_mv   =(const float*)d_in[1];
  const float* b_in_mv   =(const float*)d_in[2];
  const float* w_in_m2s  =(const float*)d_in[3];
  const float* b_in_s    =(const float*)d_in[4];
  const float* w_qkv_mv  =(const float*)d_in[5];
  const float* w_qkv_s2mv=(const float*)d_in[6];
  const float* w_qkv_m2s =(const float*)d_in[7];
  const float* w_qkv_s2s =(const float*)d_in[8];
  const float* w_ao_mv   =(const float*)d_in[9];
  const float* w_ao_s2mv =(const float*)d_in[10];
  const float* w_ao_m2s  =(const float*)d_in[11];
  const float* w_ao_s2s  =(const float*)d_in[12];
  const float* b_ao_mv   =(const float*)d_in[13];
  const float* b_ao_s    =(const float*)d_in[14];
  const float* w_m1_mv   =(const float*)d_in[15];
  const float* w_m1_s2mv =(const float*)d_in[16];
  const float* w_m1_m2s  =(const float*)d_in[17];
  const float* w_m1_s2s  =(const float*)d_in[18];
  const float* b_m1_mv   =(const float*)d_in[19];
  const float* b_m1_s    =(const float*)d_in[20];
  const float* w_m2_mv   =(const float*)d_in[21];
  const float* w_m2_s2mv =(const float*)d_in[22];
  const float* b_m2_mv   =(const float*)d_in[25];
  const float* w_out_mv  =(const float*)d_in[27];
  float* outp=(float*)d_out;

  float* ws=(float*)d_ws;
  size_t off=0;
  float* h_mv = ws+off; off+=(size_t)BTOK*128;
  float* h_s  = ws+off; off+=(size_t)BTOK*24;
  unsigned* qph = (unsigned*)(ws+off); off+=(size_t)16*T_*8;      // 16 halfs/token
  unsigned* kph = (unsigned*)(ws+off); off+=(size_t)16*T_*8;      // 16 halfs/token
  unsigned* vph = (unsigned*)(ws+off); off+=(size_t)16*(T_/16)*256; // V^T chunk tiles
  float* part = ws+off; off+=(size_t)16*NSLOT*64*20;

  k_in  <<<BTOK/2,64,0,stream>>>(x,w_in_mv,b_in_mv,w_in_m2s,b_in_s,
                                 w_qkv_mv,w_qkv_s2mv,w_qkv_m2s,w_qkv_s2s,
                                 h_mv,h_s,qph,kph,vph);
  k_attn<<<16*NSLOT,256,0,stream>>>(qph,kph,vph,part);
  k_tail<<<BTOK/2,64,0,stream>>>(part,
                                 w_ao_mv,w_ao_s2mv,w_ao_m2s,w_ao_s2s,b_ao_mv,b_ao_s,
                                 h_mv,h_s,
                                 w_m1_mv,w_m1_s2mv,w_m1_m2s,w_m1_s2s,b_m1_mv,b_m1_s,
                                 w_m2_mv,w_m2_s2mv,b_m2_mv,w_out_mv,outp);
}